// Round 1
// baseline (11884.934 us; speedup 1.0000x reference)
//
#include <hip/hip_runtime.h>
#include <math.h>

#define NPT 65536
#define NB 4
#define R3 32768

// ws layout (float offsets)
#define OFF_WEFF 0          // 5*27*64*64 = 552960   folded conv weights [l][t][i][o]
#define OFF_BEFF 552960     // 5*64 = 320            folded conv biases
#define OFF_PW   553280     // 64*64                 folded point-branch weights [i][o]
#define OFF_PB   557376     // 64
#define OFF_WAE  557440     // 64                    collapsed attention weight on vfeat
#define OFF_WBE  557504     // 64                    collapsed attention weight on pfeat
#define OFF_Q0   557568     // 1 (+pad 15)
#define OFF_MEAN 557584     // 12
#define OFF_MAXN 557596     // 4
#define OFF_CBUF 557600     // 4*262144 = 1048576    float4 normalized coords per point
#define OFF_CNT  1606176    // 131072                voxel counts   (contiguous with GA -> one zero pass)
#define OFF_GA   1737248    // 8388608               grid buffer A [B][R3][64]
#define OFF_GB   10125856   // 8388608               grid buffer B

__global__ void k_fold_w(const float* __restrict__ vconv_w, const float* __restrict__ vbn_g,
                         const float* __restrict__ res_w, const float* __restrict__ res_bn_g,
                         float* __restrict__ weff) {
    int idx = blockIdx.x * 256 + threadIdx.x;   // = ((l*27+t)*64+i)*64+o
    if (idx >= 5 * 27 * 64 * 64) return;
    int o = idx & 63;
    int i = (idx >> 6) & 63;
    int rest = idx >> 12;        // l*27 + t
    int t = rest % 27;
    int l = rest / 27;
    const float invs = rsqrtf(1.00001f);
    float scale, wsrc;
    if (l == 0) {
        scale = vbn_g[o] * invs;
        wsrc = vconv_w[(o * 64 + i) * 27 + t];
    } else {
        scale = res_bn_g[(l - 1) * 64 + o] * invs;
        wsrc = res_w[(size_t)(l - 1) * 110592 + (o * 64 + i) * 27 + t];
    }
    weff[idx] = wsrc * scale;
}

__global__ void k_misc(const float* __restrict__ vconv_b, const float* __restrict__ vbn_g,
                       const float* __restrict__ vbn_b,
                       const float* __restrict__ res_b, const float* __restrict__ res_bn_g,
                       const float* __restrict__ res_bn_b,
                       const float* __restrict__ pf_w, const float* __restrict__ pf_b,
                       const float* __restrict__ pf_bn_g, const float* __restrict__ pf_bn_b,
                       const float* __restrict__ wa, const float* __restrict__ ba,
                       const float* __restrict__ wb, const float* __restrict__ bb,
                       const float* __restrict__ wc, const float* __restrict__ bc,
                       float* __restrict__ ws) {
    int idx = blockIdx.x * 256 + threadIdx.x;
    const float invs = rsqrtf(1.00001f);
    if (idx < 320) {
        int l = idx >> 6, o = idx & 63;
        float b_, g_, s_;
        if (l == 0) { b_ = vconv_b[o]; g_ = vbn_g[o]; s_ = vbn_b[o]; }
        else {
            b_ = res_b[(l - 1) * 64 + o];
            g_ = res_bn_g[(l - 1) * 64 + o];
            s_ = res_bn_b[(l - 1) * 64 + o];
        }
        ws[OFF_BEFF + idx] = b_ * g_ * invs + s_;
    } else if (idx < 4416) {
        int j = idx - 320; int o = j & 63; int i = j >> 6;
        ws[OFF_PW + j] = pf_w[o * 64 + i] * pf_bn_g[o] * invs;
    } else if (idx < 4480) {
        int o = idx - 4416;
        ws[OFF_PB + o] = pf_b[o] * pf_bn_g[o] * invs + pf_bn_b[o];
    } else if (idx < 4544) {
        int o = idx - 4480;
        float s = 0.f;
        for (int j = 0; j < 16; j++) s += wc[j] * wa[j * 64 + o];
        ws[OFF_WAE + o] = s;
    } else if (idx < 4608) {
        int o = idx - 4544;
        float s = 0.f;
        for (int j = 0; j < 16; j++) s += wc[16 + j] * wb[j * 64 + o];
        ws[OFF_WBE + o] = s;
    } else if (idx == 4608) {
        float s = bc[0];
        for (int j = 0; j < 16; j++) s += wc[j] * ba[j] + wc[16 + j] * bb[j];
        ws[OFF_Q0] = s;
    }
}

__global__ void k_zero(float4* __restrict__ p, int n4) {
    int i = blockIdx.x * 256 + threadIdx.x;
    if (i < n4) p[i] = make_float4(0.f, 0.f, 0.f, 0.f);
}

__global__ void k_mean(const float* __restrict__ coords, float* __restrict__ mean) {
    __shared__ float sm[1024];
    int bd = blockIdx.x;          // b*3+d, 0..11
    int tid = threadIdx.x;
    const float* p = coords + (size_t)bd * NPT;
    float s = 0.f;
    for (int n = tid; n < NPT; n += 1024) s += p[n];
    sm[tid] = s; __syncthreads();
    for (int st = 512; st > 0; st >>= 1) {
        if (tid < st) sm[tid] += sm[tid + st];
        __syncthreads();
    }
    if (tid == 0) mean[bd] = sm[0] * (1.0f / NPT);
}

__global__ void k_maxn(const float* __restrict__ coords, const float* __restrict__ mean,
                       float* __restrict__ maxn) {
    __shared__ float sm[1024];
    int b = blockIdx.x; int tid = threadIdx.x;
    float m0 = mean[b * 3], m1 = mean[b * 3 + 1], m2 = mean[b * 3 + 2];
    const float* p0 = coords + (size_t)(b * 3) * NPT;
    float mx = 0.f;
    for (int n = tid; n < NPT; n += 1024) {
        float dx = p0[n] - m0, dy = p0[NPT + n] - m1, dz = p0[2 * NPT + n] - m2;
        mx = fmaxf(mx, dx * dx + dy * dy + dz * dz);
    }
    sm[tid] = mx; __syncthreads();
    for (int st = 512; st > 0; st >>= 1) {
        if (tid < st) sm[tid] = fmaxf(sm[tid], sm[tid + st]);
        __syncthreads();
    }
    if (tid == 0) maxn[b] = sqrtf(sm[0]);
}

__global__ void k_scatter(const float* __restrict__ coords, const float* __restrict__ feats,
                          const float* __restrict__ mean, const float* __restrict__ maxn,
                          float4* __restrict__ cbuf, float* __restrict__ cnt,
                          float* __restrict__ ga) {
    int gid = blockIdx.x * 256 + threadIdx.x;   // < 262144
    int b = gid >> 16, n = gid & 65535;
    float inv = 0.5f / maxn[b];
    float c0 = (coords[(size_t)(b * 3) * NPT + n]     - mean[b * 3])     * inv + 0.5f;
    float c1 = (coords[(size_t)(b * 3 + 1) * NPT + n] - mean[b * 3 + 1]) * inv + 0.5f;
    float c2 = (coords[(size_t)(b * 3 + 2) * NPT + n] - mean[b * 3 + 2]) * inv + 0.5f;
    c0 = fminf(fmaxf(c0 * 32.f, 0.f), 31.f);
    c1 = fminf(fmaxf(c1 * 32.f, 0.f), 31.f);
    c2 = fminf(fmaxf(c2 * 32.f, 0.f), 31.f);
    cbuf[gid] = make_float4(c0, c1, c2, 0.f);
    int v0 = (int)rintf(c0), v1 = (int)rintf(c1), v2 = (int)rintf(c2);
    int vx = b * R3 + (v0 * 1024 + v1 * 32 + v2);
    atomicAdd(&cnt[vx], 1.0f);
    float* gp = ga + ((size_t)vx << 6);
    const float* fp = feats + (size_t)(b * 64) * NPT + n;
    for (int ch = 0; ch < 64; ch++) atomicAdd(&gp[ch], fp[(size_t)ch * NPT]);
}

__global__ void k_avg(float* __restrict__ ga, const float* __restrict__ cnt) {
    int gid = blockIdx.x * 256 + threadIdx.x;   // < 8388608
    int bv = gid >> 6;
    ga[gid] *= (1.0f / fmaxf(cnt[bv], 1.0f));
}

// in/out: [B][R3][64] channel-last. weights [27][64][64] ([tap][in][out], BN-folded).
// out = relu(conv(in) + bias (+ idn)). idn read only at the written voxel -> in-place-safe.
__global__ __launch_bounds__(256) void k_conv(const float* __restrict__ in,
        const float* __restrict__ w, const float* __restrict__ bias,
        const float* __restrict__ idn, float* __restrict__ out) {
    int tid = threadIdx.x;
    int v = tid & 63;
    int g = tid >> 6;
    int o0 = g << 4;
    int tile = blockIdx.x;
    int b = blockIdx.y;
    int x = ((tile >> 6) << 2) + (v >> 4);
    int y = (((tile >> 3) & 7) << 2) + ((v >> 2) & 3);
    int z = ((tile & 7) << 2) + (v & 3);
    float acc[16];
    const float* bp = bias + o0;
    #pragma unroll
    for (int j = 0; j < 16; j++) acc[j] = bp[j];
    #pragma unroll 1
    for (int t = 0; t < 27; t++) {
        int dx = t / 9 - 1, dy = (t / 3) % 3 - 1, dz = t % 3 - 1;
        int xx = x + dx, yy = y + dy, zz = z + dz;
        if ((unsigned)xx < 32u && (unsigned)yy < 32u && (unsigned)zz < 32u) {
            const float* ip = in + (((size_t)(b * R3) + (xx << 10) + (yy << 5) + zz) << 6);
            const float* wp = w + t * 4096 + o0;
            #pragma unroll 2
            for (int i = 0; i < 64; i += 4) {
                float4 iv = *(const float4*)(ip + i);
                const float* w0 = wp + (i << 6);
                float vals[4] = {iv.x, iv.y, iv.z, iv.w};
                #pragma unroll
                for (int s = 0; s < 4; s++) {
                    float4 w_0 = *(const float4*)(w0 + (s << 6));
                    float4 w_1 = *(const float4*)(w0 + (s << 6) + 4);
                    float4 w_2 = *(const float4*)(w0 + (s << 6) + 8);
                    float4 w_3 = *(const float4*)(w0 + (s << 6) + 12);
                    float val = vals[s];
                    acc[0]  += val * w_0.x; acc[1]  += val * w_0.y;
                    acc[2]  += val * w_0.z; acc[3]  += val * w_0.w;
                    acc[4]  += val * w_1.x; acc[5]  += val * w_1.y;
                    acc[6]  += val * w_1.z; acc[7]  += val * w_1.w;
                    acc[8]  += val * w_2.x; acc[9]  += val * w_2.y;
                    acc[10] += val * w_2.z; acc[11] += val * w_2.w;
                    acc[12] += val * w_3.x; acc[13] += val * w_3.y;
                    acc[14] += val * w_3.z; acc[15] += val * w_3.w;
                }
            }
        }
    }
    size_t ob = (((size_t)(b * R3) + (x << 10) + (y << 5) + z) << 6) + o0;
    if (idn != nullptr) {
        #pragma unroll
        for (int j = 0; j < 16; j += 4) {
            float4 dv = *(const float4*)(idn + ob + j);
            acc[j] += dv.x; acc[j + 1] += dv.y; acc[j + 2] += dv.z; acc[j + 3] += dv.w;
        }
    }
    #pragma unroll
    for (int j = 0; j < 16; j += 4) {
        float4 ov = make_float4(fmaxf(acc[j], 0.f), fmaxf(acc[j + 1], 0.f),
                                fmaxf(acc[j + 2], 0.f), fmaxf(acc[j + 3], 0.f));
        *(float4*)(out + ob + j) = ov;
    }
}

// devox gather + point MLP + collapsed attention + fuse. 64 points x 4 channel-groups per block.
__global__ __launch_bounds__(256) void k_final(const float* __restrict__ feats,
        const float4* __restrict__ cbuf, const float* __restrict__ gb,
        const float* __restrict__ ws, float* __restrict__ out) {
    __shared__ float sq[256];
    int tid = threadIdx.x;
    int l = tid & 63;
    int g = tid >> 6;
    int o0 = g << 4;
    int b = blockIdx.y;
    int n = (blockIdx.x << 6) + l;
    int gid = (b << 16) + n;
    float4 c4 = cbuf[gid];
    int lx = (int)floorf(c4.x), ly = (int)floorf(c4.y), lz = (int)floorf(c4.z);
    int hx = min(lx + 1, 31), hy = min(ly + 1, 31), hz = min(lz + 1, 31);
    float fx = c4.x - (float)lx, fy = c4.y - (float)ly, fz = c4.z - (float)lz;
    int xs[2] = {lx, hx}; float wxx[2] = {1.f - fx, fx};
    int ys[2] = {ly, hy}; float wyy[2] = {1.f - fy, fy};
    int zs[2] = {lz, hz}; float wzz[2] = {1.f - fz, fz};
    float vf[16];
    #pragma unroll
    for (int j = 0; j < 16; j++) vf[j] = 0.f;
    #pragma unroll
    for (int ii = 0; ii < 2; ii++)
    #pragma unroll
    for (int jj = 0; jj < 2; jj++)
    #pragma unroll
    for (int kk = 0; kk < 2; kk++) {
        float wgt = wxx[ii] * wyy[jj] * wzz[kk];
        const float* gp = gb + (((size_t)(b * R3) + (xs[ii] << 10) + (ys[jj] << 5) + zs[kk]) << 6) + o0;
        #pragma unroll
        for (int j = 0; j < 16; j += 4) {
            float4 gv = *(const float4*)(gp + j);
            vf[j]     += wgt * gv.x; vf[j + 1] += wgt * gv.y;
            vf[j + 2] += wgt * gv.z; vf[j + 3] += wgt * gv.w;
        }
    }
    // point branch: pfeat = relu(PW^T * feat + PB)
    float pf[16];
    const float* pb = ws + OFF_PB + o0;
    #pragma unroll
    for (int j = 0; j < 16; j++) pf[j] = pb[j];
    const float* pw = ws + OFF_PW + o0;
    const float* fp = feats + (size_t)(b * 64) * NPT + n;
    #pragma unroll 4
    for (int i = 0; i < 64; i++) {
        float fv = fp[(size_t)i * NPT];
        float4 w_0 = *(const float4*)(pw + (i << 6));
        float4 w_1 = *(const float4*)(pw + (i << 6) + 4);
        float4 w_2 = *(const float4*)(pw + (i << 6) + 8);
        float4 w_3 = *(const float4*)(pw + (i << 6) + 12);
        pf[0]  += fv * w_0.x; pf[1]  += fv * w_0.y; pf[2]  += fv * w_0.z; pf[3]  += fv * w_0.w;
        pf[4]  += fv * w_1.x; pf[5]  += fv * w_1.y; pf[6]  += fv * w_1.z; pf[7]  += fv * w_1.w;
        pf[8]  += fv * w_2.x; pf[9]  += fv * w_2.y; pf[10] += fv * w_2.z; pf[11] += fv * w_2.w;
        pf[12] += fv * w_3.x; pf[13] += fv * w_3.y; pf[14] += fv * w_3.z; pf[15] += fv * w_3.w;
    }
    #pragma unroll
    for (int j = 0; j < 16; j++) pf[j] = fmaxf(pf[j], 0.f);
    // collapsed attention: q = WAE.vfeat + WBE.pfeat + q0
    const float* wae = ws + OFF_WAE + o0;
    const float* wbe = ws + OFF_WBE + o0;
    float part = 0.f;
    #pragma unroll
    for (int j = 0; j < 16; j++) part += wae[j] * vf[j] + wbe[j] * pf[j];
    sq[tid] = part;
    __syncthreads();
    float q = sq[l] + sq[l + 64] + sq[l + 128] + sq[l + 192] + ws[OFF_Q0];
    float attn = 1.0f + 1.0f / (1.0f + expf(-q));
    float* op = out + (size_t)(b * 64 + o0) * NPT + n;
    #pragma unroll
    for (int j = 0; j < 16; j++) op[(size_t)j * NPT] = vf[j] * attn + pf[j];
}

extern "C" void kernel_launch(void* const* d_in, const int* in_sizes, int n_in,
                              void* d_out, int out_size, void* d_ws, size_t ws_size,
                              hipStream_t stream) {
    const float* features = (const float*)d_in[0];
    const float* coords   = (const float*)d_in[1];
    const float* vconv_w  = (const float*)d_in[2];
    const float* vconv_b  = (const float*)d_in[3];
    const float* vbn_g    = (const float*)d_in[4];
    const float* vbn_b    = (const float*)d_in[5];
    const float* res_w    = (const float*)d_in[6];
    const float* res_b    = (const float*)d_in[7];
    const float* res_bn_g = (const float*)d_in[8];
    const float* res_bn_b = (const float*)d_in[9];
    const float* pf_w     = (const float*)d_in[10];
    const float* pf_b     = (const float*)d_in[11];
    const float* pf_bn_g  = (const float*)d_in[12];
    const float* pf_bn_b  = (const float*)d_in[13];
    const float* attn_wa  = (const float*)d_in[14];
    const float* attn_ba  = (const float*)d_in[15];
    const float* attn_wb  = (const float*)d_in[16];
    const float* attn_bb  = (const float*)d_in[17];
    const float* attn_wc  = (const float*)d_in[18];
    const float* attn_bc  = (const float*)d_in[19];
    float* ws  = (float*)d_ws;
    float* out = (float*)d_out;

    k_fold_w<<<2160, 256, 0, stream>>>(vconv_w, vbn_g, res_w, res_bn_g, ws + OFF_WEFF);
    k_misc<<<19, 256, 0, stream>>>(vconv_b, vbn_g, vbn_b, res_b, res_bn_g, res_bn_b,
                                   pf_w, pf_b, pf_bn_g, pf_bn_b,
                                   attn_wa, attn_ba, attn_wb, attn_bb, attn_wc, attn_bc, ws);
    k_zero<<<8320, 256, 0, stream>>>((float4*)(ws + OFF_CNT), 2129920);
    k_mean<<<12, 1024, 0, stream>>>(coords, ws + OFF_MEAN);
    k_maxn<<<4, 1024, 0, stream>>>(coords, ws + OFF_MEAN, ws + OFF_MAXN);
    k_scatter<<<1024, 256, 0, stream>>>(coords, features, ws + OFF_MEAN, ws + OFF_MAXN,
                                        (float4*)(ws + OFF_CBUF), ws + OFF_CNT, ws + OFF_GA);
    k_avg<<<32768, 256, 0, stream>>>(ws + OFF_GA, ws + OFF_CNT);

    float* GA = ws + OFF_GA;
    float* GB = ws + OFF_GB;
    const float* W  = ws + OFF_WEFF;
    const float* Bv = ws + OFF_BEFF;
    dim3 cg(512, 4);
    k_conv<<<cg, 256, 0, stream>>>(GA, W + 0 * 110592, Bv + 0,   nullptr, GB);  // BasicConvBlock
    k_conv<<<cg, 256, 0, stream>>>(GB, W + 1 * 110592, Bv + 64,  nullptr, GA);  // res0 conv0
    k_conv<<<cg, 256, 0, stream>>>(GA, W + 2 * 110592, Bv + 128, GB,      GB);  // res0 conv1 + id
    k_conv<<<cg, 256, 0, stream>>>(GB, W + 3 * 110592, Bv + 192, nullptr, GA);  // res1 conv0
    k_conv<<<cg, 256, 0, stream>>>(GA, W + 4 * 110592, Bv + 256, GB,      GB);  // res1 conv1 + id

    dim3 fg(1024, 4);
    k_final<<<fg, 256, 0, stream>>>(features, (const float4*)(ws + OFF_CBUF), GB, ws, out);
}

// Round 2
// 1594.077 us; speedup vs baseline: 7.4557x; 7.4557x over previous
//
#include <hip/hip_runtime.h>
#include <math.h>

#define NPT 65536
#define NB 4
#define R3 32768

typedef __attribute__((ext_vector_type(8))) short short8;
typedef __attribute__((ext_vector_type(16))) float f32x16;

// ws layout (float offsets)
#define OFF_WB16 0          // 552960 bf16 = 276480 floats: 5 layers, B-frag order [t][ks][nh][lane][j]
#define OFF_BEFF 276480     // 5*64
#define OFF_PW   276800     // 64*64
#define OFF_PB   280896     // 64
#define OFF_WAE  280960     // 64
#define OFF_WBE  281024     // 64
#define OFF_Q0   281088     // 1 (+pad)
#define OFF_MEAN 281104     // 12
#define OFF_MAXN 281116     // 4
#define OFF_CBUF 281120     // 1048576 (float4 coords)
#define OFF_CNT  1329696    // 131072 voxel counts (contiguous with GA -> one zero pass)
#define OFF_GA   1460768    // 8388608 fp32 scatter grid; reused as fp32 residual buffer F
#define OFF_G0   9849376    // 4194304 floats = 8388608 bf16, swizzled grid ping
#define OFF_G1   14043680   // 4194304 floats = 8388608 bf16, swizzled grid pong

__device__ __forceinline__ unsigned short f2b(float f) {
    union { float f; unsigned int u; } v; v.f = f;
    unsigned int r = v.u + 0x7fffu + ((v.u >> 16) & 1u);
    return (unsigned short)(r >> 16);
}
__device__ __forceinline__ float b2f(unsigned short u) {
    union { unsigned int u; float f; } v; v.u = ((unsigned int)u) << 16; return v.f;
}

// Fold BN into conv weights, write bf16 in MFMA B-fragment order:
// flat = ((((layer*27+t)*4+ks)*2+nh)*64+lane)*8+j ; i = ks*16+(lane>>5)*8+j ; o = nh*32+(lane&31)
__global__ void k_fold_w(const float* __restrict__ vconv_w, const float* __restrict__ vbn_g,
                         const float* __restrict__ res_w, const float* __restrict__ res_bn_g,
                         unsigned short* __restrict__ wb16) {
    int idx = blockIdx.x * 256 + threadIdx.x;
    if (idx >= 5 * 27 * 4 * 2 * 64 * 8) return;
    int j = idx & 7;
    int l = (idx >> 3) & 63;
    int nh = (idx >> 9) & 1;
    int ks = (idx >> 10) & 3;
    int rest = idx >> 12;          // layer*27 + t
    int t = rest % 27;
    int layer = rest / 27;
    int i = ks * 16 + ((l >> 5) << 3) + j;
    int o = nh * 32 + (l & 31);
    const float invs = rsqrtf(1.00001f);
    float scale, wsrc;
    if (layer == 0) {
        scale = vbn_g[o] * invs;
        wsrc = vconv_w[(o * 64 + i) * 27 + t];
    } else {
        scale = res_bn_g[(layer - 1) * 64 + o] * invs;
        wsrc = res_w[(size_t)(layer - 1) * 110592 + (o * 64 + i) * 27 + t];
    }
    wb16[idx] = f2b(wsrc * scale);
}

__global__ void k_misc(const float* __restrict__ vconv_b, const float* __restrict__ vbn_g,
                       const float* __restrict__ vbn_b,
                       const float* __restrict__ res_b, const float* __restrict__ res_bn_g,
                       const float* __restrict__ res_bn_b,
                       const float* __restrict__ pf_w, const float* __restrict__ pf_b,
                       const float* __restrict__ pf_bn_g, const float* __restrict__ pf_bn_b,
                       const float* __restrict__ wa, const float* __restrict__ ba,
                       const float* __restrict__ wb, const float* __restrict__ bb,
                       const float* __restrict__ wc, const float* __restrict__ bc,
                       float* __restrict__ ws) {
    int idx = blockIdx.x * 256 + threadIdx.x;
    const float invs = rsqrtf(1.00001f);
    if (idx < 320) {
        int l = idx >> 6, o = idx & 63;
        float b_, g_, s_;
        if (l == 0) { b_ = vconv_b[o]; g_ = vbn_g[o]; s_ = vbn_b[o]; }
        else {
            b_ = res_b[(l - 1) * 64 + o];
            g_ = res_bn_g[(l - 1) * 64 + o];
            s_ = res_bn_b[(l - 1) * 64 + o];
        }
        ws[OFF_BEFF + idx] = b_ * g_ * invs + s_;
    } else if (idx < 4416) {
        int j = idx - 320; int o = j & 63; int i = j >> 6;
        ws[OFF_PW + j] = pf_w[o * 64 + i] * pf_bn_g[o] * invs;
    } else if (idx < 4480) {
        int o = idx - 4416;
        ws[OFF_PB + o] = pf_b[o] * pf_bn_g[o] * invs + pf_bn_b[o];
    } else if (idx < 4544) {
        int o = idx - 4480;
        float s = 0.f;
        for (int j = 0; j < 16; j++) s += wc[j] * wa[j * 64 + o];
        ws[OFF_WAE + o] = s;
    } else if (idx < 4608) {
        int o = idx - 4544;
        float s = 0.f;
        for (int j = 0; j < 16; j++) s += wc[16 + j] * wb[j * 64 + o];
        ws[OFF_WBE + o] = s;
    } else if (idx == 4608) {
        float s = bc[0];
        for (int j = 0; j < 16; j++) s += wc[j] * ba[j] + wc[16 + j] * bb[j];
        ws[OFF_Q0] = s;
    }
}

__global__ void k_zero(float4* __restrict__ p, int n4) {
    int i = blockIdx.x * 256 + threadIdx.x;
    if (i < n4) p[i] = make_float4(0.f, 0.f, 0.f, 0.f);
}

__global__ void k_mean(const float* __restrict__ coords, float* __restrict__ mean) {
    __shared__ float sm[1024];
    int bd = blockIdx.x;
    int tid = threadIdx.x;
    const float* p = coords + (size_t)bd * NPT;
    float s = 0.f;
    for (int n = tid; n < NPT; n += 1024) s += p[n];
    sm[tid] = s; __syncthreads();
    for (int st = 512; st > 0; st >>= 1) {
        if (tid < st) sm[tid] += sm[tid + st];
        __syncthreads();
    }
    if (tid == 0) mean[bd] = sm[0] * (1.0f / NPT);
}

__global__ void k_maxn(const float* __restrict__ coords, const float* __restrict__ mean,
                       float* __restrict__ maxn) {
    __shared__ float sm[1024];
    int b = blockIdx.x; int tid = threadIdx.x;
    float m0 = mean[b * 3], m1 = mean[b * 3 + 1], m2 = mean[b * 3 + 2];
    const float* p0 = coords + (size_t)(b * 3) * NPT;
    float mx = 0.f;
    for (int n = tid; n < NPT; n += 1024) {
        float dx = p0[n] - m0, dy = p0[NPT + n] - m1, dz = p0[2 * NPT + n] - m2;
        mx = fmaxf(mx, dx * dx + dy * dy + dz * dz);
    }
    sm[tid] = mx; __syncthreads();
    for (int st = 512; st > 0; st >>= 1) {
        if (tid < st) sm[tid] = fmaxf(sm[tid], sm[tid + st]);
        __syncthreads();
    }
    if (tid == 0) maxn[b] = sqrtf(sm[0]);
}

__global__ void k_scatter(const float* __restrict__ coords, const float* __restrict__ feats,
                          const float* __restrict__ mean, const float* __restrict__ maxn,
                          float4* __restrict__ cbuf, float* __restrict__ cnt,
                          float* __restrict__ ga) {
    int gid = blockIdx.x * 256 + threadIdx.x;
    int b = gid >> 16, n = gid & 65535;
    float inv = 0.5f / maxn[b];
    float c0 = (coords[(size_t)(b * 3) * NPT + n]     - mean[b * 3])     * inv + 0.5f;
    float c1 = (coords[(size_t)(b * 3 + 1) * NPT + n] - mean[b * 3 + 1]) * inv + 0.5f;
    float c2 = (coords[(size_t)(b * 3 + 2) * NPT + n] - mean[b * 3 + 2]) * inv + 0.5f;
    c0 = fminf(fmaxf(c0 * 32.f, 0.f), 31.f);
    c1 = fminf(fmaxf(c1 * 32.f, 0.f), 31.f);
    c2 = fminf(fmaxf(c2 * 32.f, 0.f), 31.f);
    cbuf[gid] = make_float4(c0, c1, c2, 0.f);
    int v0 = (int)rintf(c0), v1 = (int)rintf(c1), v2 = (int)rintf(c2);
    int vx = b * R3 + (v0 * 1024 + v1 * 32 + v2);
    atomicAdd(&cnt[vx], 1.0f);
    float* gp = ga + ((size_t)vx << 6);
    const float* fp = feats + (size_t)(b * 64) * NPT + n;
    for (int ch = 0; ch < 64; ch++) atomicAdd(&gp[ch], fp[(size_t)ch * NPT]);
}

// average + convert to bf16 swizzled layout: elem = col*2048 + kk*256 + z*8 + c  (col=b*1024+x*32+y)
__global__ void k_avg_cvt(const float* __restrict__ ga, const float* __restrict__ cnt,
                          unsigned short* __restrict__ g0) {
    int gid = blockIdx.x * 256 + threadIdx.x;      // < 1048576 ; gid = col*256 + kk*32 + z
    int z = gid & 31, kk = (gid >> 5) & 7, col = gid >> 8;
    int vx = (col << 5) + z;
    float inv = 1.0f / fmaxf(cnt[vx], 1.0f);
    const float4* src = (const float4*)(ga + ((size_t)vx << 6) + (kk << 3));
    float4 a = src[0], b = src[1];
    short8 sv;
    sv[0] = (short)f2b(a.x * inv); sv[1] = (short)f2b(a.y * inv);
    sv[2] = (short)f2b(a.z * inv); sv[3] = (short)f2b(a.w * inv);
    sv[4] = (short)f2b(b.x * inv); sv[5] = (short)f2b(b.y * inv);
    sv[6] = (short)f2b(b.z * inv); sv[7] = (short)f2b(b.w * inv);
    *(short8*)(g0 + ((size_t)gid << 3)) = sv;
}

// MFMA implicit-GEMM 3^3 conv. in/out: bf16 swizzled grid. 4 waves: 2 z-columns x 2 out-ch halves.
// idF/outF: optional fp32 residual side-buffer (same swizzled indexing).
__global__ __launch_bounds__(256) void k_conv(const unsigned short* __restrict__ in,
        const unsigned short* __restrict__ w, const float* __restrict__ bias,
        const float* __restrict__ idF, float* __restrict__ outF,
        unsigned short* __restrict__ out) {
    __shared__ unsigned short sA[12 * 2048];    // 48 KB: 12 columns x [kk(8)][z(32)][8ch]
    int tid = threadIdx.x;
    int lane = tid & 63;
    int wid = tid >> 6;
    int colsel = wid & 1;
    int nh = wid >> 1;
    int tile = blockIdx.x;
    int b = blockIdx.y;
    int x = tile >> 4;
    int y0 = (tile & 15) << 1;
    // stage 12 input columns (4KB each; thread t copies 16B of each)
    for (int s = 0; s < 12; s++) {
        int gx = x + (s >> 2) - 1;
        int gy = y0 + (s & 3) - 1;
        float4 v = make_float4(0.f, 0.f, 0.f, 0.f);
        if ((unsigned)gx < 32u && (unsigned)gy < 32u) {
            const float4* src = (const float4*)(in + (((size_t)b * 1024 + gx * 32 + gy) << 11));
            v = src[tid];
        }
        ((float4*)(sA + s * 2048))[tid] = v;
    }
    __syncthreads();
    f32x16 acc = {};
    const short8 zero8 = {0, 0, 0, 0, 0, 0, 0, 0};
    int half = lane >> 5;
    #pragma unroll 1
    for (int t = 0; t < 27; t++) {
        int dxi = t / 9, dyi = (t / 3) % 3, dz = t % 3 - 1;
        int s = dxi * 4 + dyi + colsel;
        int zz = (lane & 31) + dz;
        bool zv = (unsigned)zz < 32u;
        int zc = zv ? zz : 0;
        const unsigned short* ac = sA + s * 2048 + (half << 8) + zc * 8;
        const unsigned short* wp = w + t * 4096 + nh * 512 + lane * 8;
        #pragma unroll
        for (int ks = 0; ks < 4; ks++) {
            short8 af = *(const short8*)(ac + ks * 512);
            if (!zv) af = zero8;
            short8 bf = *(const short8*)(wp + ks * 1024);
            acc = __builtin_amdgcn_mfma_f32_32x32x16_bf16(af, bf, acc, 0, 0, 0);
        }
    }
    // epilogue: C layout col(n)=lane&31, row(z)=(r&3)+8*(r>>2)+4*(lane>>5)
    int o = nh * 32 + (lane & 31);
    float bb = bias[o];
    int outcol = b * 1024 + x * 32 + (y0 + colsel);
    size_t obase = ((size_t)outcol << 11) + (size_t)((o >> 3) << 8) + (o & 7);
    #pragma unroll
    for (int r = 0; r < 16; r++) {
        int z = (r & 3) + ((r >> 2) << 3) + ((lane >> 5) << 2);
        size_t oe = obase + (size_t)z * 8;
        float v = acc[r] + bb;
        if (idF) v += idF[oe];
        v = fmaxf(v, 0.f);
        out[oe] = f2b(v);
        if (outF) outF[oe] = v;
    }
}

// devox gather (bf16 swizzled grid) + point MLP + collapsed attention + fuse.
__global__ __launch_bounds__(256) void k_final(const float* __restrict__ feats,
        const float4* __restrict__ cbuf, const unsigned short* __restrict__ gb,
        const float* __restrict__ ws, float* __restrict__ out) {
    __shared__ float sq[256];
    int tid = threadIdx.x;
    int l = tid & 63;
    int g = tid >> 6;
    int o0 = g << 4;
    int b = blockIdx.y;
    int n = (blockIdx.x << 6) + l;
    int gid = (b << 16) + n;
    float4 c4 = cbuf[gid];
    int lx = (int)floorf(c4.x), ly = (int)floorf(c4.y), lz = (int)floorf(c4.z);
    int hx = min(lx + 1, 31), hy = min(ly + 1, 31), hz = min(lz + 1, 31);
    float fx = c4.x - (float)lx, fy = c4.y - (float)ly, fz = c4.z - (float)lz;
    int xs[2] = {lx, hx}; float wxx[2] = {1.f - fx, fx};
    int ys[2] = {ly, hy}; float wyy[2] = {1.f - fy, fy};
    int zs[2] = {lz, hz}; float wzz[2] = {1.f - fz, fz};
    float vf[16];
    #pragma unroll
    for (int j = 0; j < 16; j++) vf[j] = 0.f;
    #pragma unroll
    for (int ii = 0; ii < 2; ii++)
    #pragma unroll
    for (int jj = 0; jj < 2; jj++)
    #pragma unroll
    for (int kk = 0; kk < 2; kk++) {
        float wgt = wxx[ii] * wyy[jj] * wzz[kk];
        const unsigned short* gp = gb + (((size_t)b * 1024 + xs[ii] * 32 + ys[jj]) << 11)
                                      + ((size_t)g << 9) + zs[kk] * 8;
        short8 v0 = *(const short8*)(gp);
        short8 v1 = *(const short8*)(gp + 256);
        #pragma unroll
        for (int j = 0; j < 8; j++) {
            vf[j]     += wgt * b2f((unsigned short)v0[j]);
            vf[8 + j] += wgt * b2f((unsigned short)v1[j]);
        }
    }
    // point branch: pfeat = relu(PW^T * feat + PB)
    float pf[16];
    const float* pb = ws + OFF_PB + o0;
    #pragma unroll
    for (int j = 0; j < 16; j++) pf[j] = pb[j];
    const float* pw = ws + OFF_PW + o0;
    const float* fp = feats + (size_t)(b * 64) * NPT + n;
    #pragma unroll 4
    for (int i = 0; i < 64; i++) {
        float fv = fp[(size_t)i * NPT];
        float4 w_0 = *(const float4*)(pw + (i << 6));
        float4 w_1 = *(const float4*)(pw + (i << 6) + 4);
        float4 w_2 = *(const float4*)(pw + (i << 6) + 8);
        float4 w_3 = *(const float4*)(pw + (i << 6) + 12);
        pf[0]  += fv * w_0.x; pf[1]  += fv * w_0.y; pf[2]  += fv * w_0.z; pf[3]  += fv * w_0.w;
        pf[4]  += fv * w_1.x; pf[5]  += fv * w_1.y; pf[6]  += fv * w_1.z; pf[7]  += fv * w_1.w;
        pf[8]  += fv * w_2.x; pf[9]  += fv * w_2.y; pf[10] += fv * w_2.z; pf[11] += fv * w_2.w;
        pf[12] += fv * w_3.x; pf[13] += fv * w_3.y; pf[14] += fv * w_3.z; pf[15] += fv * w_3.w;
    }
    #pragma unroll
    for (int j = 0; j < 16; j++) pf[j] = fmaxf(pf[j], 0.f);
    // collapsed attention: q = WAE.vfeat + WBE.pfeat + q0
    const float* wae = ws + OFF_WAE + o0;
    const float* wbe = ws + OFF_WBE + o0;
    float part = 0.f;
    #pragma unroll
    for (int j = 0; j < 16; j++) part += wae[j] * vf[j] + wbe[j] * pf[j];
    sq[tid] = part;
    __syncthreads();
    float q = sq[l] + sq[l + 64] + sq[l + 128] + sq[l + 192] + ws[OFF_Q0];
    float attn = 1.0f + 1.0f / (1.0f + expf(-q));
    float* op = out + (size_t)(b * 64 + o0) * NPT + n;
    #pragma unroll
    for (int j = 0; j < 16; j++) op[(size_t)j * NPT] = vf[j] * attn + pf[j];
}

extern "C" void kernel_launch(void* const* d_in, const int* in_sizes, int n_in,
                              void* d_out, int out_size, void* d_ws, size_t ws_size,
                              hipStream_t stream) {
    const float* features = (const float*)d_in[0];
    const float* coords   = (const float*)d_in[1];
    const float* vconv_w  = (const float*)d_in[2];
    const float* vconv_b  = (const float*)d_in[3];
    const float* vbn_g    = (const float*)d_in[4];
    const float* vbn_b    = (const float*)d_in[5];
    const float* res_w    = (const float*)d_in[6];
    const float* res_b    = (const float*)d_in[7];
    const float* res_bn_g = (const float*)d_in[8];
    const float* res_bn_b = (const float*)d_in[9];
    const float* pf_w     = (const float*)d_in[10];
    const float* pf_b     = (const float*)d_in[11];
    const float* pf_bn_g  = (const float*)d_in[12];
    const float* pf_bn_b  = (const float*)d_in[13];
    const float* attn_wa  = (const float*)d_in[14];
    const float* attn_ba  = (const float*)d_in[15];
    const float* attn_wb  = (const float*)d_in[16];
    const float* attn_bb  = (const float*)d_in[17];
    const float* attn_wc  = (const float*)d_in[18];
    const float* attn_bc  = (const float*)d_in[19];
    float* ws  = (float*)d_ws;
    float* out = (float*)d_out;

    unsigned short* WB = (unsigned short*)(ws + OFF_WB16);
    unsigned short* G0 = (unsigned short*)(ws + OFF_G0);
    unsigned short* G1 = (unsigned short*)(ws + OFF_G1);
    float* GA = ws + OFF_GA;     // scatter accum, later fp32 residual buffer
    const float* Bv = ws + OFF_BEFF;

    k_fold_w<<<2160, 256, 0, stream>>>(vconv_w, vbn_g, res_w, res_bn_g, WB);
    k_misc<<<19, 256, 0, stream>>>(vconv_b, vbn_g, vbn_b, res_b, res_bn_g, res_bn_b,
                                   pf_w, pf_b, pf_bn_g, pf_bn_b,
                                   attn_wa, attn_ba, attn_wb, attn_bb, attn_wc, attn_bc, ws);
    k_zero<<<8320, 256, 0, stream>>>((float4*)(ws + OFF_CNT), 2129920);
    k_mean<<<12, 1024, 0, stream>>>(coords, ws + OFF_MEAN);
    k_maxn<<<4, 1024, 0, stream>>>(coords, ws + OFF_MEAN, ws + OFF_MAXN);
    k_scatter<<<1024, 256, 0, stream>>>(coords, features, ws + OFF_MEAN, ws + OFF_MAXN,
                                        (float4*)(ws + OFF_CBUF), ws + OFF_CNT, GA);
    k_avg_cvt<<<4096, 256, 0, stream>>>(GA, ws + OFF_CNT, G0);

    // L0: x1 = relu(bn(conv(g0)))            G0 -> G1, write F(=GA)
    // L1: t  = relu(bn(conv(x1)))            G1 -> G0
    // L2: x2 = relu(bn(conv(t)) + x1)        G0 -> G1, read F, write F
    // L3: u  = relu(bn(conv(x2)))            G1 -> G0
    // L4: x3 = relu(bn(conv(u)) + x2)        G0 -> G1, read F
    dim3 cg(512, 4);
    k_conv<<<cg, 256, 0, stream>>>(G0, WB + 0 * 110592, Bv + 0,   nullptr, GA,      G1);
    k_conv<<<cg, 256, 0, stream>>>(G1, WB + 1 * 110592, Bv + 64,  nullptr, nullptr, G0);
    k_conv<<<cg, 256, 0, stream>>>(G0, WB + 2 * 110592, Bv + 128, GA,      GA,      G1);
    k_conv<<<cg, 256, 0, stream>>>(G1, WB + 3 * 110592, Bv + 192, nullptr, nullptr, G0);
    k_conv<<<cg, 256, 0, stream>>>(G0, WB + 4 * 110592, Bv + 256, GA,      nullptr, G1);

    dim3 fg(1024, 4);
    k_final<<<fg, 256, 0, stream>>>(features, (const float4*)(ws + OFF_CBUF), G1, ws, out);
}

// Round 3
// 895.885 us; speedup vs baseline: 13.2661x; 1.7793x over previous
//
#include <hip/hip_runtime.h>
#include <math.h>

#define NPT 65536
#define NB 4
#define R3 32768

typedef __attribute__((ext_vector_type(8))) short short8;
typedef __attribute__((ext_vector_type(16))) float f32x16;

// ws layout (float offsets)
#define OFF_WB16 0          // 552960 bf16: 5 layers, B-frag order
#define OFF_BEFF 276480     // 5*64
#define OFF_PW   276800     // 64*64
#define OFF_PB   280896     // 64
#define OFF_WAE  280960     // 64
#define OFF_WBE  281024     // 64
#define OFF_Q0   281088     // 1 (+pad)
#define OFF_MEAN 281104     // 12
#define OFF_MAXN 281116     // 4
#define OFF_CB3  281120     // 786432: 3 floats/point normalized coords
#define OFF_CUR  1067552    // 131072 int: histogram -> start -> end cursor
#define OFF_ORD  1198624    // 131072 floats = 262144 ushort: point-in-batch ids, voxel-sorted
#define OFF_GA   1329696    // 8388608 fp32 residual buffer; bf16 FT [B][N][64] overlays (dead by conv L0)
#define OFF_G0   9718304    // 4194304 floats = 8388608 bf16 swizzled grid ping
#define OFF_G1   13912608   // 4194304 floats = 8388608 bf16 swizzled grid pong

__device__ __forceinline__ unsigned short f2b(float f) {
    union { float f; unsigned int u; } v; v.f = f;
    unsigned int r = v.u + 0x7fffu + ((v.u >> 16) & 1u);
    return (unsigned short)(r >> 16);
}
__device__ __forceinline__ float b2f(unsigned short u) {
    union { unsigned int u; float f; } v; v.u = ((unsigned int)u) << 16; return v.f;
}

__global__ void k_fold_w(const float* __restrict__ vconv_w, const float* __restrict__ vbn_g,
                         const float* __restrict__ res_w, const float* __restrict__ res_bn_g,
                         unsigned short* __restrict__ wb16) {
    int idx = blockIdx.x * 256 + threadIdx.x;
    if (idx >= 5 * 27 * 4 * 2 * 64 * 8) return;
    int j = idx & 7;
    int l = (idx >> 3) & 63;
    int nh = (idx >> 9) & 1;
    int ks = (idx >> 10) & 3;
    int rest = idx >> 12;          // layer*27 + t
    int t = rest % 27;
    int layer = rest / 27;
    int i = ks * 16 + ((l >> 5) << 3) + j;
    int o = nh * 32 + (l & 31);
    const float invs = rsqrtf(1.00001f);
    float scale, wsrc;
    if (layer == 0) {
        scale = vbn_g[o] * invs;
        wsrc = vconv_w[(o * 64 + i) * 27 + t];
    } else {
        scale = res_bn_g[(layer - 1) * 64 + o] * invs;
        wsrc = res_w[(size_t)(layer - 1) * 110592 + (o * 64 + i) * 27 + t];
    }
    wb16[idx] = f2b(wsrc * scale);
}

__global__ void k_misc(const float* __restrict__ vconv_b, const float* __restrict__ vbn_g,
                       const float* __restrict__ vbn_b,
                       const float* __restrict__ res_b, const float* __restrict__ res_bn_g,
                       const float* __restrict__ res_bn_b,
                       const float* __restrict__ pf_w, const float* __restrict__ pf_b,
                       const float* __restrict__ pf_bn_g, const float* __restrict__ pf_bn_b,
                       const float* __restrict__ wa, const float* __restrict__ ba,
                       const float* __restrict__ wb, const float* __restrict__ bb,
                       const float* __restrict__ wc, const float* __restrict__ bc,
                       float* __restrict__ ws) {
    int idx = blockIdx.x * 256 + threadIdx.x;
    const float invs = rsqrtf(1.00001f);
    if (idx < 320) {
        int l = idx >> 6, o = idx & 63;
        float b_, g_, s_;
        if (l == 0) { b_ = vconv_b[o]; g_ = vbn_g[o]; s_ = vbn_b[o]; }
        else {
            b_ = res_b[(l - 1) * 64 + o];
            g_ = res_bn_g[(l - 1) * 64 + o];
            s_ = res_bn_b[(l - 1) * 64 + o];
        }
        ws[OFF_BEFF + idx] = b_ * g_ * invs + s_;
    } else if (idx < 4416) {
        int j = idx - 320; int o = j & 63; int i = j >> 6;
        ws[OFF_PW + j] = pf_w[o * 64 + i] * pf_bn_g[o] * invs;
    } else if (idx < 4480) {
        int o = idx - 4416;
        ws[OFF_PB + o] = pf_b[o] * pf_bn_g[o] * invs + pf_bn_b[o];
    } else if (idx < 4544) {
        int o = idx - 4480;
        float s = 0.f;
        for (int j = 0; j < 16; j++) s += wc[j] * wa[j * 64 + o];
        ws[OFF_WAE + o] = s;
    } else if (idx < 4608) {
        int o = idx - 4544;
        float s = 0.f;
        for (int j = 0; j < 16; j++) s += wc[16 + j] * wb[j * 64 + o];
        ws[OFF_WBE + o] = s;
    } else if (idx == 4608) {
        float s = bc[0];
        for (int j = 0; j < 16; j++) s += wc[j] * ba[j] + wc[16 + j] * bb[j];
        ws[OFF_Q0] = s;
    }
}

__global__ void k_zero(float4* __restrict__ p, int n4) {
    int i = blockIdx.x * 256 + threadIdx.x;
    if (i < n4) p[i] = make_float4(0.f, 0.f, 0.f, 0.f);
}

__global__ void k_mean(const float* __restrict__ coords, float* __restrict__ mean) {
    __shared__ float sm[1024];
    int bd = blockIdx.x;
    int tid = threadIdx.x;
    const float* p = coords + (size_t)bd * NPT;
    float s = 0.f;
    for (int n = tid; n < NPT; n += 1024) s += p[n];
    sm[tid] = s; __syncthreads();
    for (int st = 512; st > 0; st >>= 1) {
        if (tid < st) sm[tid] += sm[tid + st];
        __syncthreads();
    }
    if (tid == 0) mean[bd] = sm[0] * (1.0f / NPT);
}

__global__ void k_maxn(const float* __restrict__ coords, const float* __restrict__ mean,
                       float* __restrict__ maxn) {
    __shared__ float sm[1024];
    int b = blockIdx.x; int tid = threadIdx.x;
    float m0 = mean[b * 3], m1 = mean[b * 3 + 1], m2 = mean[b * 3 + 2];
    const float* p0 = coords + (size_t)(b * 3) * NPT;
    float mx = 0.f;
    for (int n = tid; n < NPT; n += 1024) {
        float dx = p0[n] - m0, dy = p0[NPT + n] - m1, dz = p0[2 * NPT + n] - m2;
        mx = fmaxf(mx, dx * dx + dy * dy + dz * dz);
    }
    sm[tid] = mx; __syncthreads();
    for (int st = 512; st > 0; st >>= 1) {
        if (tid < st) sm[tid] = fmaxf(sm[tid], sm[tid + st]);
        __syncthreads();
    }
    if (tid == 0) maxn[b] = sqrtf(sm[0]);
}

// per-point normalized coords + voxel histogram
__global__ void k_prep(const float* __restrict__ coords, const float* __restrict__ mean,
                       const float* __restrict__ maxn, float* __restrict__ cb3,
                       int* __restrict__ cursor) {
    int gid = blockIdx.x * 256 + threadIdx.x;
    int b = gid >> 16, n = gid & 65535;
    float inv = 0.5f / maxn[b];
    float c0 = (coords[(size_t)(b * 3) * NPT + n]     - mean[b * 3])     * inv + 0.5f;
    float c1 = (coords[(size_t)(b * 3 + 1) * NPT + n] - mean[b * 3 + 1]) * inv + 0.5f;
    float c2 = (coords[(size_t)(b * 3 + 2) * NPT + n] - mean[b * 3 + 2]) * inv + 0.5f;
    c0 = fminf(fmaxf(c0 * 32.f, 0.f), 31.f);
    c1 = fminf(fmaxf(c1 * 32.f, 0.f), 31.f);
    c2 = fminf(fmaxf(c2 * 32.f, 0.f), 31.f);
    cb3[gid * 3]     = c0;
    cb3[gid * 3 + 1] = c1;
    cb3[gid * 3 + 2] = c2;
    int vx = b * R3 + ((int)rintf(c0) * 1024 + (int)rintf(c1) * 32 + (int)rintf(c2));
    atomicAdd(&cursor[vx], 1);
}

// in-place exclusive prefix sum of 131072 bins (1 block x 1024 thr x 128 elems)
__global__ void k_scan(int* __restrict__ cur) {
    __shared__ int sm[1024];
    int t = threadIdx.x;
    int base = t << 7;
    int s = 0;
    for (int j = 0; j < 128; j++) s += cur[base + j];
    sm[t] = s;
    __syncthreads();
    for (int off = 1; off < 1024; off <<= 1) {
        int v = (t >= off) ? sm[t - off] : 0;
        __syncthreads();
        sm[t] += v;
        __syncthreads();
    }
    int run = sm[t] - s;     // exclusive base
    for (int j = 0; j < 128; j++) {
        int c = cur[base + j];
        cur[base + j] = run;
        run += c;
    }
}

// features [B][64][N] fp32 -> FT [B][N][64] bf16 (LDS transpose, 64n x 64ch tiles)
__global__ __launch_bounds__(256) void k_trans(const float* __restrict__ feats,
                                               unsigned short* __restrict__ ft) {
    __shared__ float lds[64][65];
    int b = blockIdx.x >> 10;
    int n0 = (blockIdx.x & 1023) << 6;
    int tid = threadIdx.x;
    int nl = tid & 63;
    #pragma unroll
    for (int it = 0; it < 16; it++) {
        int ch = it * 4 + (tid >> 6);
        lds[nl][ch] = feats[((size_t)(b * 64 + ch) << 16) + n0 + nl];
    }
    __syncthreads();
    int nn = tid >> 2;
    int ch0 = (tid & 3) << 4;
    size_t obase = (((size_t)(b << 16) + n0 + nn) << 6) + ch0;
    short8 v0, v1;
    #pragma unroll
    for (int j = 0; j < 8; j++) v0[j] = (short)f2b(lds[nn][ch0 + j]);
    #pragma unroll
    for (int j = 0; j < 8; j++) v1[j] = (short)f2b(lds[nn][ch0 + 8 + j]);
    *(short8*)(ft + obase) = v0;
    *(short8*)(ft + obase + 8) = v1;
}

// place point ids into voxel-sorted order
__global__ void k_place(const float* __restrict__ cb3, int* __restrict__ cursor,
                        unsigned short* __restrict__ order) {
    int gid = blockIdx.x * 256 + threadIdx.x;
    int b = gid >> 16;
    float c0 = cb3[gid * 3], c1 = cb3[gid * 3 + 1], c2 = cb3[gid * 3 + 2];
    int vx = b * R3 + ((int)rintf(c0) * 1024 + (int)rintf(c1) * 32 + (int)rintf(c2));
    int slot = atomicAdd(&cursor[vx], 1);
    order[slot] = (unsigned short)(gid & 65535);
}

// one wave per voxel: coalesced gather of its points, average, write swizzled bf16 grid
__global__ __launch_bounds__(256) void k_gather(const int* __restrict__ cursor,
        const unsigned short* __restrict__ order, const unsigned short* __restrict__ ft,
        unsigned short* __restrict__ g0) {
    int tid = threadIdx.x;
    int lane = tid & 63;
    int vx = blockIdx.x * 4 + (tid >> 6);
    int e = cursor[vx];
    int s = (vx == 0) ? 0 : cursor[vx - 1];
    int bb = vx >> 15;
    float acc = 0.f;
    for (int p = s; p < e; p++) {
        int n = order[p];
        acc += b2f(ft[(((size_t)(bb << 16) + n) << 6) + lane]);
    }
    float avg = acc / (float)max(e - s, 1);
    int col = vx >> 5, z = vx & 31;
    g0[(size_t)col * 2048 + ((lane >> 3) << 8) + z * 8 + (lane & 7)] = f2b(avg);
}

// MFMA implicit-GEMM 3^3 conv. in/out: bf16 swizzled grid. 4 waves: 2 z-columns x 2 out-ch halves.
__global__ __launch_bounds__(256) void k_conv(const unsigned short* __restrict__ in,
        const unsigned short* __restrict__ w, const float* __restrict__ bias,
        const float* __restrict__ idF, float* __restrict__ outF,
        unsigned short* __restrict__ out) {
    __shared__ unsigned short sA[12 * 2048];    // 48 KB
    int tid = threadIdx.x;
    int lane = tid & 63;
    int wid = tid >> 6;
    int colsel = wid & 1;
    int nh = wid >> 1;
    int tile = blockIdx.x;
    int b = blockIdx.y;
    int x = tile >> 4;
    int y0 = (tile & 15) << 1;
    for (int s = 0; s < 12; s++) {
        int gx = x + (s >> 2) - 1;
        int gy = y0 + (s & 3) - 1;
        float4 v = make_float4(0.f, 0.f, 0.f, 0.f);
        if ((unsigned)gx < 32u && (unsigned)gy < 32u) {
            const float4* src = (const float4*)(in + (((size_t)b * 1024 + gx * 32 + gy) << 11));
            v = src[tid];
        }
        ((float4*)(sA + s * 2048))[tid] = v;
    }
    __syncthreads();
    f32x16 acc = {};
    const short8 zero8 = {0, 0, 0, 0, 0, 0, 0, 0};
    int half = lane >> 5;
    #pragma unroll 1
    for (int t = 0; t < 27; t++) {
        int dxi = t / 9, dyi = (t / 3) % 3, dz = t % 3 - 1;
        int s = dxi * 4 + dyi + colsel;
        int zz = (lane & 31) + dz;
        bool zv = (unsigned)zz < 32u;
        int zc = zv ? zz : 0;
        const unsigned short* ac = sA + s * 2048 + (half << 8) + zc * 8;
        const unsigned short* wp = w + t * 4096 + nh * 512 + lane * 8;
        #pragma unroll
        for (int ks = 0; ks < 4; ks++) {
            short8 af = *(const short8*)(ac + ks * 512);
            if (!zv) af = zero8;
            short8 bf = *(const short8*)(wp + ks * 1024);
            acc = __builtin_amdgcn_mfma_f32_32x32x16_bf16(af, bf, acc, 0, 0, 0);
        }
    }
    int o = nh * 32 + (lane & 31);
    float bb = bias[o];
    int outcol = b * 1024 + x * 32 + (y0 + colsel);
    size_t obase = ((size_t)outcol << 11) + (size_t)((o >> 3) << 8) + (o & 7);
    #pragma unroll
    for (int r = 0; r < 16; r++) {
        int z = (r & 3) + ((r >> 2) << 3) + ((lane >> 5) << 2);
        size_t oe = obase + (size_t)z * 8;
        float v = acc[r] + bb;
        if (idF) v += idF[oe];
        v = fmaxf(v, 0.f);
        out[oe] = f2b(v);
        if (outF) outF[oe] = v;
    }
}

// devox gather (bf16 swizzled grid) + point MLP + collapsed attention + fuse.
__global__ __launch_bounds__(256) void k_final(const float* __restrict__ feats,
        const float* __restrict__ cb3, const unsigned short* __restrict__ gb,
        const float* __restrict__ ws, float* __restrict__ out) {
    __shared__ float sq[256];
    int tid = threadIdx.x;
    int l = tid & 63;
    int g = tid >> 6;
    int o0 = g << 4;
    int b = blockIdx.y;
    int n = (blockIdx.x << 6) + l;
    int gid = (b << 16) + n;
    float c0 = cb3[gid * 3], c1 = cb3[gid * 3 + 1], c2 = cb3[gid * 3 + 2];
    int lx = (int)floorf(c0), ly = (int)floorf(c1), lz = (int)floorf(c2);
    int hx = min(lx + 1, 31), hy = min(ly + 1, 31), hz = min(lz + 1, 31);
    float fx = c0 - (float)lx, fy = c1 - (float)ly, fz = c2 - (float)lz;
    int xs[2] = {lx, hx}; float wxx[2] = {1.f - fx, fx};
    int ys[2] = {ly, hy}; float wyy[2] = {1.f - fy, fy};
    int zs[2] = {lz, hz}; float wzz[2] = {1.f - fz, fz};
    float vf[16];
    #pragma unroll
    for (int j = 0; j < 16; j++) vf[j] = 0.f;
    #pragma unroll
    for (int ii = 0; ii < 2; ii++)
    #pragma unroll
    for (int jj = 0; jj < 2; jj++)
    #pragma unroll
    for (int kk = 0; kk < 2; kk++) {
        float wgt = wxx[ii] * wyy[jj] * wzz[kk];
        const unsigned short* gp = gb + (((size_t)b * 1024 + xs[ii] * 32 + ys[jj]) << 11)
                                      + ((size_t)g << 9) + zs[kk] * 8;
        short8 v0 = *(const short8*)(gp);
        short8 v1 = *(const short8*)(gp + 256);
        #pragma unroll
        for (int j = 0; j < 8; j++) {
            vf[j]     += wgt * b2f((unsigned short)v0[j]);
            vf[8 + j] += wgt * b2f((unsigned short)v1[j]);
        }
    }
    float pf[16];
    const float* pb = ws + OFF_PB + o0;
    #pragma unroll
    for (int j = 0; j < 16; j++) pf[j] = pb[j];
    const float* pw = ws + OFF_PW + o0;
    const float* fp = feats + (size_t)(b * 64) * NPT + n;
    #pragma unroll 4
    for (int i = 0; i < 64; i++) {
        float fv = fp[(size_t)i * NPT];
        float4 w_0 = *(const float4*)(pw + (i << 6));
        float4 w_1 = *(const float4*)(pw + (i << 6) + 4);
        float4 w_2 = *(const float4*)(pw + (i << 6) + 8);
        float4 w_3 = *(const float4*)(pw + (i << 6) + 12);
        pf[0]  += fv * w_0.x; pf[1]  += fv * w_0.y; pf[2]  += fv * w_0.z; pf[3]  += fv * w_0.w;
        pf[4]  += fv * w_1.x; pf[5]  += fv * w_1.y; pf[6]  += fv * w_1.z; pf[7]  += fv * w_1.w;
        pf[8]  += fv * w_2.x; pf[9]  += fv * w_2.y; pf[10] += fv * w_2.z; pf[11] += fv * w_2.w;
        pf[12] += fv * w_3.x; pf[13] += fv * w_3.y; pf[14] += fv * w_3.z; pf[15] += fv * w_3.w;
    }
    #pragma unroll
    for (int j = 0; j < 16; j++) pf[j] = fmaxf(pf[j], 0.f);
    const float* wae = ws + OFF_WAE + o0;
    const float* wbe = ws + OFF_WBE + o0;
    float part = 0.f;
    #pragma unroll
    for (int j = 0; j < 16; j++) part += wae[j] * vf[j] + wbe[j] * pf[j];
    sq[tid] = part;
    __syncthreads();
    float q = sq[l] + sq[l + 64] + sq[l + 128] + sq[l + 192] + ws[OFF_Q0];
    float attn = 1.0f + 1.0f / (1.0f + expf(-q));
    float* op = out + (size_t)(b * 64 + o0) * NPT + n;
    #pragma unroll
    for (int j = 0; j < 16; j++) op[(size_t)j * NPT] = vf[j] * attn + pf[j];
}

extern "C" void kernel_launch(void* const* d_in, const int* in_sizes, int n_in,
                              void* d_out, int out_size, void* d_ws, size_t ws_size,
                              hipStream_t stream) {
    const float* features = (const float*)d_in[0];
    const float* coords   = (const float*)d_in[1];
    const float* vconv_w  = (const float*)d_in[2];
    const float* vconv_b  = (const float*)d_in[3];
    const float* vbn_g    = (const float*)d_in[4];
    const float* vbn_b    = (const float*)d_in[5];
    const float* res_w    = (const float*)d_in[6];
    const float* res_b    = (const float*)d_in[7];
    const float* res_bn_g = (const float*)d_in[8];
    const float* res_bn_b = (const float*)d_in[9];
    const float* pf_w     = (const float*)d_in[10];
    const float* pf_b     = (const float*)d_in[11];
    const float* pf_bn_g  = (const float*)d_in[12];
    const float* pf_bn_b  = (const float*)d_in[13];
    const float* attn_wa  = (const float*)d_in[14];
    const float* attn_ba  = (const float*)d_in[15];
    const float* attn_wb  = (const float*)d_in[16];
    const float* attn_bb  = (const float*)d_in[17];
    const float* attn_wc  = (const float*)d_in[18];
    const float* attn_bc  = (const float*)d_in[19];
    float* ws  = (float*)d_ws;
    float* out = (float*)d_out;

    unsigned short* WB = (unsigned short*)(ws + OFF_WB16);
    int*            CUR = (int*)(ws + OFF_CUR);
    unsigned short* ORD = (unsigned short*)(ws + OFF_ORD);
    unsigned short* FT = (unsigned short*)(ws + OFF_GA);   // overlays residual buffer
    float* GA = ws + OFF_GA;
    unsigned short* G0 = (unsigned short*)(ws + OFF_G0);
    unsigned short* G1 = (unsigned short*)(ws + OFF_G1);
    const float* Bv = ws + OFF_BEFF;

    k_fold_w<<<2160, 256, 0, stream>>>(vconv_w, vbn_g, res_w, res_bn_g, WB);
    k_misc<<<19, 256, 0, stream>>>(vconv_b, vbn_g, vbn_b, res_b, res_bn_g, res_bn_b,
                                   pf_w, pf_b, pf_bn_g, pf_bn_b,
                                   attn_wa, attn_ba, attn_wb, attn_bb, attn_wc, attn_bc, ws);
    k_zero<<<128, 256, 0, stream>>>((float4*)CUR, 32768);
    k_mean<<<12, 1024, 0, stream>>>(coords, ws + OFF_MEAN);
    k_maxn<<<4, 1024, 0, stream>>>(coords, ws + OFF_MEAN, ws + OFF_MAXN);
    k_prep<<<1024, 256, 0, stream>>>(coords, ws + OFF_MEAN, ws + OFF_MAXN,
                                     ws + OFF_CB3, CUR);
    k_scan<<<1, 1024, 0, stream>>>(CUR);
    k_trans<<<4096, 256, 0, stream>>>(features, FT);
    k_place<<<1024, 256, 0, stream>>>(ws + OFF_CB3, CUR, ORD);
    k_gather<<<32768, 256, 0, stream>>>(CUR, ORD, FT, G0);

    dim3 cg(512, 4);
    k_conv<<<cg, 256, 0, stream>>>(G0, WB + 0 * 110592, Bv + 0,   nullptr, GA,      G1);
    k_conv<<<cg, 256, 0, stream>>>(G1, WB + 1 * 110592, Bv + 64,  nullptr, nullptr, G0);
    k_conv<<<cg, 256, 0, stream>>>(G0, WB + 2 * 110592, Bv + 128, GA,      GA,      G1);
    k_conv<<<cg, 256, 0, stream>>>(G1, WB + 3 * 110592, Bv + 192, nullptr, nullptr, G0);
    k_conv<<<cg, 256, 0, stream>>>(G0, WB + 4 * 110592, Bv + 256, GA,      nullptr, G1);

    dim3 fg(1024, 4);
    k_final<<<fg, 256, 0, stream>>>(features, ws + OFF_CB3, G1, ws, out);
}

// Round 4
// 636.637 us; speedup vs baseline: 18.6683x; 1.4072x over previous
//
#include <hip/hip_runtime.h>
#include <math.h>

#define NPT 65536
#define NB 4
#define R3 32768

typedef __attribute__((ext_vector_type(8))) short short8;
typedef __attribute__((ext_vector_type(16))) float f32x16;

// ws layout (float offsets)
#define OFF_WB16 0          // 276480 floats = 552960 bf16: 5 conv layers, B-frag order
#define OFF_BEFF 276480     // 5*64 conv biases (BN-folded)
#define OFF_PWB  276800     // 2048 floats = 4096 bf16: point-branch weights, B-frag order
#define OFF_PB   280896     // 64
#define OFF_WAE  280960     // 64
#define OFF_WBE  281024     // 64
#define OFF_Q0   281088     // 1 (+pad)
#define OFF_MEAN 281104     // 12
#define OFF_MAXN 281116     // 4
#define OFF_PART 281120     // 128 reduction partials (96 mean + 32 max)
#define OFF_AUX  281248     // 256 scan block sums (int)
#define OFF_CB3  281504     // 786432: 3 floats/point normalized coords
#define OFF_CUR  1067936    // 131072 int cursor
#define OFF_ORD  1199008    // 131072 floats = 262144 ushort sorted point ids
#define OFF_GA   1330080    // 8388608 fp32 residual; FT bf16 overlays pre-conv; PF bf16 overlays post-conv
#define OFF_G0   9718688    // 4194304 floats = 8388608 bf16 swizzled grid ping
#define OFF_G1   13912992   // 4194304 floats = 8388608 bf16 swizzled grid pong

__device__ __forceinline__ unsigned short f2b(float f) {
    union { float f; unsigned int u; } v; v.f = f;
    unsigned int r = v.u + 0x7fffu + ((v.u >> 16) & 1u);
    return (unsigned short)(r >> 16);
}
__device__ __forceinline__ float b2f(unsigned short u) {
    union { unsigned int u; float f; } v; v.u = ((unsigned int)u) << 16; return v.f;
}

__global__ void k_fold_w(const float* __restrict__ vconv_w, const float* __restrict__ vbn_g,
                         const float* __restrict__ res_w, const float* __restrict__ res_bn_g,
                         unsigned short* __restrict__ wb16) {
    int idx = blockIdx.x * 256 + threadIdx.x;
    if (idx >= 5 * 27 * 4 * 2 * 64 * 8) return;
    int j = idx & 7;
    int l = (idx >> 3) & 63;
    int nh = (idx >> 9) & 1;
    int ks = (idx >> 10) & 3;
    int rest = idx >> 12;          // layer*27 + t
    int t = rest % 27;
    int layer = rest / 27;
    int i = ks * 16 + ((l >> 5) << 3) + j;
    int o = nh * 32 + (l & 31);
    const float invs = rsqrtf(1.00001f);
    float scale, wsrc;
    if (layer == 0) {
        scale = vbn_g[o] * invs;
        wsrc = vconv_w[(o * 64 + i) * 27 + t];
    } else {
        scale = res_bn_g[(layer - 1) * 64 + o] * invs;
        wsrc = res_w[(size_t)(layer - 1) * 110592 + (o * 64 + i) * 27 + t];
    }
    wb16[idx] = f2b(wsrc * scale);
}

__global__ void k_misc(const float* __restrict__ vconv_b, const float* __restrict__ vbn_g,
                       const float* __restrict__ vbn_b,
                       const float* __restrict__ res_b, const float* __restrict__ res_bn_g,
                       const float* __restrict__ res_bn_b,
                       const float* __restrict__ pf_w, const float* __restrict__ pf_b,
                       const float* __restrict__ pf_bn_g, const float* __restrict__ pf_bn_b,
                       const float* __restrict__ wa, const float* __restrict__ ba,
                       const float* __restrict__ wb, const float* __restrict__ bb,
                       const float* __restrict__ wc, const float* __restrict__ bc,
                       float* __restrict__ ws) {
    int idx = blockIdx.x * 256 + threadIdx.x;
    const float invs = rsqrtf(1.00001f);
    if (idx < 320) {
        int l = idx >> 6, o = idx & 63;
        float b_, g_, s_;
        if (l == 0) { b_ = vconv_b[o]; g_ = vbn_g[o]; s_ = vbn_b[o]; }
        else {
            b_ = res_b[(l - 1) * 64 + o];
            g_ = res_bn_g[(l - 1) * 64 + o];
            s_ = res_bn_b[(l - 1) * 64 + o];
        }
        ws[OFF_BEFF + idx] = b_ * g_ * invs + s_;
    } else if (idx < 4416) {
        // point-branch weights in MFMA B-frag order, bf16
        int e = idx - 320;                 // 0..4095
        int j = e & 7;
        int lane = (e >> 3) & 63;
        int ks = (e >> 9) & 3;
        int half = e >> 11;
        int i = ks * 16 + ((lane >> 5) << 3) + j;
        int o = half * 32 + (lane & 31);
        ((unsigned short*)(ws + OFF_PWB))[e] = f2b(pf_w[o * 64 + i] * pf_bn_g[o] * invs);
    } else if (idx < 4480) {
        int o = idx - 4416;
        ws[OFF_PB + o] = pf_b[o] * pf_bn_g[o] * invs + pf_bn_b[o];
    } else if (idx < 4544) {
        int o = idx - 4480;
        float s = 0.f;
        for (int j = 0; j < 16; j++) s += wc[j] * wa[j * 64 + o];
        ws[OFF_WAE + o] = s;
    } else if (idx < 4608) {
        int o = idx - 4544;
        float s = 0.f;
        for (int j = 0; j < 16; j++) s += wc[16 + j] * wb[j * 64 + o];
        ws[OFF_WBE + o] = s;
    } else if (idx == 4608) {
        float s = bc[0];
        for (int j = 0; j < 16; j++) s += wc[j] * ba[j] + wc[16 + j] * bb[j];
        ws[OFF_Q0] = s;
    }
}

__global__ void k_zero(float4* __restrict__ p, int n4) {
    int i = blockIdx.x * 256 + threadIdx.x;
    if (i < n4) p[i] = make_float4(0.f, 0.f, 0.f, 0.f);
}

// stage-1 mean partials: 96 blocks = 12 (b,d) x 8 chunks of 8192
__global__ __launch_bounds__(256) void k_mean1(const float* __restrict__ coords,
                                               float* __restrict__ part) {
    __shared__ float sm[256];
    int bd = blockIdx.x >> 3, chunk = blockIdx.x & 7;
    int tid = threadIdx.x;
    const float* p = coords + (size_t)bd * NPT + chunk * 8192;
    float s = 0.f;
    for (int n = tid; n < 8192; n += 256) s += p[n];
    sm[tid] = s; __syncthreads();
    for (int st = 128; st > 0; st >>= 1) {
        if (tid < st) sm[tid] += sm[tid + st];
        __syncthreads();
    }
    if (tid == 0) part[blockIdx.x] = sm[0];
}

__global__ void k_mean2(const float* __restrict__ part, float* __restrict__ mean) {
    int t = threadIdx.x;
    if (t < 12) {
        float s = 0.f;
        for (int c = 0; c < 8; c++) s += part[t * 8 + c];
        mean[t] = s * (1.0f / NPT);
    }
}

// stage-1 max-norm^2 partials: 32 blocks = 4 b x 8 chunks
__global__ __launch_bounds__(256) void k_maxn1(const float* __restrict__ coords,
                                               const float* __restrict__ mean,
                                               float* __restrict__ part) {
    __shared__ float sm[256];
    int b = blockIdx.x >> 3, chunk = blockIdx.x & 7;
    int tid = threadIdx.x;
    float m0 = mean[b * 3], m1 = mean[b * 3 + 1], m2 = mean[b * 3 + 2];
    const float* p0 = coords + (size_t)(b * 3) * NPT + chunk * 8192;
    float mx = 0.f;
    for (int n = tid; n < 8192; n += 256) {
        float dx = p0[n] - m0, dy = p0[NPT + n] - m1, dz = p0[2 * NPT + n] - m2;
        mx = fmaxf(mx, dx * dx + dy * dy + dz * dz);
    }
    sm[tid] = mx; __syncthreads();
    for (int st = 128; st > 0; st >>= 1) {
        if (tid < st) sm[tid] = fmaxf(sm[tid], sm[tid + st]);
        __syncthreads();
    }
    if (tid == 0) part[96 + blockIdx.x] = sm[0];
}

__global__ void k_maxn2(const float* __restrict__ part, float* __restrict__ maxn) {
    int t = threadIdx.x;
    if (t < 4) {
        float m = 0.f;
        for (int c = 0; c < 8; c++) m = fmaxf(m, part[96 + t * 8 + c]);
        maxn[t] = sqrtf(m);
    }
}

// per-point normalized coords + voxel histogram
__global__ void k_prep(const float* __restrict__ coords, const float* __restrict__ mean,
                       const float* __restrict__ maxn, float* __restrict__ cb3,
                       int* __restrict__ cursor) {
    int gid = blockIdx.x * 256 + threadIdx.x;
    int b = gid >> 16, n = gid & 65535;
    float inv = 0.5f / maxn[b];
    float c0 = (coords[(size_t)(b * 3) * NPT + n]     - mean[b * 3])     * inv + 0.5f;
    float c1 = (coords[(size_t)(b * 3 + 1) * NPT + n] - mean[b * 3 + 1]) * inv + 0.5f;
    float c2 = (coords[(size_t)(b * 3 + 2) * NPT + n] - mean[b * 3 + 2]) * inv + 0.5f;
    c0 = fminf(fmaxf(c0 * 32.f, 0.f), 31.f);
    c1 = fminf(fmaxf(c1 * 32.f, 0.f), 31.f);
    c2 = fminf(fmaxf(c2 * 32.f, 0.f), 31.f);
    cb3[gid * 3]     = c0;
    cb3[gid * 3 + 1] = c1;
    cb3[gid * 3 + 2] = c2;
    int vx = b * R3 + ((int)rintf(c0) * 1024 + (int)rintf(c1) * 32 + (int)rintf(c2));
    atomicAdd(&cursor[vx], 1);
}

// scan stage 1: 256 blocks x 512 bins -> local exclusive scan + block totals
__global__ void k_scan1(int* __restrict__ cur, int* __restrict__ aux) {
    __shared__ int sm[256];
    int t = threadIdx.x;
    int base = blockIdx.x * 512 + t * 2;
    int c0 = cur[base], c1 = cur[base + 1];
    int s = c0 + c1;
    sm[t] = s; __syncthreads();
    for (int off = 1; off < 256; off <<= 1) {
        int v = (t >= off) ? sm[t - off] : 0;
        __syncthreads();
        sm[t] += v;
        __syncthreads();
    }
    int ex = sm[t] - s;
    cur[base] = ex;
    cur[base + 1] = ex + c0;
    if (t == 255) aux[blockIdx.x] = sm[t];
}

// scan stage 2: exclusive scan of 256 block totals
__global__ void k_scan2(int* __restrict__ aux) {
    __shared__ int sm[256];
    int t = threadIdx.x;
    int v0 = aux[t];
    sm[t] = v0; __syncthreads();
    for (int off = 1; off < 256; off <<= 1) {
        int v = (t >= off) ? sm[t - off] : 0;
        __syncthreads();
        sm[t] += v;
        __syncthreads();
    }
    aux[t] = sm[t] - v0;
}

// scan stage 3: add block offsets
__global__ void k_scan3(int* __restrict__ cur, const int* __restrict__ aux) {
    int t = threadIdx.x;
    int add = aux[blockIdx.x];
    int base = blockIdx.x * 512 + t * 2;
    cur[base] += add;
    cur[base + 1] += add;
}

// features [B][64][N] fp32 -> FT [B][N][64] bf16 (LDS transpose)
__global__ __launch_bounds__(256) void k_trans(const float* __restrict__ feats,
                                               unsigned short* __restrict__ ft) {
    __shared__ float lds[64][65];
    int b = blockIdx.x >> 10;
    int n0 = (blockIdx.x & 1023) << 6;
    int tid = threadIdx.x;
    int nl = tid & 63;
    #pragma unroll
    for (int it = 0; it < 16; it++) {
        int ch = it * 4 + (tid >> 6);
        lds[nl][ch] = feats[((size_t)(b * 64 + ch) << 16) + n0 + nl];
    }
    __syncthreads();
    int nn = tid >> 2;
    int ch0 = (tid & 3) << 4;
    size_t obase = (((size_t)(b << 16) + n0 + nn) << 6) + ch0;
    short8 v0, v1;
    #pragma unroll
    for (int j = 0; j < 8; j++) v0[j] = (short)f2b(lds[nn][ch0 + j]);
    #pragma unroll
    for (int j = 0; j < 8; j++) v1[j] = (short)f2b(lds[nn][ch0 + 8 + j]);
    *(short8*)(ft + obase) = v0;
    *(short8*)(ft + obase + 8) = v1;
}

// place point ids into voxel-sorted order
__global__ void k_place(const float* __restrict__ cb3, int* __restrict__ cursor,
                        unsigned short* __restrict__ order) {
    int gid = blockIdx.x * 256 + threadIdx.x;
    int b = gid >> 16;
    float c0 = cb3[gid * 3], c1 = cb3[gid * 3 + 1], c2 = cb3[gid * 3 + 2];
    int vx = b * R3 + ((int)rintf(c0) * 1024 + (int)rintf(c1) * 32 + (int)rintf(c2));
    int slot = atomicAdd(&cursor[vx], 1);
    order[slot] = (unsigned short)(gid & 65535);
}

// one wave per voxel: coalesced gather, average, write swizzled bf16 grid
__global__ __launch_bounds__(256) void k_gather(const int* __restrict__ cursor,
        const unsigned short* __restrict__ order, const unsigned short* __restrict__ ft,
        unsigned short* __restrict__ g0) {
    int tid = threadIdx.x;
    int lane = tid & 63;
    int vx = blockIdx.x * 4 + (tid >> 6);
    int e = cursor[vx];
    int s = (vx == 0) ? 0 : cursor[vx - 1];
    int bb = vx >> 15;
    float acc = 0.f;
    int p = s;
    for (; p + 1 < e; p += 2) {
        int n0 = order[p], n1 = order[p + 1];
        acc += b2f(ft[(((size_t)(bb << 16) + n0) << 6) + lane]);
        acc += b2f(ft[(((size_t)(bb << 16) + n1) << 6) + lane]);
    }
    if (p < e) {
        int n0 = order[p];
        acc += b2f(ft[(((size_t)(bb << 16) + n0) << 6) + lane]);
    }
    float avg = acc / (float)max(e - s, 1);
    int col = vx >> 5, z = vx & 31;
    g0[(size_t)col * 2048 + ((lane >> 3) << 8) + z * 8 + (lane & 7)] = f2b(avg);
}

// MFMA implicit-GEMM 3^3 conv, 4 columns/block.
// 4 waves: (column-pair, out-ch-half). 18 staged columns (72KB LDS).
__global__ __launch_bounds__(256) void k_conv(const unsigned short* __restrict__ in,
        const unsigned short* __restrict__ w, const float* __restrict__ bias,
        const float* __restrict__ idF, float* __restrict__ outF,
        unsigned short* __restrict__ out) {
    __shared__ unsigned short sA[18 * 2048];    // 72 KB
    int tid = threadIdx.x;
    int lane = tid & 63;
    int wid = tid >> 6;
    int cp = wid & 1;          // column pair: y0+2cp, y0+2cp+1
    int nh = wid >> 1;         // out-channel half
    int tile = blockIdx.x;     // 0..255
    int b = blockIdx.y;
    int x = tile >> 3;
    int y0 = (tile & 7) << 2;
    for (int s = 0; s < 18; s++) {
        int gx = x + s / 6 - 1;
        int gy = y0 + s % 6 - 1;
        float4 v = make_float4(0.f, 0.f, 0.f, 0.f);
        if ((unsigned)gx < 32u && (unsigned)gy < 32u) {
            const float4* src = (const float4*)(in + (((size_t)b * 1024 + gx * 32 + gy) << 11));
            v = src[tid];
        }
        ((float4*)(sA + s * 2048))[tid] = v;
    }
    __syncthreads();
    f32x16 accA = {}, accB = {};
    const short8 zero8 = {0, 0, 0, 0, 0, 0, 0, 0};
    int half = lane >> 5;
    #pragma unroll 1
    for (int t = 0; t < 27; t++) {
        int dxi = t / 9, dyi = (t / 3) % 3, dz = t % 3 - 1;
        int s0 = dxi * 6 + dyi + cp * 2;
        int zz = (lane & 31) + dz;
        bool zv = (unsigned)zz < 32u;
        int zc = zv ? zz : 0;
        const unsigned short* ac = sA + s0 * 2048 + (half << 8) + zc * 8;
        const unsigned short* wp = w + t * 4096 + nh * 512 + lane * 8;
        #pragma unroll
        for (int ks = 0; ks < 4; ks++) {
            short8 bf = *(const short8*)(wp + ks * 1024);
            short8 a0 = *(const short8*)(ac + ks * 512);
            short8 a1 = *(const short8*)(ac + 2048 + ks * 512);
            if (!zv) { a0 = zero8; a1 = zero8; }
            accA = __builtin_amdgcn_mfma_f32_32x32x16_bf16(a0, bf, accA, 0, 0, 0);
            accB = __builtin_amdgcn_mfma_f32_32x32x16_bf16(a1, bf, accB, 0, 0, 0);
        }
    }
    int o = nh * 32 + (lane & 31);
    float bb = bias[o];
    #pragma unroll
    for (int cc = 0; cc < 2; cc++) {
        int outcol = b * 1024 + x * 32 + (y0 + cp * 2 + cc);
        size_t obase = ((size_t)outcol << 11) + (size_t)((o >> 3) << 8) + (o & 7);
        const f32x16& acc = cc ? accB : accA;
        #pragma unroll
        for (int r = 0; r < 16; r++) {
            int z = (r & 3) + ((r >> 2) << 3) + ((lane >> 5) << 2);
            size_t oe = obase + (size_t)z * 8;
            float v = acc[r] + bb;
            if (idF) v += idF[oe];
            v = fmaxf(v, 0.f);
            out[oe] = f2b(v);
            if (outF) outF[oe] = v;
        }
    }
}

// point-branch MLP via MFMA: pfeat[B][N][64] bf16 = relu(PW * feat + PB)
__global__ __launch_bounds__(256) void k_pfeat(const float* __restrict__ feats,
        const float* __restrict__ pb, const unsigned short* __restrict__ pwb,
        unsigned short* __restrict__ pf) {
    int tid = threadIdx.x;
    int lane = tid & 63;
    int wv = tid >> 6;
    int tile = blockIdx.x * 4 + wv;          // 0..8191
    int b = tile >> 11;
    int n0 = (tile & 2047) << 5;
    int m = lane & 31, kg = lane >> 5;
    const float* fb = feats + ((size_t)b << 22) + n0 + m;
    f32x16 acc0 = {}, acc1 = {};
    #pragma unroll
    for (int ks = 0; ks < 4; ks++) {
        short8 af;
        #pragma unroll
        for (int j = 0; j < 8; j++)
            af[j] = (short)f2b(fb[(size_t)(ks * 16 + kg * 8 + j) << 16]);
        short8 b0 = *(const short8*)(pwb + ((size_t)(ks * 64 + lane) << 3));
        short8 b1 = *(const short8*)(pwb + ((size_t)((4 + ks) * 64 + lane) << 3));
        acc0 = __builtin_amdgcn_mfma_f32_32x32x16_bf16(af, b0, acc0, 0, 0, 0);
        acc1 = __builtin_amdgcn_mfma_f32_32x32x16_bf16(af, b1, acc1, 0, 0, 0);
    }
    int och = lane & 31;
    float bias0 = pb[och], bias1 = pb[32 + och];
    #pragma unroll
    for (int r = 0; r < 16; r++) {
        int p = (r & 3) + ((r >> 2) << 3) + ((lane >> 5) << 2);
        size_t base = ((size_t)(b << 16) + n0 + p) << 6;
        pf[base + och]      = f2b(fmaxf(acc0[r] + bias0, 0.f));
        pf[base + 32 + och] = f2b(fmaxf(acc1[r] + bias1, 0.f));
    }
}

// devox gather + pfeat load + collapsed attention + fuse.
__global__ __launch_bounds__(256) void k_final(const float* __restrict__ cb3,
        const unsigned short* __restrict__ gb, const unsigned short* __restrict__ pfeat,
        const float* __restrict__ ws, float* __restrict__ out) {
    __shared__ float sq[256];
    int tid = threadIdx.x;
    int l = tid & 63;
    int g = tid >> 6;
    int o0 = g << 4;
    int b = blockIdx.y;
    int n = (blockIdx.x << 6) + l;
    int gid = (b << 16) + n;
    float c0 = cb3[gid * 3], c1 = cb3[gid * 3 + 1], c2 = cb3[gid * 3 + 2];
    int lx = (int)floorf(c0), ly = (int)floorf(c1), lz = (int)floorf(c2);
    int hx = min(lx + 1, 31), hy = min(ly + 1, 31), hz = min(lz + 1, 31);
    float fx = c0 - (float)lx, fy = c1 - (float)ly, fz = c2 - (float)lz;
    int xs[2] = {lx, hx}; float wxx[2] = {1.f - fx, fx};
    int ys[2] = {ly, hy}; float wyy[2] = {1.f - fy, fy};
    int zs[2] = {lz, hz}; float wzz[2] = {1.f - fz, fz};
    float vf[16];
    #pragma unroll
    for (int j = 0; j < 16; j++) vf[j] = 0.f;
    #pragma unroll
    for (int ii = 0; ii < 2; ii++)
    #pragma unroll
    for (int jj = 0; jj < 2; jj++)
    #pragma unroll
    for (int kk = 0; kk < 2; kk++) {
        float wgt = wxx[ii] * wyy[jj] * wzz[kk];
        const unsigned short* gp = gb + (((size_t)b * 1024 + xs[ii] * 32 + ys[jj]) << 11)
                                      + ((size_t)g << 9) + zs[kk] * 8;
        short8 v0 = *(const short8*)(gp);
        short8 v1 = *(const short8*)(gp + 256);
        #pragma unroll
        for (int j = 0; j < 8; j++) {
            vf[j]     += wgt * b2f((unsigned short)v0[j]);
            vf[8 + j] += wgt * b2f((unsigned short)v1[j]);
        }
    }
    // point branch: load precomputed pfeat
    float pf[16];
    const unsigned short* pp = pfeat + ((size_t)gid << 6) + o0;
    short8 p0 = *(const short8*)pp;
    short8 p1 = *(const short8*)(pp + 8);
    #pragma unroll
    for (int j = 0; j < 8; j++) {
        pf[j]     = b2f((unsigned short)p0[j]);
        pf[8 + j] = b2f((unsigned short)p1[j]);
    }
    const float* wae = ws + OFF_WAE + o0;
    const float* wbe = ws + OFF_WBE + o0;
    float part = 0.f;
    #pragma unroll
    for (int j = 0; j < 16; j++) part += wae[j] * vf[j] + wbe[j] * pf[j];
    sq[tid] = part;
    __syncthreads();
    float q = sq[l] + sq[l + 64] + sq[l + 128] + sq[l + 192] + ws[OFF_Q0];
    float attn = 1.0f + 1.0f / (1.0f + expf(-q));
    float* op = out + (size_t)(b * 64 + o0) * NPT + n;
    #pragma unroll
    for (int j = 0; j < 16; j++) op[(size_t)j * NPT] = vf[j] * attn + pf[j];
}

extern "C" void kernel_launch(void* const* d_in, const int* in_sizes, int n_in,
                              void* d_out, int out_size, void* d_ws, size_t ws_size,
                              hipStream_t stream) {
    const float* features = (const float*)d_in[0];
    const float* coords   = (const float*)d_in[1];
    const float* vconv_w  = (const float*)d_in[2];
    const float* vconv_b  = (const float*)d_in[3];
    const float* vbn_g    = (const float*)d_in[4];
    const float* vbn_b    = (const float*)d_in[5];
    const float* res_w    = (const float*)d_in[6];
    const float* res_b    = (const float*)d_in[7];
    const float* res_bn_g = (const float*)d_in[8];
    const float* res_bn_b = (const float*)d_in[9];
    const float* pf_w     = (const float*)d_in[10];
    const float* pf_b     = (const float*)d_in[11];
    const float* pf_bn_g  = (const float*)d_in[12];
    const float* pf_bn_b  = (const float*)d_in[13];
    const float* attn_wa  = (const float*)d_in[14];
    const float* attn_ba  = (const float*)d_in[15];
    const float* attn_wb  = (const float*)d_in[16];
    const float* attn_bb  = (const float*)d_in[17];
    const float* attn_wc  = (const float*)d_in[18];
    const float* attn_bc  = (const float*)d_in[19];
    float* ws  = (float*)d_ws;
    float* out = (float*)d_out;

    unsigned short* WB  = (unsigned short*)(ws + OFF_WB16);
    unsigned short* PWB = (unsigned short*)(ws + OFF_PWB);
    int*            CUR = (int*)(ws + OFF_CUR);
    int*            AUX = (int*)(ws + OFF_AUX);
    unsigned short* ORD = (unsigned short*)(ws + OFF_ORD);
    unsigned short* FT  = (unsigned short*)(ws + OFF_GA);   // pre-conv overlay
    unsigned short* PF  = (unsigned short*)(ws + OFF_GA);   // post-conv overlay
    float* GA = ws + OFF_GA;
    unsigned short* G0 = (unsigned short*)(ws + OFF_G0);
    unsigned short* G1 = (unsigned short*)(ws + OFF_G1);
    const float* Bv = ws + OFF_BEFF;

    k_fold_w<<<2160, 256, 0, stream>>>(vconv_w, vbn_g, res_w, res_bn_g, WB);
    k_misc<<<19, 256, 0, stream>>>(vconv_b, vbn_g, vbn_b, res_b, res_bn_g, res_bn_b,
                                   pf_w, pf_b, pf_bn_g, pf_bn_b,
                                   attn_wa, attn_ba, attn_wb, attn_bb, attn_wc, attn_bc, ws);
    k_zero<<<128, 256, 0, stream>>>((float4*)CUR, 32768);
    k_mean1<<<96, 256, 0, stream>>>(coords, ws + OFF_PART);
    k_mean2<<<1, 64, 0, stream>>>(ws + OFF_PART, ws + OFF_MEAN);
    k_maxn1<<<32, 256, 0, stream>>>(coords, ws + OFF_MEAN, ws + OFF_PART);
    k_maxn2<<<1, 64, 0, stream>>>(ws + OFF_PART, ws + OFF_MAXN);
    k_prep<<<1024, 256, 0, stream>>>(coords, ws + OFF_MEAN, ws + OFF_MAXN,
                                     ws + OFF_CB3, CUR);
    k_scan1<<<256, 256, 0, stream>>>(CUR, AUX);
    k_scan2<<<1, 256, 0, stream>>>(AUX);
    k_scan3<<<256, 256, 0, stream>>>(CUR, AUX);
    k_trans<<<4096, 256, 0, stream>>>(features, FT);
    k_place<<<1024, 256, 0, stream>>>(ws + OFF_CB3, CUR, ORD);
    k_gather<<<32768, 256, 0, stream>>>(CUR, ORD, FT, G0);

    dim3 cg(256, 4);
    k_conv<<<cg, 256, 0, stream>>>(G0, WB + 0 * 110592, Bv + 0,   nullptr, GA,      G1);
    k_conv<<<cg, 256, 0, stream>>>(G1, WB + 1 * 110592, Bv + 64,  nullptr, nullptr, G0);
    k_conv<<<cg, 256, 0, stream>>>(G0, WB + 2 * 110592, Bv + 128, GA,      GA,      G1);
    k_conv<<<cg, 256, 0, stream>>>(G1, WB + 3 * 110592, Bv + 192, nullptr, nullptr, G0);
    k_conv<<<cg, 256, 0, stream>>>(G0, WB + 4 * 110592, Bv + 256, GA,      nullptr, G1);

    k_pfeat<<<2048, 256, 0, stream>>>(features, ws + OFF_PB, PWB, PF);

    dim3 fg(1024, 4);
    k_final<<<fg, 256, 0, stream>>>(ws + OFF_CB3, G1, PF, ws, out);
}

// Round 5
// 580.478 us; speedup vs baseline: 20.4744x; 1.0967x over previous
//
#include <hip/hip_runtime.h>
#include <math.h>

#define NPT 65536
#define NB 4
#define R3 32768

typedef __attribute__((ext_vector_type(8))) short short8;
typedef __attribute__((ext_vector_type(16))) float f32x16;

// ws layout (float offsets)
#define OFF_WB16 0          // 276480 floats = 552960 bf16: 5 conv layers, B-frag order
#define OFF_BEFF 276480     // 5*64 conv biases (BN-folded)
#define OFF_PWB  276800     // 2048 floats = 4096 bf16: point-branch weights, B-frag order
#define OFF_PB   280896     // 64
#define OFF_WAE  280960     // 64
#define OFF_WBE  281024     // 64
#define OFF_Q0   281088     // 1 (+pad)
#define OFF_MEAN 281104     // 12
#define OFF_MAXN 281116     // 4
#define OFF_PART 281120     // 128 reduction partials (96 mean + 32 max)
#define OFF_AUX  281248     // 256 scan block sums (int)
#define OFF_CB3  281504     // 786432: 3 floats/point normalized coords
#define OFF_CUR  1067936    // 131072 int cursor
#define OFF_ORD  1199008    // 131072 floats = 262144 ushort sorted point ids
#define OFF_GA   1330080    // 8388608 fp32 residual; FT bf16 overlays pre-conv; PF bf16 overlays post-conv
#define OFF_G0   9718688    // 4194304 floats = 8388608 bf16 swizzled grid ping
#define OFF_G1   13912992   // 4194304 floats = 8388608 bf16 swizzled grid pong

__device__ __forceinline__ unsigned short f2b(float f) {
    union { float f; unsigned int u; } v; v.f = f;
    unsigned int r = v.u + 0x7fffu + ((v.u >> 16) & 1u);
    return (unsigned short)(r >> 16);
}
__device__ __forceinline__ float b2f(unsigned short u) {
    union { unsigned int u; float f; } v; v.u = ((unsigned int)u) << 16; return v.f;
}

__global__ void k_fold_w(const float* __restrict__ vconv_w, const float* __restrict__ vbn_g,
                         const float* __restrict__ res_w, const float* __restrict__ res_bn_g,
                         unsigned short* __restrict__ wb16) {
    int idx = blockIdx.x * 256 + threadIdx.x;
    if (idx >= 5 * 27 * 4 * 2 * 64 * 8) return;
    int j = idx & 7;
    int l = (idx >> 3) & 63;
    int nh = (idx >> 9) & 1;
    int ks = (idx >> 10) & 3;
    int rest = idx >> 12;          // layer*27 + t
    int t = rest % 27;
    int layer = rest / 27;
    int i = ks * 16 + ((l >> 5) << 3) + j;
    int o = nh * 32 + (l & 31);
    const float invs = rsqrtf(1.00001f);
    float scale, wsrc;
    if (layer == 0) {
        scale = vbn_g[o] * invs;
        wsrc = vconv_w[(o * 64 + i) * 27 + t];
    } else {
        scale = res_bn_g[(layer - 1) * 64 + o] * invs;
        wsrc = res_w[(size_t)(layer - 1) * 110592 + (o * 64 + i) * 27 + t];
    }
    wb16[idx] = f2b(wsrc * scale);
}

__global__ void k_misc(const float* __restrict__ vconv_b, const float* __restrict__ vbn_g,
                       const float* __restrict__ vbn_b,
                       const float* __restrict__ res_b, const float* __restrict__ res_bn_g,
                       const float* __restrict__ res_bn_b,
                       const float* __restrict__ pf_w, const float* __restrict__ pf_b,
                       const float* __restrict__ pf_bn_g, const float* __restrict__ pf_bn_b,
                       const float* __restrict__ wa, const float* __restrict__ ba,
                       const float* __restrict__ wb, const float* __restrict__ bb,
                       const float* __restrict__ wc, const float* __restrict__ bc,
                       float* __restrict__ ws) {
    int idx = blockIdx.x * 256 + threadIdx.x;
    const float invs = rsqrtf(1.00001f);
    if (idx < 320) {
        int l = idx >> 6, o = idx & 63;
        float b_, g_, s_;
        if (l == 0) { b_ = vconv_b[o]; g_ = vbn_g[o]; s_ = vbn_b[o]; }
        else {
            b_ = res_b[(l - 1) * 64 + o];
            g_ = res_bn_g[(l - 1) * 64 + o];
            s_ = res_bn_b[(l - 1) * 64 + o];
        }
        ws[OFF_BEFF + idx] = b_ * g_ * invs + s_;
    } else if (idx < 4416) {
        int e = idx - 320;                 // 0..4095
        int j = e & 7;
        int lane = (e >> 3) & 63;
        int ks = (e >> 9) & 3;
        int half = e >> 11;
        int i = ks * 16 + ((lane >> 5) << 3) + j;
        int o = half * 32 + (lane & 31);
        ((unsigned short*)(ws + OFF_PWB))[e] = f2b(pf_w[o * 64 + i] * pf_bn_g[o] * invs);
    } else if (idx < 4480) {
        int o = idx - 4416;
        ws[OFF_PB + o] = pf_b[o] * pf_bn_g[o] * invs + pf_bn_b[o];
    } else if (idx < 4544) {
        int o = idx - 4480;
        float s = 0.f;
        for (int j = 0; j < 16; j++) s += wc[j] * wa[j * 64 + o];
        ws[OFF_WAE + o] = s;
    } else if (idx < 4608) {
        int o = idx - 4544;
        float s = 0.f;
        for (int j = 0; j < 16; j++) s += wc[16 + j] * wb[j * 64 + o];
        ws[OFF_WBE + o] = s;
    } else if (idx == 4608) {
        float s = bc[0];
        for (int j = 0; j < 16; j++) s += wc[j] * ba[j] + wc[16 + j] * bb[j];
        ws[OFF_Q0] = s;
    }
}

__global__ void k_zero(float4* __restrict__ p, int n4) {
    int i = blockIdx.x * 256 + threadIdx.x;
    if (i < n4) p[i] = make_float4(0.f, 0.f, 0.f, 0.f);
}

// stage-1 mean partials: 96 blocks = 12 (b,d) x 8 chunks of 8192
__global__ __launch_bounds__(256) void k_mean1(const float* __restrict__ coords,
                                               float* __restrict__ part) {
    __shared__ float sm[256];
    int bd = blockIdx.x >> 3, chunk = blockIdx.x & 7;
    int tid = threadIdx.x;
    const float* p = coords + (size_t)bd * NPT + chunk * 8192;
    float s = 0.f;
    for (int n = tid; n < 8192; n += 256) s += p[n];
    sm[tid] = s; __syncthreads();
    for (int st = 128; st > 0; st >>= 1) {
        if (tid < st) sm[tid] += sm[tid + st];
        __syncthreads();
    }
    if (tid == 0) part[blockIdx.x] = sm[0];
}

__global__ void k_mean2(const float* __restrict__ part, float* __restrict__ mean) {
    int t = threadIdx.x;
    if (t < 12) {
        float s = 0.f;
        for (int c = 0; c < 8; c++) s += part[t * 8 + c];
        mean[t] = s * (1.0f / NPT);
    }
}

// stage-1 max-norm^2 partials: 32 blocks = 4 b x 8 chunks
__global__ __launch_bounds__(256) void k_maxn1(const float* __restrict__ coords,
                                               const float* __restrict__ mean,
                                               float* __restrict__ part) {
    __shared__ float sm[256];
    int b = blockIdx.x >> 3, chunk = blockIdx.x & 7;
    int tid = threadIdx.x;
    float m0 = mean[b * 3], m1 = mean[b * 3 + 1], m2 = mean[b * 3 + 2];
    const float* p0 = coords + (size_t)(b * 3) * NPT + chunk * 8192;
    float mx = 0.f;
    for (int n = tid; n < 8192; n += 256) {
        float dx = p0[n] - m0, dy = p0[NPT + n] - m1, dz = p0[2 * NPT + n] - m2;
        mx = fmaxf(mx, dx * dx + dy * dy + dz * dz);
    }
    sm[tid] = mx; __syncthreads();
    for (int st = 128; st > 0; st >>= 1) {
        if (tid < st) sm[tid] = fmaxf(sm[tid], sm[tid + st]);
        __syncthreads();
    }
    if (tid == 0) part[96 + blockIdx.x] = sm[0];
}

__global__ void k_maxn2(const float* __restrict__ part, float* __restrict__ maxn) {
    int t = threadIdx.x;
    if (t < 4) {
        float m = 0.f;
        for (int c = 0; c < 8; c++) m = fmaxf(m, part[96 + t * 8 + c]);
        maxn[t] = sqrtf(m);
    }
}

// per-point normalized coords + voxel histogram
__global__ void k_prep(const float* __restrict__ coords, const float* __restrict__ mean,
                       const float* __restrict__ maxn, float* __restrict__ cb3,
                       int* __restrict__ cursor) {
    int gid = blockIdx.x * 256 + threadIdx.x;
    int b = gid >> 16, n = gid & 65535;
    float inv = 0.5f / maxn[b];
    float c0 = (coords[(size_t)(b * 3) * NPT + n]     - mean[b * 3])     * inv + 0.5f;
    float c1 = (coords[(size_t)(b * 3 + 1) * NPT + n] - mean[b * 3 + 1]) * inv + 0.5f;
    float c2 = (coords[(size_t)(b * 3 + 2) * NPT + n] - mean[b * 3 + 2]) * inv + 0.5f;
    c0 = fminf(fmaxf(c0 * 32.f, 0.f), 31.f);
    c1 = fminf(fmaxf(c1 * 32.f, 0.f), 31.f);
    c2 = fminf(fmaxf(c2 * 32.f, 0.f), 31.f);
    cb3[gid * 3]     = c0;
    cb3[gid * 3 + 1] = c1;
    cb3[gid * 3 + 2] = c2;
    int vx = b * R3 + ((int)rintf(c0) * 1024 + (int)rintf(c1) * 32 + (int)rintf(c2));
    atomicAdd(&cursor[vx], 1);
}

// scan stage 1: 256 blocks x 512 bins -> local exclusive scan + block totals
__global__ void k_scan1(int* __restrict__ cur, int* __restrict__ aux) {
    __shared__ int sm[256];
    int t = threadIdx.x;
    int base = blockIdx.x * 512 + t * 2;
    int c0 = cur[base], c1 = cur[base + 1];
    int s = c0 + c1;
    sm[t] = s; __syncthreads();
    for (int off = 1; off < 256; off <<= 1) {
        int v = (t >= off) ? sm[t - off] : 0;
        __syncthreads();
        sm[t] += v;
        __syncthreads();
    }
    int ex = sm[t] - s;
    cur[base] = ex;
    cur[base + 1] = ex + c0;
    if (t == 255) aux[blockIdx.x] = sm[t];
}

// scan stage 2: exclusive scan of 256 block totals
__global__ void k_scan2(int* __restrict__ aux) {
    __shared__ int sm[256];
    int t = threadIdx.x;
    int v0 = aux[t];
    sm[t] = v0; __syncthreads();
    for (int off = 1; off < 256; off <<= 1) {
        int v = (t >= off) ? sm[t - off] : 0;
        __syncthreads();
        sm[t] += v;
        __syncthreads();
    }
    aux[t] = sm[t] - v0;
}

// scan stage 3: add block offsets
__global__ void k_scan3(int* __restrict__ cur, const int* __restrict__ aux) {
    int t = threadIdx.x;
    int add = aux[blockIdx.x];
    int base = blockIdx.x * 512 + t * 2;
    cur[base] += add;
    cur[base + 1] += add;
}

// features [B][64][N] fp32 -> FT [B][N][64] bf16 (LDS transpose)
__global__ __launch_bounds__(256) void k_trans(const float* __restrict__ feats,
                                               unsigned short* __restrict__ ft) {
    __shared__ float lds[64][65];
    int b = blockIdx.x >> 10;
    int n0 = (blockIdx.x & 1023) << 6;
    int tid = threadIdx.x;
    int nl = tid & 63;
    #pragma unroll
    for (int it = 0; it < 16; it++) {
        int ch = it * 4 + (tid >> 6);
        lds[nl][ch] = feats[((size_t)(b * 64 + ch) << 16) + n0 + nl];
    }
    __syncthreads();
    int nn = tid >> 2;
    int ch0 = (tid & 3) << 4;
    size_t obase = (((size_t)(b << 16) + n0 + nn) << 6) + ch0;
    short8 v0, v1;
    #pragma unroll
    for (int j = 0; j < 8; j++) v0[j] = (short)f2b(lds[nn][ch0 + j]);
    #pragma unroll
    for (int j = 0; j < 8; j++) v1[j] = (short)f2b(lds[nn][ch0 + 8 + j]);
    *(short8*)(ft + obase) = v0;
    *(short8*)(ft + obase + 8) = v1;
}

// place point ids into voxel-sorted order
__global__ void k_place(const float* __restrict__ cb3, int* __restrict__ cursor,
                        unsigned short* __restrict__ order) {
    int gid = blockIdx.x * 256 + threadIdx.x;
    int b = gid >> 16;
    float c0 = cb3[gid * 3], c1 = cb3[gid * 3 + 1], c2 = cb3[gid * 3 + 2];
    int vx = b * R3 + ((int)rintf(c0) * 1024 + (int)rintf(c1) * 32 + (int)rintf(c2));
    int slot = atomicAdd(&cursor[vx], 1);
    order[slot] = (unsigned short)(gid & 65535);
}

// one wave per voxel, point-parallel: lane = (point-slot p, ch-group g).
// Each iteration consumes 8 points (1 KB coalesced); one butterfly reduce per voxel.
__global__ __launch_bounds__(256) void k_gather(const int* __restrict__ cursor,
        const unsigned short* __restrict__ order, const unsigned short* __restrict__ ft,
        unsigned short* __restrict__ g0) {
    int tid = threadIdx.x;
    int lane = tid & 63;
    int vx = blockIdx.x * 4 + (tid >> 6);
    int e = cursor[vx];
    int s = (vx == 0) ? 0 : cursor[vx - 1];
    int cnt = e - s;
    int p = lane >> 3;      // point slot 0..7
    int g = lane & 7;       // channel group 0..7 (8 channels each)
    int bb = vx >> 15;
    float acc[8] = {0.f, 0.f, 0.f, 0.f, 0.f, 0.f, 0.f, 0.f};
    for (int base = s; base < e; base += 8) {
        int idx = base + p;
        if (idx < e) {
            int n = order[idx];
            const unsigned short* fp = ft + (((size_t)(bb << 16) + n) << 6) + (g << 3);
            short8 v = *(const short8*)fp;
            #pragma unroll
            for (int j = 0; j < 8; j++) acc[j] += b2f((unsigned short)v[j]);
        }
    }
    // reduce across point slots (lane bits 3,4,5)
    #pragma unroll
    for (int j = 0; j < 8; j++) {
        acc[j] += __shfl_xor(acc[j], 8, 64);
        acc[j] += __shfl_xor(acc[j], 16, 64);
        acc[j] += __shfl_xor(acc[j], 32, 64);
    }
    if (p == 0) {
        float inv = 1.0f / (float)max(cnt, 1);
        int col = vx >> 5, z = vx & 31;
        short8 o8;
        #pragma unroll
        for (int j = 0; j < 8; j++) o8[j] = (short)f2b(acc[j] * inv);
        *(short8*)(g0 + (size_t)col * 2048 + (g << 8) + z * 8) = o8;
    }
}

// MFMA implicit-GEMM 3^3 conv, 4 columns/block.
// 4 waves: (column-pair, out-ch-half). 18 staged columns (72KB LDS).
__global__ __launch_bounds__(256) void k_conv(const unsigned short* __restrict__ in,
        const unsigned short* __restrict__ w, const float* __restrict__ bias,
        const float* __restrict__ idF, float* __restrict__ outF,
        unsigned short* __restrict__ out) {
    __shared__ unsigned short sA[18 * 2048];    // 72 KB
    int tid = threadIdx.x;
    int lane = tid & 63;
    int wid = tid >> 6;
    int cp = wid & 1;          // column pair: y0+2cp, y0+2cp+1
    int nh = wid >> 1;         // out-channel half
    int tile = blockIdx.x;     // 0..255
    int b = blockIdx.y;
    int x = tile >> 3;
    int y0 = (tile & 7) << 2;
    for (int s = 0; s < 18; s++) {
        int gx = x + s / 6 - 1;
        int gy = y0 + s % 6 - 1;
        float4 v = make_float4(0.f, 0.f, 0.f, 0.f);
        if ((unsigned)gx < 32u && (unsigned)gy < 32u) {
            const float4* src = (const float4*)(in + (((size_t)b * 1024 + gx * 32 + gy) << 11));
            v = src[tid];
        }
        ((float4*)(sA + s * 2048))[tid] = v;
    }
    __syncthreads();
    f32x16 accA = {}, accB = {};
    const short8 zero8 = {0, 0, 0, 0, 0, 0, 0, 0};
    int half = lane >> 5;
    #pragma unroll 1
    for (int t = 0; t < 27; t++) {
        int dxi = t / 9, dyi = (t / 3) % 3, dz = t % 3 - 1;
        int s0 = dxi * 6 + dyi + cp * 2;
        int zz = (lane & 31) + dz;
        bool zv = (unsigned)zz < 32u;
        int zc = zv ? zz : 0;
        const unsigned short* ac = sA + s0 * 2048 + (half << 8) + zc * 8;
        const unsigned short* wp = w + t * 4096 + nh * 512 + lane * 8;
        #pragma unroll
        for (int ks = 0; ks < 4; ks++) {
            short8 bf = *(const short8*)(wp + ks * 1024);
            short8 a0 = *(const short8*)(ac + ks * 512);
            short8 a1 = *(const short8*)(ac + 2048 + ks * 512);
            if (!zv) { a0 = zero8; a1 = zero8; }
            accA = __builtin_amdgcn_mfma_f32_32x32x16_bf16(a0, bf, accA, 0, 0, 0);
            accB = __builtin_amdgcn_mfma_f32_32x32x16_bf16(a1, bf, accB, 0, 0, 0);
        }
    }
    int o = nh * 32 + (lane & 31);
    float bb = bias[o];
    #pragma unroll
    for (int cc = 0; cc < 2; cc++) {
        int outcol = b * 1024 + x * 32 + (y0 + cp * 2 + cc);
        size_t obase = ((size_t)outcol << 11) + (size_t)((o >> 3) << 8) + (o & 7);
        const f32x16& acc = cc ? accB : accA;
        #pragma unroll
        for (int r = 0; r < 16; r++) {
            int z = (r & 3) + ((r >> 2) << 3) + ((lane >> 5) << 2);
            size_t oe = obase + (size_t)z * 8;
            float v = acc[r] + bb;
            if (idF) v += idF[oe];
            v = fmaxf(v, 0.f);
            out[oe] = f2b(v);
            if (outF) outF[oe] = v;
        }
    }
}

// point-branch MLP via MFMA: pfeat[B][N][64] bf16 = relu(PW * feat + PB)
__global__ __launch_bounds__(256) void k_pfeat(const float* __restrict__ feats,
        const float* __restrict__ pb, const unsigned short* __restrict__ pwb,
        unsigned short* __restrict__ pf) {
    int tid = threadIdx.x;
    int lane = tid & 63;
    int wv = tid >> 6;
    int tile = blockIdx.x * 4 + wv;          // 0..8191
    int b = tile >> 11;
    int n0 = (tile & 2047) << 5;
    int m = lane & 31, kg = lane >> 5;
    const float* fb = feats + ((size_t)b << 22) + n0 + m;
    f32x16 acc0 = {}, acc1 = {};
    #pragma unroll
    for (int ks = 0; ks < 4; ks++) {
        short8 af;
        #pragma unroll
        for (int j = 0; j < 8; j++)
            af[j] = (short)f2b(fb[(size_t)(ks * 16 + kg * 8 + j) << 16]);
        short8 b0 = *(const short8*)(pwb + ((size_t)(ks * 64 + lane) << 3));
        short8 b1 = *(const short8*)(pwb + ((size_t)((4 + ks) * 64 + lane) << 3));
        acc0 = __builtin_amdgcn_mfma_f32_32x32x16_bf16(af, b0, acc0, 0, 0, 0);
        acc1 = __builtin_amdgcn_mfma_f32_32x32x16_bf16(af, b1, acc1, 0, 0, 0);
    }
    int och = lane & 31;
    float bias0 = pb[och], bias1 = pb[32 + och];
    #pragma unroll
    for (int r = 0; r < 16; r++) {
        int p = (r & 3) + ((r >> 2) << 3) + ((lane >> 5) << 2);
        size_t base = ((size_t)(b << 16) + n0 + p) << 6;
        pf[base + och]      = f2b(fmaxf(acc0[r] + bias0, 0.f));
        pf[base + 32 + och] = f2b(fmaxf(acc1[r] + bias1, 0.f));
    }
}

// devox gather + pfeat load + collapsed attention + fuse.
__global__ __launch_bounds__(256) void k_final(const float* __restrict__ cb3,
        const unsigned short* __restrict__ gb, const unsigned short* __restrict__ pfeat,
        const float* __restrict__ ws, float* __restrict__ out) {
    __shared__ float sq[256];
    int tid = threadIdx.x;
    int l = tid & 63;
    int g = tid >> 6;
    int o0 = g << 4;
    int b = blockIdx.y;
    int n = (blockIdx.x << 6) + l;
    int gid = (b << 16) + n;
    float c0 = cb3[gid * 3], c1 = cb3[gid * 3 + 1], c2 = cb3[gid * 3 + 2];
    int lx = (int)floorf(c0), ly = (int)floorf(c1), lz = (int)floorf(c2);
    int hx = min(lx + 1, 31), hy = min(ly + 1, 31), hz = min(lz + 1, 31);
    float fx = c0 - (float)lx, fy = c1 - (float)ly, fz = c2 - (float)lz;
    int xs[2] = {lx, hx}; float wxx[2] = {1.f - fx, fx};
    int ys[2] = {ly, hy}; float wyy[2] = {1.f - fy, fy};
    int zs[2] = {lz, hz}; float wzz[2] = {1.f - fz, fz};
    float vf[16];
    #pragma unroll
    for (int j = 0; j < 16; j++) vf[j] = 0.f;
    #pragma unroll
    for (int ii = 0; ii < 2; ii++)
    #pragma unroll
    for (int jj = 0; jj < 2; jj++)
    #pragma unroll
    for (int kk = 0; kk < 2; kk++) {
        float wgt = wxx[ii] * wyy[jj] * wzz[kk];
        const unsigned short* gp = gb + (((size_t)b * 1024 + xs[ii] * 32 + ys[jj]) << 11)
                                      + ((size_t)g << 9) + zs[kk] * 8;
        short8 v0 = *(const short8*)(gp);
        short8 v1 = *(const short8*)(gp + 256);
        #pragma unroll
        for (int j = 0; j < 8; j++) {
            vf[j]     += wgt * b2f((unsigned short)v0[j]);
            vf[8 + j] += wgt * b2f((unsigned short)v1[j]);
        }
    }
    float pf[16];
    const unsigned short* pp = pfeat + ((size_t)gid << 6) + o0;
    short8 p0 = *(const short8*)pp;
    short8 p1 = *(const short8*)(pp + 8);
    #pragma unroll
    for (int j = 0; j < 8; j++) {
        pf[j]     = b2f((unsigned short)p0[j]);
        pf[8 + j] = b2f((unsigned short)p1[j]);
    }
    const float* wae = ws + OFF_WAE + o0;
    const float* wbe = ws + OFF_WBE + o0;
    float part = 0.f;
    #pragma unroll
    for (int j = 0; j < 16; j++) part += wae[j] * vf[j] + wbe[j] * pf[j];
    sq[tid] = part;
    __syncthreads();
    float q = sq[l] + sq[l + 64] + sq[l + 128] + sq[l + 192] + ws[OFF_Q0];
    float attn = 1.0f + 1.0f / (1.0f + expf(-q));
    float* op = out + (size_t)(b * 64 + o0) * NPT + n;
    #pragma unroll
    for (int j = 0; j < 16; j++) op[(size_t)j * NPT] = vf[j] * attn + pf[j];
}

extern "C" void kernel_launch(void* const* d_in, const int* in_sizes, int n_in,
                              void* d_out, int out_size, void* d_ws, size_t ws_size,
                              hipStream_t stream) {
    const float* features = (const float*)d_in[0];
    const float* coords   = (const float*)d_in[1];
    const float* vconv_w  = (const float*)d_in[2];
    const float* vconv_b  = (const float*)d_in[3];
    const float* vbn_g    = (const float*)d_in[4];
    const float* vbn_b    = (const float*)d_in[5];
    const float* res_w    = (const float*)d_in[6];
    const float* res_b    = (const float*)d_in[7];
    const float* res_bn_g = (const float*)d_in[8];
    const float* res_bn_b = (const float*)d_in[9];
    const float* pf_w     = (const float*)d_in[10];
    const float* pf_b     = (const float*)d_in[11];
    const float* pf_bn_g  = (const float*)d_in[12];
    const float* pf_bn_b  = (const float*)d_in[13];
    const float* attn_wa  = (const float*)d_in[14];
    const float* attn_ba  = (const float*)d_in[15];
    const float* attn_wb  = (const float*)d_in[16];
    const float* attn_bb  = (const float*)d_in[17];
    const float* attn_wc  = (const float*)d_in[18];
    const float* attn_bc  = (const float*)d_in[19];
    float* ws  = (float*)d_ws;
    float* out = (float*)d_out;

    unsigned short* WB  = (unsigned short*)(ws + OFF_WB16);
    unsigned short* PWB = (unsigned short*)(ws + OFF_PWB);
    int*            CUR = (int*)(ws + OFF_CUR);
    int*            AUX = (int*)(ws + OFF_AUX);
    unsigned short* ORD = (unsigned short*)(ws + OFF_ORD);
    unsigned short* FT  = (unsigned short*)(ws + OFF_GA);   // pre-conv overlay
    unsigned short* PF  = (unsigned short*)(ws + OFF_GA);   // post-conv overlay
    float* GA = ws + OFF_GA;
    unsigned short* G0 = (unsigned short*)(ws + OFF_G0);
    unsigned short* G1 = (unsigned short*)(ws + OFF_G1);
    const float* Bv = ws + OFF_BEFF;

    k_fold_w<<<2160, 256, 0, stream>>>(vconv_w, vbn_g, res_w, res_bn_g, WB);
    k_misc<<<19, 256, 0, stream>>>(vconv_b, vbn_g, vbn_b, res_b, res_bn_g, res_bn_b,
                                   pf_w, pf_b, pf_bn_g, pf_bn_b,
                                   attn_wa, attn_ba, attn_wb, attn_bb, attn_wc, attn_bc, ws);
    k_zero<<<128, 256, 0, stream>>>((float4*)CUR, 32768);
    k_mean1<<<96, 256, 0, stream>>>(coords, ws + OFF_PART);
    k_mean2<<<1, 64, 0, stream>>>(ws + OFF_PART, ws + OFF_MEAN);
    k_maxn1<<<32, 256, 0, stream>>>(coords, ws + OFF_MEAN, ws + OFF_PART);
    k_maxn2<<<1, 64, 0, stream>>>(ws + OFF_PART, ws + OFF_MAXN);
    k_prep<<<1024, 256, 0, stream>>>(coords, ws + OFF_MEAN, ws + OFF_MAXN,
                                     ws + OFF_CB3, CUR);
    k_scan1<<<256, 256, 0, stream>>>(CUR, AUX);
    k_scan2<<<1, 256, 0, stream>>>(AUX);
    k_scan3<<<256, 256, 0, stream>>>(CUR, AUX);
    k_trans<<<4096, 256, 0, stream>>>(features, FT);
    k_place<<<1024, 256, 0, stream>>>(ws + OFF_CB3, CUR, ORD);
    k_gather<<<32768, 256, 0, stream>>>(CUR, ORD, FT, G0);

    dim3 cg(256, 4);
    k_conv<<<cg, 256, 0, stream>>>(G0, WB + 0 * 110592, Bv + 0,   nullptr, GA,      G1);
    k_conv<<<cg, 256, 0, stream>>>(G1, WB + 1 * 110592, Bv + 64,  nullptr, nullptr, G0);
    k_conv<<<cg, 256, 0, stream>>>(G0, WB + 2 * 110592, Bv + 128, GA,      GA,      G1);
    k_conv<<<cg, 256, 0, stream>>>(G1, WB + 3 * 110592, Bv + 192, nullptr, nullptr, G0);
    k_conv<<<cg, 256, 0, stream>>>(G0, WB + 4 * 110592, Bv + 256, GA,      nullptr, G1);

    k_pfeat<<<2048, 256, 0, stream>>>(features, ws + OFF_PB, PWB, PF);

    dim3 fg(1024, 4);
    k_final<<<fg, 256, 0, stream>>>(ws + OFF_CB3, G1, PF, ws, out);
}

// Round 6
// 563.520 us; speedup vs baseline: 21.0905x; 1.0301x over previous
//
#include <hip/hip_runtime.h>
#include <math.h>

#define NPT 65536
#define NB 4
#define R3 32768

typedef __attribute__((ext_vector_type(8))) short short8;
typedef __attribute__((ext_vector_type(16))) float f32x16;

// ws layout (float offsets)
#define OFF_WB16 0          // 276480 floats = 552960 bf16: 5 conv layers, B-frag order
#define OFF_BEFF 276480     // 5*64 conv biases (BN-folded)
#define OFF_PWB  276800     // 2048 floats = 4096 bf16: point-branch weights, B-frag order
#define OFF_PB   280896     // 64
#define OFF_WAE  280960     // 64
#define OFF_WBE  281024     // 64
#define OFF_Q0   281088     // 1 (+pad)
#define OFF_MEAN 281104     // 12
#define OFF_MAXN 281116     // 4
#define OFF_PART 281120     // 128 reduction partials (96 mean + 32 max)
#define OFF_AUX  281248     // 256 scan block sums (int)
#define OFF_CB3  281504     // 786432: 3 floats/point normalized coords
#define OFF_CUR  1067936    // 131072 int cursor
#define OFF_ORD  1199008    // 131072 floats = 262144 ushort sorted point ids
#define OFF_GA   1330080    // 8388608 fp32 residual; FT bf16 overlays pre-conv; PF bf16 overlays post-conv
#define OFF_G0   9718688    // 4194304 floats = 8388608 bf16 swizzled grid ping
#define OFF_G1   13912992   // 4194304 floats = 8388608 bf16 swizzled grid pong

__device__ __forceinline__ unsigned short f2b(float f) {
    union { float f; unsigned int u; } v; v.f = f;
    unsigned int r = v.u + 0x7fffu + ((v.u >> 16) & 1u);
    return (unsigned short)(r >> 16);
}
__device__ __forceinline__ float b2f(unsigned short u) {
    union { unsigned int u; float f; } v; v.u = ((unsigned int)u) << 16; return v.f;
}

__global__ void k_fold_w(const float* __restrict__ vconv_w, const float* __restrict__ vbn_g,
                         const float* __restrict__ res_w, const float* __restrict__ res_bn_g,
                         unsigned short* __restrict__ wb16) {
    int idx = blockIdx.x * 256 + threadIdx.x;
    if (idx >= 5 * 27 * 4 * 2 * 64 * 8) return;
    int j = idx & 7;
    int l = (idx >> 3) & 63;
    int nh = (idx >> 9) & 1;
    int ks = (idx >> 10) & 3;
    int rest = idx >> 12;          // layer*27 + t
    int t = rest % 27;
    int layer = rest / 27;
    int i = ks * 16 + ((l >> 5) << 3) + j;
    int o = nh * 32 + (l & 31);
    const float invs = rsqrtf(1.00001f);
    float scale, wsrc;
    if (layer == 0) {
        scale = vbn_g[o] * invs;
        wsrc = vconv_w[(o * 64 + i) * 27 + t];
    } else {
        scale = res_bn_g[(layer - 1) * 64 + o] * invs;
        wsrc = res_w[(size_t)(layer - 1) * 110592 + (o * 64 + i) * 27 + t];
    }
    wb16[idx] = f2b(wsrc * scale);
}

__global__ void k_misc(const float* __restrict__ vconv_b, const float* __restrict__ vbn_g,
                       const float* __restrict__ vbn_b,
                       const float* __restrict__ res_b, const float* __restrict__ res_bn_g,
                       const float* __restrict__ res_bn_b,
                       const float* __restrict__ pf_w, const float* __restrict__ pf_b,
                       const float* __restrict__ pf_bn_g, const float* __restrict__ pf_bn_b,
                       const float* __restrict__ wa, const float* __restrict__ ba,
                       const float* __restrict__ wb, const float* __restrict__ bb,
                       const float* __restrict__ wc, const float* __restrict__ bc,
                       float* __restrict__ ws) {
    int idx = blockIdx.x * 256 + threadIdx.x;
    const float invs = rsqrtf(1.00001f);
    if (idx < 320) {
        int l = idx >> 6, o = idx & 63;
        float b_, g_, s_;
        if (l == 0) { b_ = vconv_b[o]; g_ = vbn_g[o]; s_ = vbn_b[o]; }
        else {
            b_ = res_b[(l - 1) * 64 + o];
            g_ = res_bn_g[(l - 1) * 64 + o];
            s_ = res_bn_b[(l - 1) * 64 + o];
        }
        ws[OFF_BEFF + idx] = b_ * g_ * invs + s_;
    } else if (idx < 4416) {
        int e = idx - 320;                 // 0..4095
        int j = e & 7;
        int lane = (e >> 3) & 63;
        int ks = (e >> 9) & 3;
        int half = e >> 11;
        int i = ks * 16 + ((lane >> 5) << 3) + j;
        int o = half * 32 + (lane & 31);
        ((unsigned short*)(ws + OFF_PWB))[e] = f2b(pf_w[o * 64 + i] * pf_bn_g[o] * invs);
    } else if (idx < 4480) {
        int o = idx - 4416;
        ws[OFF_PB + o] = pf_b[o] * pf_bn_g[o] * invs + pf_bn_b[o];
    } else if (idx < 4544) {
        int o = idx - 4480;
        float s = 0.f;
        for (int j = 0; j < 16; j++) s += wc[j] * wa[j * 64 + o];
        ws[OFF_WAE + o] = s;
    } else if (idx < 4608) {
        int o = idx - 4544;
        float s = 0.f;
        for (int j = 0; j < 16; j++) s += wc[16 + j] * wb[j * 64 + o];
        ws[OFF_WBE + o] = s;
    } else if (idx == 4608) {
        float s = bc[0];
        for (int j = 0; j < 16; j++) s += wc[j] * ba[j] + wc[16 + j] * bb[j];
        ws[OFF_Q0] = s;
    }
}

__global__ void k_zero(float4* __restrict__ p, int n4) {
    int i = blockIdx.x * 256 + threadIdx.x;
    if (i < n4) p[i] = make_float4(0.f, 0.f, 0.f, 0.f);
}

// stage-1 mean partials: 96 blocks = 12 (b,d) x 8 chunks of 8192
__global__ __launch_bounds__(256) void k_mean1(const float* __restrict__ coords,
                                               float* __restrict__ part) {
    __shared__ float sm[256];
    int bd = blockIdx.x >> 3, chunk = blockIdx.x & 7;
    int tid = threadIdx.x;
    const float* p = coords + (size_t)bd * NPT + chunk * 8192;
    float s = 0.f;
    for (int n = tid; n < 8192; n += 256) s += p[n];
    sm[tid] = s; __syncthreads();
    for (int st = 128; st > 0; st >>= 1) {
        if (tid < st) sm[tid] += sm[tid + st];
        __syncthreads();
    }
    if (tid == 0) part[blockIdx.x] = sm[0];
}

__global__ void k_mean2(const float* __restrict__ part, float* __restrict__ mean) {
    int t = threadIdx.x;
    if (t < 12) {
        float s = 0.f;
        for (int c = 0; c < 8; c++) s += part[t * 8 + c];
        mean[t] = s * (1.0f / NPT);
    }
}

// stage-1 max-norm^2 partials: 32 blocks = 4 b x 8 chunks
__global__ __launch_bounds__(256) void k_maxn1(const float* __restrict__ coords,
                                               const float* __restrict__ mean,
                                               float* __restrict__ part) {
    __shared__ float sm[256];
    int b = blockIdx.x >> 3, chunk = blockIdx.x & 7;
    int tid = threadIdx.x;
    float m0 = mean[b * 3], m1 = mean[b * 3 + 1], m2 = mean[b * 3 + 2];
    const float* p0 = coords + (size_t)(b * 3) * NPT + chunk * 8192;
    float mx = 0.f;
    for (int n = tid; n < 8192; n += 256) {
        float dx = p0[n] - m0, dy = p0[NPT + n] - m1, dz = p0[2 * NPT + n] - m2;
        mx = fmaxf(mx, dx * dx + dy * dy + dz * dz);
    }
    sm[tid] = mx; __syncthreads();
    for (int st = 128; st > 0; st >>= 1) {
        if (tid < st) sm[tid] = fmaxf(sm[tid], sm[tid + st]);
        __syncthreads();
    }
    if (tid == 0) part[96 + blockIdx.x] = sm[0];
}

__global__ void k_maxn2(const float* __restrict__ part, float* __restrict__ maxn) {
    int t = threadIdx.x;
    if (t < 4) {
        float m = 0.f;
        for (int c = 0; c < 8; c++) m = fmaxf(m, part[96 + t * 8 + c]);
        maxn[t] = sqrtf(m);
    }
}

// per-point normalized coords + voxel histogram
__global__ void k_prep(const float* __restrict__ coords, const float* __restrict__ mean,
                       const float* __restrict__ maxn, float* __restrict__ cb3,
                       int* __restrict__ cursor) {
    int gid = blockIdx.x * 256 + threadIdx.x;
    int b = gid >> 16, n = gid & 65535;
    float inv = 0.5f / maxn[b];
    float c0 = (coords[(size_t)(b * 3) * NPT + n]     - mean[b * 3])     * inv + 0.5f;
    float c1 = (coords[(size_t)(b * 3 + 1) * NPT + n] - mean[b * 3 + 1]) * inv + 0.5f;
    float c2 = (coords[(size_t)(b * 3 + 2) * NPT + n] - mean[b * 3 + 2]) * inv + 0.5f;
    c0 = fminf(fmaxf(c0 * 32.f, 0.f), 31.f);
    c1 = fminf(fmaxf(c1 * 32.f, 0.f), 31.f);
    c2 = fminf(fmaxf(c2 * 32.f, 0.f), 31.f);
    cb3[gid * 3]     = c0;
    cb3[gid * 3 + 1] = c1;
    cb3[gid * 3 + 2] = c2;
    int vx = b * R3 + ((int)rintf(c0) * 1024 + (int)rintf(c1) * 32 + (int)rintf(c2));
    atomicAdd(&cursor[vx], 1);
}

// scan stage 1: 256 blocks x 512 bins -> local exclusive scan + block totals
__global__ void k_scan1(int* __restrict__ cur, int* __restrict__ aux) {
    __shared__ int sm[256];
    int t = threadIdx.x;
    int base = blockIdx.x * 512 + t * 2;
    int c0 = cur[base], c1 = cur[base + 1];
    int s = c0 + c1;
    sm[t] = s; __syncthreads();
    for (int off = 1; off < 256; off <<= 1) {
        int v = (t >= off) ? sm[t - off] : 0;
        __syncthreads();
        sm[t] += v;
        __syncthreads();
    }
    int ex = sm[t] - s;
    cur[base] = ex;
    cur[base + 1] = ex + c0;
    if (t == 255) aux[blockIdx.x] = sm[t];
}

// scan stage 2: exclusive scan of 256 block totals
__global__ void k_scan2(int* __restrict__ aux) {
    __shared__ int sm[256];
    int t = threadIdx.x;
    int v0 = aux[t];
    sm[t] = v0; __syncthreads();
    for (int off = 1; off < 256; off <<= 1) {
        int v = (t >= off) ? sm[t - off] : 0;
        __syncthreads();
        sm[t] += v;
        __syncthreads();
    }
    aux[t] = sm[t] - v0;
}

// scan stage 3: add block offsets
__global__ void k_scan3(int* __restrict__ cur, const int* __restrict__ aux) {
    int t = threadIdx.x;
    int add = aux[blockIdx.x];
    int base = blockIdx.x * 512 + t * 2;
    cur[base] += add;
    cur[base + 1] += add;
}

// features [B][64][N] fp32 -> FT [B][N][64] bf16 (LDS transpose)
__global__ __launch_bounds__(256) void k_trans(const float* __restrict__ feats,
                                               unsigned short* __restrict__ ft) {
    __shared__ float lds[64][65];
    int b = blockIdx.x >> 10;
    int n0 = (blockIdx.x & 1023) << 6;
    int tid = threadIdx.x;
    int nl = tid & 63;
    #pragma unroll
    for (int it = 0; it < 16; it++) {
        int ch = it * 4 + (tid >> 6);
        lds[nl][ch] = feats[((size_t)(b * 64 + ch) << 16) + n0 + nl];
    }
    __syncthreads();
    int nn = tid >> 2;
    int ch0 = (tid & 3) << 4;
    size_t obase = (((size_t)(b << 16) + n0 + nn) << 6) + ch0;
    short8 v0, v1;
    #pragma unroll
    for (int j = 0; j < 8; j++) v0[j] = (short)f2b(lds[nn][ch0 + j]);
    #pragma unroll
    for (int j = 0; j < 8; j++) v1[j] = (short)f2b(lds[nn][ch0 + 8 + j]);
    *(short8*)(ft + obase) = v0;
    *(short8*)(ft + obase + 8) = v1;
}

// place point ids into voxel-sorted order
__global__ void k_place(const float* __restrict__ cb3, int* __restrict__ cursor,
                        unsigned short* __restrict__ order) {
    int gid = blockIdx.x * 256 + threadIdx.x;
    int b = gid >> 16;
    float c0 = cb3[gid * 3], c1 = cb3[gid * 3 + 1], c2 = cb3[gid * 3 + 2];
    int vx = b * R3 + ((int)rintf(c0) * 1024 + (int)rintf(c1) * 32 + (int)rintf(c2));
    int slot = atomicAdd(&cursor[vx], 1);
    order[slot] = (unsigned short)(gid & 65535);
}

// one wave per voxel, point-parallel: lane = (point-slot p, ch-group g).
__global__ __launch_bounds__(256) void k_gather(const int* __restrict__ cursor,
        const unsigned short* __restrict__ order, const unsigned short* __restrict__ ft,
        unsigned short* __restrict__ g0) {
    int tid = threadIdx.x;
    int lane = tid & 63;
    int vx = blockIdx.x * 4 + (tid >> 6);
    int e = cursor[vx];
    int s = (vx == 0) ? 0 : cursor[vx - 1];
    int cnt = e - s;
    int p = lane >> 3;      // point slot 0..7
    int g = lane & 7;       // channel group 0..7 (8 channels each)
    int bb = vx >> 15;
    float acc[8] = {0.f, 0.f, 0.f, 0.f, 0.f, 0.f, 0.f, 0.f};
    for (int base = s; base < e; base += 8) {
        int idx = base + p;
        if (idx < e) {
            int n = order[idx];
            const unsigned short* fp = ft + (((size_t)(bb << 16) + n) << 6) + (g << 3);
            short8 v = *(const short8*)fp;
            #pragma unroll
            for (int j = 0; j < 8; j++) acc[j] += b2f((unsigned short)v[j]);
        }
    }
    #pragma unroll
    for (int j = 0; j < 8; j++) {
        acc[j] += __shfl_xor(acc[j], 8, 64);
        acc[j] += __shfl_xor(acc[j], 16, 64);
        acc[j] += __shfl_xor(acc[j], 32, 64);
    }
    if (p == 0) {
        float inv = 1.0f / (float)max(cnt, 1);
        int col = vx >> 5, z = vx & 31;
        short8 o8;
        #pragma unroll
        for (int j = 0; j < 8; j++) o8[j] = (short)f2b(acc[j] * inv);
        *(short8*)(g0 + (size_t)col * 2048 + (g << 8) + z * 8) = o8;
    }
}

// MFMA implicit-GEMM 3^3 conv, 4 columns/block.
// 4 waves: (column-pair, out-ch-half). 18 staged columns (72KB LDS) via global_load_lds.
__global__ __launch_bounds__(256) void k_conv(const unsigned short* __restrict__ in,
        const unsigned short* __restrict__ w, const float* __restrict__ bias,
        const float* __restrict__ idF, float* __restrict__ outF,
        unsigned short* __restrict__ out) {
    __shared__ unsigned short sA[18 * 2048];    // 72 KB
    int tid = threadIdx.x;
    int lane = tid & 63;
    int wid = tid >> 6;
    int cp = wid & 1;          // column pair: y0+2cp, y0+2cp+1
    int nh = wid >> 1;         // out-channel half
    int tile = blockIdx.x;     // 0..255
    int b = blockIdx.y;
    int x = tile >> 3;
    int y0 = (tile & 7) << 2;
    // stage 18 columns: async global->LDS (wave-uniform LDS base + lane*16B)
    #pragma unroll 1
    for (int s = 0; s < 18; s++) {
        int gx = x + s / 6 - 1;
        int gy = y0 + s % 6 - 1;
        if ((unsigned)gx < 32u && (unsigned)gy < 32u) {
            const unsigned short* gsrc = in + (((size_t)b * 1024 + gx * 32 + gy) << 11)
                                            + ((size_t)tid << 3);
            __builtin_amdgcn_global_load_lds(
                (const __attribute__((address_space(1))) unsigned int*)gsrc,
                (__attribute__((address_space(3))) unsigned int*)(sA + s * 2048 + (wid << 9)),
                16, 0, 0);
        } else {
            ((float4*)(sA + s * 2048))[tid] = make_float4(0.f, 0.f, 0.f, 0.f);
        }
    }
    __syncthreads();
    f32x16 accA = {}, accB = {};
    const short8 zero8 = {0, 0, 0, 0, 0, 0, 0, 0};
    int half = lane >> 5;
    #pragma unroll 1
    for (int t = 0; t < 27; t++) {
        int dxi = t / 9, dyi = (t / 3) % 3, dz = t % 3 - 1;
        int s0 = dxi * 6 + dyi + cp * 2;
        int zz = (lane & 31) + dz;
        bool zv = (unsigned)zz < 32u;
        int zc = zv ? zz : 0;
        const unsigned short* ac = sA + s0 * 2048 + (half << 8) + zc * 8;
        const unsigned short* wp = w + t * 4096 + nh * 512 + lane * 8;
        #pragma unroll
        for (int ks = 0; ks < 4; ks++) {
            short8 bf = *(const short8*)(wp + ks * 1024);
            short8 a0 = *(const short8*)(ac + ks * 512);
            short8 a1 = *(const short8*)(ac + 2048 + ks * 512);
            if (!zv) { a0 = zero8; a1 = zero8; }
            accA = __builtin_amdgcn_mfma_f32_32x32x16_bf16(a0, bf, accA, 0, 0, 0);
            accB = __builtin_amdgcn_mfma_f32_32x32x16_bf16(a1, bf, accB, 0, 0, 0);
        }
    }
    int o = nh * 32 + (lane & 31);
    float bb = bias[o];
    #pragma unroll
    for (int cc = 0; cc < 2; cc++) {
        int outcol = b * 1024 + x * 32 + (y0 + cp * 2 + cc);
        size_t obase = ((size_t)outcol << 11) + (size_t)((o >> 3) << 8) + (o & 7);
        const f32x16& acc = cc ? accB : accA;
        #pragma unroll
        for (int r = 0; r < 16; r++) {
            int z = (r & 3) + ((r >> 2) << 3) + ((lane >> 5) << 2);
            size_t oe = obase + (size_t)z * 8;
            float v = acc[r] + bb;
            if (idF) v += idF[oe];
            v = fmaxf(v, 0.f);
            out[oe] = f2b(v);
            if (outF) outF[oe] = v;
        }
    }
}

// point-branch MLP via MFMA: pfeat[B][N][64] bf16 = relu(PW * feat + PB)
__global__ __launch_bounds__(256) void k_pfeat(const float* __restrict__ feats,
        const float* __restrict__ pb, const unsigned short* __restrict__ pwb,
        unsigned short* __restrict__ pf) {
    int tid = threadIdx.x;
    int lane = tid & 63;
    int wv = tid >> 6;
    int tile = blockIdx.x * 4 + wv;          // 0..8191
    int b = tile >> 11;
    int n0 = (tile & 2047) << 5;
    int m = lane & 31, kg = lane >> 5;
    const float* fb = feats + ((size_t)b << 22) + n0 + m;
    f32x16 acc0 = {}, acc1 = {};
    #pragma unroll
    for (int ks = 0; ks < 4; ks++) {
        short8 af;
        #pragma unroll
        for (int j = 0; j < 8; j++)
            af[j] = (short)f2b(fb[(size_t)(ks * 16 + kg * 8 + j) << 16]);
        short8 b0 = *(const short8*)(pwb + ((size_t)(ks * 64 + lane) << 3));
        short8 b1 = *(const short8*)(pwb + ((size_t)((4 + ks) * 64 + lane) << 3));
        acc0 = __builtin_amdgcn_mfma_f32_32x32x16_bf16(af, b0, acc0, 0, 0, 0);
        acc1 = __builtin_amdgcn_mfma_f32_32x32x16_bf16(af, b1, acc1, 0, 0, 0);
    }
    int och = lane & 31;
    float bias0 = pb[och], bias1 = pb[32 + och];
    #pragma unroll
    for (int r = 0; r < 16; r++) {
        int p = (r & 3) + ((r >> 2) << 3) + ((lane >> 5) << 2);
        size_t base = ((size_t)(b << 16) + n0 + p) << 6;
        pf[base + och]      = f2b(fmaxf(acc0[r] + bias0, 0.f));
        pf[base + 32 + och] = f2b(fmaxf(acc1[r] + bias1, 0.f));
    }
}

// devox gather + pfeat load + collapsed attention + fuse.
// 256 threads = 32 points x 8 channel-groups (8 ch each).
__global__ __launch_bounds__(256) void k_final(const float* __restrict__ cb3,
        const unsigned short* __restrict__ gb, const unsigned short* __restrict__ pfeat,
        const float* __restrict__ ws, float* __restrict__ out) {
    __shared__ float sq[256];
    int tid = threadIdx.x;
    int p = tid & 31;       // point within block
    int g = tid >> 5;       // channel group 0..7
    int b = blockIdx.y;
    int n = (blockIdx.x << 5) + p;
    int gid = (b << 16) + n;
    float c0 = cb3[gid * 3], c1 = cb3[gid * 3 + 1], c2 = cb3[gid * 3 + 2];
    int lx = (int)floorf(c0), ly = (int)floorf(c1), lz = (int)floorf(c2);
    int hx = min(lx + 1, 31), hy = min(ly + 1, 31), hz = min(lz + 1, 31);
    float fx = c0 - (float)lx, fy = c1 - (float)ly, fz = c2 - (float)lz;
    int xs[2] = {lx, hx}; float wxx[2] = {1.f - fx, fx};
    int ys[2] = {ly, hy}; float wyy[2] = {1.f - fy, fy};
    int zs[2] = {lz, hz}; float wzz[2] = {1.f - fz, fz};
    float vf[8];
    #pragma unroll
    for (int j = 0; j < 8; j++) vf[j] = 0.f;
    #pragma unroll
    for (int ii = 0; ii < 2; ii++)
    #pragma unroll
    for (int jj = 0; jj < 2; jj++)
    #pragma unroll
    for (int kk = 0; kk < 2; kk++) {
        float wgt = wxx[ii] * wyy[jj] * wzz[kk];
        const unsigned short* gp = gb + (((size_t)b * 1024 + xs[ii] * 32 + ys[jj]) << 11)
                                      + (g << 8) + zs[kk] * 8;
        short8 v = *(const short8*)gp;
        #pragma unroll
        for (int j = 0; j < 8; j++) vf[j] += wgt * b2f((unsigned short)v[j]);
    }
    float pfv[8];
    const unsigned short* pp = pfeat + ((size_t)gid << 6) + (g << 3);
    short8 pv = *(const short8*)pp;
    #pragma unroll
    for (int j = 0; j < 8; j++) pfv[j] = b2f((unsigned short)pv[j]);
    const float* wae = ws + OFF_WAE + (g << 3);
    const float* wbe = ws + OFF_WBE + (g << 3);
    float part = 0.f;
    #pragma unroll
    for (int j = 0; j < 8; j++) part += wae[j] * vf[j] + wbe[j] * pfv[j];
    sq[tid] = part;
    __syncthreads();
    float q = ws[OFF_Q0];
    #pragma unroll
    for (int gg = 0; gg < 8; gg++) q += sq[(gg << 5) + p];
    float attn = 1.0f + 1.0f / (1.0f + expf(-q));
    float* op = out + (((size_t)(b * 64 + (g << 3))) << 16) + n;
    #pragma unroll
    for (int j = 0; j < 8; j++) op[(size_t)j << 16] = vf[j] * attn + pfv[j];
}

extern "C" void kernel_launch(void* const* d_in, const int* in_sizes, int n_in,
                              void* d_out, int out_size, void* d_ws, size_t ws_size,
                              hipStream_t stream) {
    const float* features = (const float*)d_in[0];
    const float* coords   = (const float*)d_in[1];
    const float* vconv_w  = (const float*)d_in[2];
    const float* vconv_b  = (const float*)d_in[3];
    const float* vbn_g    = (const float*)d_in[4];
    const float* vbn_b    = (const float*)d_in[5];
    const float* res_w    = (const float*)d_in[6];
    const float* res_b    = (const float*)d_in[7];
    const float* res_bn_g = (const float*)d_in[8];
    const float* res_bn_b = (const float*)d_in[9];
    const float* pf_w     = (const float*)d_in[10];
    const float* pf_b     = (const float*)d_in[11];
    const float* pf_bn_g  = (const float*)d_in[12];
    const float* pf_bn_b  = (const float*)d_in[13];
    const float* attn_wa  = (const float*)d_in[14];
    const float* attn_ba  = (const float*)d_in[15];
    const float* attn_wb  = (const float*)d_in[16];
    const float* attn_bb  = (const float*)d_in[17];
    const float* attn_wc  = (const float*)d_in[18];
    const float* attn_bc  = (const float*)d_in[19];
    float* ws  = (float*)d_ws;
    float* out = (float*)d_out;

    unsigned short* WB  = (unsigned short*)(ws + OFF_WB16);
    unsigned short* PWB = (unsigned short*)(ws + OFF_PWB);
    int*            CUR = (int*)(ws + OFF_CUR);
    int*            AUX = (int*)(ws + OFF_AUX);
    unsigned short* ORD = (unsigned short*)(ws + OFF_ORD);
    unsigned short* FT  = (unsigned short*)(ws + OFF_GA);   // pre-conv overlay
    unsigned short* PF  = (unsigned short*)(ws + OFF_GA);   // post-conv overlay
    float* GA = ws + OFF_GA;
    unsigned short* G0 = (unsigned short*)(ws + OFF_G0);
    unsigned short* G1 = (unsigned short*)(ws + OFF_G1);
    const float* Bv = ws + OFF_BEFF;

    k_fold_w<<<2160, 256, 0, stream>>>(vconv_w, vbn_g, res_w, res_bn_g, WB);
    k_misc<<<19, 256, 0, stream>>>(vconv_b, vbn_g, vbn_b, res_b, res_bn_g, res_bn_b,
                                   pf_w, pf_b, pf_bn_g, pf_bn_b,
                                   attn_wa, attn_ba, attn_wb, attn_bb, attn_wc, attn_bc, ws);
    k_zero<<<128, 256, 0, stream>>>((float4*)CUR, 32768);
    k_mean1<<<96, 256, 0, stream>>>(coords, ws + OFF_PART);
    k_mean2<<<1, 64, 0, stream>>>(ws + OFF_PART, ws + OFF_MEAN);
    k_maxn1<<<32, 256, 0, stream>>>(coords, ws + OFF_MEAN, ws + OFF_PART);
    k_maxn2<<<1, 64, 0, stream>>>(ws + OFF_PART, ws + OFF_MAXN);
    k_prep<<<1024, 256, 0, stream>>>(coords, ws + OFF_MEAN, ws + OFF_MAXN,
                                     ws + OFF_CB3, CUR);
    k_scan1<<<256, 256, 0, stream>>>(CUR, AUX);
    k_scan2<<<1, 256, 0, stream>>>(AUX);
    k_scan3<<<256, 256, 0, stream>>>(CUR, AUX);
    k_trans<<<4096, 256, 0, stream>>>(features, FT);
    k_place<<<1024, 256, 0, stream>>>(ws + OFF_CB3, CUR, ORD);
    k_gather<<<32768, 256, 0, stream>>>(CUR, ORD, FT, G0);

    dim3 cg(256, 4);
    k_conv<<<cg, 256, 0, stream>>>(G0, WB + 0 * 110592, Bv + 0,   nullptr, GA,      G1);
    k_conv<<<cg, 256, 0, stream>>>(G1, WB + 1 * 110592, Bv + 64,  nullptr, nullptr, G0);
    k_conv<<<cg, 256, 0, stream>>>(G0, WB + 2 * 110592, Bv + 128, GA,      GA,      G1);
    k_conv<<<cg, 256, 0, stream>>>(G1, WB + 3 * 110592, Bv + 192, nullptr, nullptr, G0);
    k_conv<<<cg, 256, 0, stream>>>(G0, WB + 4 * 110592, Bv + 256, GA,      nullptr, G1);

    k_pfeat<<<2048, 256, 0, stream>>>(features, ws + OFF_PB, PWB, PF);

    dim3 fg(2048, 4);
    k_final<<<fg, 256, 0, stream>>>(ws + OFF_CB3, G1, PF, ws, out);
}

// Round 7
// 554.469 us; speedup vs baseline: 21.4348x; 1.0163x over previous
//
#include <hip/hip_runtime.h>
#include <math.h>

#define NPT 65536
#define NB 4
#define R3 32768

typedef __attribute__((ext_vector_type(8))) short short8;
typedef __attribute__((ext_vector_type(16))) float f32x16;

// ws layout (float offsets)
#define OFF_WB16 0          // 276480 floats = 552960 bf16: 5 conv layers, B-frag order
#define OFF_BEFF 276480     // 5*64 conv biases (BN-folded)
#define OFF_PWB  276800     // 2048 floats = 4096 bf16: point-branch weights, B-frag order
#define OFF_PB   280896     // 64
#define OFF_WAE  280960     // 64
#define OFF_WBE  281024     // 64
#define OFF_Q0   281088     // 1 (+pad)
#define OFF_MEAN 281104     // 12
#define OFF_MAXN 281116     // 4
#define OFF_PART 281120     // 128 reduction partials (96 mean + 32 max)
#define OFF_AUX  281248     // 256 scan block sums (int)
#define OFF_CB3  281504     // 786432: 3 floats/point normalized coords
#define OFF_CUR  1067936    // 131072 int cursor
#define OFF_ORD  1199008    // 131072 floats = 262144 ushort sorted point ids
#define OFF_GA   1330080    // 8388608 fp32 residual; FT bf16 overlays pre-conv; PF bf16 overlays post-conv
#define OFF_G0   9718688    // 4194304 floats = 8388608 bf16 swizzled grid ping
#define OFF_G1   13912992   // 4194304 floats = 8388608 bf16 swizzled grid pong

__device__ __forceinline__ unsigned short f2b(float f) {
    union { float f; unsigned int u; } v; v.f = f;
    unsigned int r = v.u + 0x7fffu + ((v.u >> 16) & 1u);
    return (unsigned short)(r >> 16);
}
__device__ __forceinline__ float b2f(unsigned short u) {
    union { unsigned int u; float f; } v; v.u = ((unsigned int)u) << 16; return v.f;
}

__global__ void k_fold_w(const float* __restrict__ vconv_w, const float* __restrict__ vbn_g,
                         const float* __restrict__ res_w, const float* __restrict__ res_bn_g,
                         unsigned short* __restrict__ wb16) {
    int idx = blockIdx.x * 256 + threadIdx.x;
    if (idx >= 5 * 27 * 4 * 2 * 64 * 8) return;
    int j = idx & 7;
    int l = (idx >> 3) & 63;
    int nh = (idx >> 9) & 1;
    int ks = (idx >> 10) & 3;
    int rest = idx >> 12;          // layer*27 + t
    int t = rest % 27;
    int layer = rest / 27;
    int i = ks * 16 + ((l >> 5) << 3) + j;
    int o = nh * 32 + (l & 31);
    const float invs = rsqrtf(1.00001f);
    float scale, wsrc;
    if (layer == 0) {
        scale = vbn_g[o] * invs;
        wsrc = vconv_w[(o * 64 + i) * 27 + t];
    } else {
        scale = res_bn_g[(layer - 1) * 64 + o] * invs;
        wsrc = res_w[(size_t)(layer - 1) * 110592 + (o * 64 + i) * 27 + t];
    }
    wb16[idx] = f2b(wsrc * scale);
}

__global__ void k_misc(const float* __restrict__ vconv_b, const float* __restrict__ vbn_g,
                       const float* __restrict__ vbn_b,
                       const float* __restrict__ res_b, const float* __restrict__ res_bn_g,
                       const float* __restrict__ res_bn_b,
                       const float* __restrict__ pf_w, const float* __restrict__ pf_b,
                       const float* __restrict__ pf_bn_g, const float* __restrict__ pf_bn_b,
                       const float* __restrict__ wa, const float* __restrict__ ba,
                       const float* __restrict__ wb, const float* __restrict__ bb,
                       const float* __restrict__ wc, const float* __restrict__ bc,
                       float* __restrict__ ws) {
    int idx = blockIdx.x * 256 + threadIdx.x;
    const float invs = rsqrtf(1.00001f);
    if (idx < 320) {
        int l = idx >> 6, o = idx & 63;
        float b_, g_, s_;
        if (l == 0) { b_ = vconv_b[o]; g_ = vbn_g[o]; s_ = vbn_b[o]; }
        else {
            b_ = res_b[(l - 1) * 64 + o];
            g_ = res_bn_g[(l - 1) * 64 + o];
            s_ = res_bn_b[(l - 1) * 64 + o];
        }
        ws[OFF_BEFF + idx] = b_ * g_ * invs + s_;
    } else if (idx < 4416) {
        int e = idx - 320;                 // 0..4095
        int j = e & 7;
        int lane = (e >> 3) & 63;
        int ks = (e >> 9) & 3;
        int half = e >> 11;
        int i = ks * 16 + ((lane >> 5) << 3) + j;
        int o = half * 32 + (lane & 31);
        ((unsigned short*)(ws + OFF_PWB))[e] = f2b(pf_w[o * 64 + i] * pf_bn_g[o] * invs);
    } else if (idx < 4480) {
        int o = idx - 4416;
        ws[OFF_PB + o] = pf_b[o] * pf_bn_g[o] * invs + pf_bn_b[o];
    } else if (idx < 4544) {
        int o = idx - 4480;
        float s = 0.f;
        for (int j = 0; j < 16; j++) s += wc[j] * wa[j * 64 + o];
        ws[OFF_WAE + o] = s;
    } else if (idx < 4608) {
        int o = idx - 4544;
        float s = 0.f;
        for (int j = 0; j < 16; j++) s += wc[16 + j] * wb[j * 64 + o];
        ws[OFF_WBE + o] = s;
    } else if (idx == 4608) {
        float s = bc[0];
        for (int j = 0; j < 16; j++) s += wc[j] * ba[j] + wc[16 + j] * bb[j];
        ws[OFF_Q0] = s;
    }
}

__global__ void k_zero(float4* __restrict__ p, int n4) {
    int i = blockIdx.x * 256 + threadIdx.x;
    if (i < n4) p[i] = make_float4(0.f, 0.f, 0.f, 0.f);
}

// stage-1 mean partials: 96 blocks = 12 (b,d) x 8 chunks of 8192
__global__ __launch_bounds__(256) void k_mean1(const float* __restrict__ coords,
                                               float* __restrict__ part) {
    __shared__ float sm[256];
    int bd = blockIdx.x >> 3, chunk = blockIdx.x & 7;
    int tid = threadIdx.x;
    const float* p = coords + (size_t)bd * NPT + chunk * 8192;
    float s = 0.f;
    for (int n = tid; n < 8192; n += 256) s += p[n];
    sm[tid] = s; __syncthreads();
    for (int st = 128; st > 0; st >>= 1) {
        if (tid < st) sm[tid] += sm[tid + st];
        __syncthreads();
    }
    if (tid == 0) part[blockIdx.x] = sm[0];
}

__global__ void k_mean2(const float* __restrict__ part, float* __restrict__ mean) {
    int t = threadIdx.x;
    if (t < 12) {
        float s = 0.f;
        for (int c = 0; c < 8; c++) s += part[t * 8 + c];
        mean[t] = s * (1.0f / NPT);
    }
}

// stage-1 max-norm^2 partials: 32 blocks = 4 b x 8 chunks
__global__ __launch_bounds__(256) void k_maxn1(const float* __restrict__ coords,
                                               const float* __restrict__ mean,
                                               float* __restrict__ part) {
    __shared__ float sm[256];
    int b = blockIdx.x >> 3, chunk = blockIdx.x & 7;
    int tid = threadIdx.x;
    float m0 = mean[b * 3], m1 = mean[b * 3 + 1], m2 = mean[b * 3 + 2];
    const float* p0 = coords + (size_t)(b * 3) * NPT + chunk * 8192;
    float mx = 0.f;
    for (int n = tid; n < 8192; n += 256) {
        float dx = p0[n] - m0, dy = p0[NPT + n] - m1, dz = p0[2 * NPT + n] - m2;
        mx = fmaxf(mx, dx * dx + dy * dy + dz * dz);
    }
    sm[tid] = mx; __syncthreads();
    for (int st = 128; st > 0; st >>= 1) {
        if (tid < st) sm[tid] = fmaxf(sm[tid], sm[tid + st]);
        __syncthreads();
    }
    if (tid == 0) part[96 + blockIdx.x] = sm[0];
}

__global__ void k_maxn2(const float* __restrict__ part, float* __restrict__ maxn) {
    int t = threadIdx.x;
    if (t < 4) {
        float m = 0.f;
        for (int c = 0; c < 8; c++) m = fmaxf(m, part[96 + t * 8 + c]);
        maxn[t] = sqrtf(m);
    }
}

// per-point normalized coords + voxel histogram
__global__ void k_prep(const float* __restrict__ coords, const float* __restrict__ mean,
                       const float* __restrict__ maxn, float* __restrict__ cb3,
                       int* __restrict__ cursor) {
    int gid = blockIdx.x * 256 + threadIdx.x;
    int b = gid >> 16, n = gid & 65535;
    float inv = 0.5f / maxn[b];
    float c0 = (coords[(size_t)(b * 3) * NPT + n]     - mean[b * 3])     * inv + 0.5f;
    float c1 = (coords[(size_t)(b * 3 + 1) * NPT + n] - mean[b * 3 + 1]) * inv + 0.5f;
    float c2 = (coords[(size_t)(b * 3 + 2) * NPT + n] - mean[b * 3 + 2]) * inv + 0.5f;
    c0 = fminf(fmaxf(c0 * 32.f, 0.f), 31.f);
    c1 = fminf(fmaxf(c1 * 32.f, 0.f), 31.f);
    c2 = fminf(fmaxf(c2 * 32.f, 0.f), 31.f);
    cb3[gid * 3]     = c0;
    cb3[gid * 3 + 1] = c1;
    cb3[gid * 3 + 2] = c2;
    int vx = b * R3 + ((int)rintf(c0) * 1024 + (int)rintf(c1) * 32 + (int)rintf(c2));
    atomicAdd(&cursor[vx], 1);
}

// scan stage 1: 256 blocks x 512 bins -> local exclusive scan + block totals
__global__ void k_scan1(int* __restrict__ cur, int* __restrict__ aux) {
    __shared__ int sm[256];
    int t = threadIdx.x;
    int base = blockIdx.x * 512 + t * 2;
    int c0 = cur[base], c1 = cur[base + 1];
    int s = c0 + c1;
    sm[t] = s; __syncthreads();
    for (int off = 1; off < 256; off <<= 1) {
        int v = (t >= off) ? sm[t - off] : 0;
        __syncthreads();
        sm[t] += v;
        __syncthreads();
    }
    int ex = sm[t] - s;
    cur[base] = ex;
    cur[base + 1] = ex + c0;
    if (t == 255) aux[blockIdx.x] = sm[t];
}

// scan stage 2: exclusive scan of 256 block totals
__global__ void k_scan2(int* __restrict__ aux) {
    __shared__ int sm[256];
    int t = threadIdx.x;
    int v0 = aux[t];
    sm[t] = v0; __syncthreads();
    for (int off = 1; off < 256; off <<= 1) {
        int v = (t >= off) ? sm[t - off] : 0;
        __syncthreads();
        sm[t] += v;
        __syncthreads();
    }
    aux[t] = sm[t] - v0;
}

// scan stage 3: add block offsets
__global__ void k_scan3(int* __restrict__ cur, const int* __restrict__ aux) {
    int t = threadIdx.x;
    int add = aux[blockIdx.x];
    int base = blockIdx.x * 512 + t * 2;
    cur[base] += add;
    cur[base + 1] += add;
}

// features [B][64][N] fp32 -> FT [B][N][64] bf16 (LDS transpose)
__global__ __launch_bounds__(256) void k_trans(const float* __restrict__ feats,
                                               unsigned short* __restrict__ ft) {
    __shared__ float lds[64][65];
    int b = blockIdx.x >> 10;
    int n0 = (blockIdx.x & 1023) << 6;
    int tid = threadIdx.x;
    int nl = tid & 63;
    #pragma unroll
    for (int it = 0; it < 16; it++) {
        int ch = it * 4 + (tid >> 6);
        lds[nl][ch] = feats[((size_t)(b * 64 + ch) << 16) + n0 + nl];
    }
    __syncthreads();
    int nn = tid >> 2;
    int ch0 = (tid & 3) << 4;
    size_t obase = (((size_t)(b << 16) + n0 + nn) << 6) + ch0;
    short8 v0, v1;
    #pragma unroll
    for (int j = 0; j < 8; j++) v0[j] = (short)f2b(lds[nn][ch0 + j]);
    #pragma unroll
    for (int j = 0; j < 8; j++) v1[j] = (short)f2b(lds[nn][ch0 + 8 + j]);
    *(short8*)(ft + obase) = v0;
    *(short8*)(ft + obase + 8) = v1;
}

// place point ids into voxel-sorted order
__global__ void k_place(const float* __restrict__ cb3, int* __restrict__ cursor,
                        unsigned short* __restrict__ order) {
    int gid = blockIdx.x * 256 + threadIdx.x;
    int b = gid >> 16;
    float c0 = cb3[gid * 3], c1 = cb3[gid * 3 + 1], c2 = cb3[gid * 3 + 2];
    int vx = b * R3 + ((int)rintf(c0) * 1024 + (int)rintf(c1) * 32 + (int)rintf(c2));
    int slot = atomicAdd(&cursor[vx], 1);
    order[slot] = (unsigned short)(gid & 65535);
}

// one wave per voxel, point-parallel: lane = (point-slot p, ch-group g).
__global__ __launch_bounds__(256) void k_gather(const int* __restrict__ cursor,
        const unsigned short* __restrict__ order, const unsigned short* __restrict__ ft,
        unsigned short* __restrict__ g0) {
    int tid = threadIdx.x;
    int lane = tid & 63;
    int vx = blockIdx.x * 4 + (tid >> 6);
    int e = cursor[vx];
    int s = (vx == 0) ? 0 : cursor[vx - 1];
    int cnt = e - s;
    int p = lane >> 3;      // point slot 0..7
    int g = lane & 7;       // channel group 0..7 (8 channels each)
    int bb = vx >> 15;
    float acc[8] = {0.f, 0.f, 0.f, 0.f, 0.f, 0.f, 0.f, 0.f};
    for (int base = s; base < e; base += 8) {
        int idx = base + p;
        if (idx < e) {
            int n = order[idx];
            const unsigned short* fp = ft + (((size_t)(bb << 16) + n) << 6) + (g << 3);
            short8 v = *(const short8*)fp;
            #pragma unroll
            for (int j = 0; j < 8; j++) acc[j] += b2f((unsigned short)v[j]);
        }
    }
    #pragma unroll
    for (int j = 0; j < 8; j++) {
        acc[j] += __shfl_xor(acc[j], 8, 64);
        acc[j] += __shfl_xor(acc[j], 16, 64);
        acc[j] += __shfl_xor(acc[j], 32, 64);
    }
    if (p == 0) {
        float inv = 1.0f / (float)max(cnt, 1);
        int col = vx >> 5, z = vx & 31;
        short8 o8;
        #pragma unroll
        for (int j = 0; j < 8; j++) o8[j] = (short)f2b(acc[j] * inv);
        *(short8*)(g0 + (size_t)col * 2048 + (g << 8) + z * 8) = o8;
    }
}

// MFMA implicit-GEMM 3^3 conv, 4 columns/block.
// 4 waves: (column-pair, out-ch-half). 18 staged columns (72KB LDS) via global_load_lds.
// zmaj: write output in devox-friendly z-major layout [col][z][64ch].
__global__ __launch_bounds__(256) void k_conv(const unsigned short* __restrict__ in,
        const unsigned short* __restrict__ w, const float* __restrict__ bias,
        const float* __restrict__ idF, float* __restrict__ outF,
        unsigned short* __restrict__ out, int zmaj) {
    __shared__ unsigned short sA[18 * 2048];    // 72 KB
    int tid = threadIdx.x;
    int lane = tid & 63;
    int wid = tid >> 6;
    int cp = wid & 1;          // column pair: y0+2cp, y0+2cp+1
    int nh = wid >> 1;         // out-channel half
    int tile = blockIdx.x;     // 0..255
    int b = blockIdx.y;
    int x = tile >> 3;
    int y0 = (tile & 7) << 2;
    #pragma unroll 1
    for (int s = 0; s < 18; s++) {
        int gx = x + s / 6 - 1;
        int gy = y0 + s % 6 - 1;
        if ((unsigned)gx < 32u && (unsigned)gy < 32u) {
            const unsigned short* gsrc = in + (((size_t)b * 1024 + gx * 32 + gy) << 11)
                                            + ((size_t)tid << 3);
            __builtin_amdgcn_global_load_lds(
                (const __attribute__((address_space(1))) unsigned int*)gsrc,
                (__attribute__((address_space(3))) unsigned int*)(sA + s * 2048 + (wid << 9)),
                16, 0, 0);
        } else {
            ((float4*)(sA + s * 2048))[tid] = make_float4(0.f, 0.f, 0.f, 0.f);
        }
    }
    __syncthreads();
    f32x16 accA = {}, accB = {};
    const short8 zero8 = {0, 0, 0, 0, 0, 0, 0, 0};
    int half = lane >> 5;
    #pragma unroll 1
    for (int t = 0; t < 27; t++) {
        int dxi = t / 9, dyi = (t / 3) % 3, dz = t % 3 - 1;
        int s0 = dxi * 6 + dyi + cp * 2;
        int zz = (lane & 31) + dz;
        bool zv = (unsigned)zz < 32u;
        int zc = zv ? zz : 0;
        const unsigned short* ac = sA + s0 * 2048 + (half << 8) + zc * 8;
        const unsigned short* wp = w + t * 4096 + nh * 512 + lane * 8;
        #pragma unroll
        for (int ks = 0; ks < 4; ks++) {
            short8 bf = *(const short8*)(wp + ks * 1024);
            short8 a0 = *(const short8*)(ac + ks * 512);
            short8 a1 = *(const short8*)(ac + 2048 + ks * 512);
            if (!zv) { a0 = zero8; a1 = zero8; }
            accA = __builtin_amdgcn_mfma_f32_32x32x16_bf16(a0, bf, accA, 0, 0, 0);
            accB = __builtin_amdgcn_mfma_f32_32x32x16_bf16(a1, bf, accB, 0, 0, 0);
        }
    }
    int o = nh * 32 + (lane & 31);
    float bb = bias[o];
    #pragma unroll
    for (int cc = 0; cc < 2; cc++) {
        int outcol = b * 1024 + x * 32 + (y0 + cp * 2 + cc);
        size_t cbase = (size_t)outcol << 11;
        size_t obase = cbase + (size_t)((o >> 3) << 8) + (o & 7);
        const f32x16& acc = cc ? accB : accA;
        #pragma unroll
        for (int r = 0; r < 16; r++) {
            int z = (r & 3) + ((r >> 2) << 3) + ((lane >> 5) << 2);
            size_t oe = obase + (size_t)z * 8;
            float v = acc[r] + bb;
            if (idF) v += idF[oe];
            v = fmaxf(v, 0.f);
            if (zmaj) out[cbase + (size_t)z * 64 + o] = f2b(v);
            else out[oe] = f2b(v);
            if (outF) outF[oe] = v;
        }
    }
}

// point-branch MLP via MFMA: pfeat[B][N][64] bf16 = relu(PW * feat + PB)
__global__ __launch_bounds__(256) void k_pfeat(const float* __restrict__ feats,
        const float* __restrict__ pb, const unsigned short* __restrict__ pwb,
        unsigned short* __restrict__ pf) {
    int tid = threadIdx.x;
    int lane = tid & 63;
    int wv = tid >> 6;
    int tile = blockIdx.x * 4 + wv;          // 0..8191
    int b = tile >> 11;
    int n0 = (tile & 2047) << 5;
    int m = lane & 31, kg = lane >> 5;
    const float* fb = feats + ((size_t)b << 22) + n0 + m;
    f32x16 acc0 = {}, acc1 = {};
    #pragma unroll
    for (int ks = 0; ks < 4; ks++) {
        short8 af;
        #pragma unroll
        for (int j = 0; j < 8; j++)
            af[j] = (short)f2b(fb[(size_t)(ks * 16 + kg * 8 + j) << 16]);
        short8 b0 = *(const short8*)(pwb + ((size_t)(ks * 64 + lane) << 3));
        short8 b1 = *(const short8*)(pwb + ((size_t)((4 + ks) * 64 + lane) << 3));
        acc0 = __builtin_amdgcn_mfma_f32_32x32x16_bf16(af, b0, acc0, 0, 0, 0);
        acc1 = __builtin_amdgcn_mfma_f32_32x32x16_bf16(af, b1, acc1, 0, 0, 0);
    }
    int och = lane & 31;
    float bias0 = pb[och], bias1 = pb[32 + och];
    #pragma unroll
    for (int r = 0; r < 16; r++) {
        int p = (r & 3) + ((r >> 2) << 3) + ((lane >> 5) << 2);
        size_t base = ((size_t)(b << 16) + n0 + p) << 6;
        pf[base + och]      = f2b(fmaxf(acc0[r] + bias0, 0.f));
        pf[base + 32 + och] = f2b(fmaxf(acc1[r] + bias1, 0.f));
    }
}

// devox gather (z-major grid) + pfeat load + collapsed attention + fuse.
// wave = 8 points x 8 channel-groups; per-corner loads coalesce to 8x128B segments.
__global__ __launch_bounds__(256) void k_final(const float* __restrict__ cb3,
        const unsigned short* __restrict__ gb, const unsigned short* __restrict__ pfeat,
        const float* __restrict__ ws, float* __restrict__ out) {
    int tid = threadIdx.x;
    int lane = tid & 63;
    int g = lane >> 3;      // channel group 0..7
    int p = lane & 7;       // point within wave
    int b = blockIdx.y;
    int n = (blockIdx.x << 5) + ((tid >> 6) << 3) + p;
    int gid = (b << 16) + n;
    float c0 = cb3[gid * 3], c1 = cb3[gid * 3 + 1], c2 = cb3[gid * 3 + 2];
    int lx = (int)floorf(c0), ly = (int)floorf(c1), lz = (int)floorf(c2);
    int hx = min(lx + 1, 31), hy = min(ly + 1, 31), hz = min(lz + 1, 31);
    float fx = c0 - (float)lx, fy = c1 - (float)ly, fz = c2 - (float)lz;
    int xs[2] = {lx, hx}; float wxx[2] = {1.f - fx, fx};
    int ys[2] = {ly, hy}; float wyy[2] = {1.f - fy, fy};
    int zs[2] = {lz, hz}; float wzz[2] = {1.f - fz, fz};
    float vf[8];
    #pragma unroll
    for (int j = 0; j < 8; j++) vf[j] = 0.f;
    #pragma unroll
    for (int ii = 0; ii < 2; ii++)
    #pragma unroll
    for (int jj = 0; jj < 2; jj++)
    #pragma unroll
    for (int kk = 0; kk < 2; kk++) {
        float wgt = wxx[ii] * wyy[jj] * wzz[kk];
        const unsigned short* gp = gb + (((size_t)b * 1024 + xs[ii] * 32 + ys[jj]) << 11)
                                      + zs[kk] * 64 + (g << 3);
        short8 v = *(const short8*)gp;
        #pragma unroll
        for (int j = 0; j < 8; j++) vf[j] += wgt * b2f((unsigned short)v[j]);
    }
    float pfv[8];
    const unsigned short* pp = pfeat + ((size_t)gid << 6) + (g << 3);
    short8 pv = *(const short8*)pp;
    #pragma unroll
    for (int j = 0; j < 8; j++) pfv[j] = b2f((unsigned short)pv[j]);
    const float* wae = ws + OFF_WAE + (g << 3);
    const float* wbe = ws + OFF_WBE + (g << 3);
    float part = 0.f;
    #pragma unroll
    for (int j = 0; j < 8; j++) part += wae[j] * vf[j] + wbe[j] * pfv[j];
    // reduce across channel groups (lane bits 3..5) -> all lanes of a point get q
    part += __shfl_xor(part, 8, 64);
    part += __shfl_xor(part, 16, 64);
    part += __shfl_xor(part, 32, 64);
    float q = part + ws[OFF_Q0];
    float attn = 1.0f + 1.0f / (1.0f + expf(-q));
    float* op = out + (((size_t)(b * 64 + (g << 3))) << 16) + n;
    #pragma unroll
    for (int j = 0; j < 8; j++) op[(size_t)j << 16] = vf[j] * attn + pfv[j];
}

extern "C" void kernel_launch(void* const* d_in, const int* in_sizes, int n_in,
                              void* d_out, int out_size, void* d_ws, size_t ws_size,
                              hipStream_t stream) {
    const float* features = (const float*)d_in[0];
    const float* coords   = (const float*)d_in[1];
    const float* vconv_w  = (const float*)d_in[2];
    const float* vconv_b  = (const float*)d_in[3];
    const float* vbn_g    = (const float*)d_in[4];
    const float* vbn_b    = (const float*)d_in[5];
    const float* res_w    = (const float*)d_in[6];
    const float* res_b    = (const float*)d_in[7];
    const float* res_bn_g = (const float*)d_in[8];
    const float* res_bn_b = (const float*)d_in[9];
    const float* pf_w     = (const float*)d_in[10];
    const float* pf_b     = (const float*)d_in[11];
    const float* pf_bn_g  = (const float*)d_in[12];
    const float* pf_bn_b  = (const float*)d_in[13];
    const float* attn_wa  = (const float*)d_in[14];
    const float* attn_ba  = (const float*)d_in[15];
    const float* attn_wb  = (const float*)d_in[16];
    const float* attn_bb  = (const float*)d_in[17];
    const float* attn_wc  = (const float*)d_in[18];
    const float* attn_bc  = (const float*)d_in[19];
    float* ws  = (float*)d_ws;
    float* out = (float*)d_out;

    unsigned short* WB  = (unsigned short*)(ws + OFF_WB16);
    unsigned short* PWB = (unsigned short*)(ws + OFF_PWB);
    int*            CUR = (int*)(ws + OFF_CUR);
    int*            AUX = (int*)(ws + OFF_AUX);
    unsigned short* ORD = (unsigned short*)(ws + OFF_ORD);
    unsigned short* FT  = (unsigned short*)(ws + OFF_GA);   // pre-conv overlay
    unsigned short* PF  = (unsigned short*)(ws + OFF_GA);   // post-conv overlay
    float* GA = ws + OFF_GA;
    unsigned short* G0 = (unsigned short*)(ws + OFF_G0);
    unsigned short* G1 = (unsigned short*)(ws + OFF_G1);
    const float* Bv = ws + OFF_BEFF;

    k_fold_w<<<2160, 256, 0, stream>>>(vconv_w, vbn_g, res_w, res_bn_g, WB);
    k_misc<<<19, 256, 0, stream>>>(vconv_b, vbn_g, vbn_b, res_b, res_bn_g, res_bn_b,
                                   pf_w, pf_b, pf_bn_g, pf_bn_b,
                                   attn_wa, attn_ba, attn_wb, attn_bb, attn_wc, attn_bc, ws);
    k_zero<<<128, 256, 0, stream>>>((float4*)CUR, 32768);
    k_mean1<<<96, 256, 0, stream>>>(coords, ws + OFF_PART);
    k_mean2<<<1, 64, 0, stream>>>(ws + OFF_PART, ws + OFF_MEAN);
    k_maxn1<<<32, 256, 0, stream>>>(coords, ws + OFF_MEAN, ws + OFF_PART);
    k_maxn2<<<1, 64, 0, stream>>>(ws + OFF_PART, ws + OFF_MAXN);
    k_prep<<<1024, 256, 0, stream>>>(coords, ws + OFF_MEAN, ws + OFF_MAXN,
                                     ws + OFF_CB3, CUR);
    k_scan1<<<256, 256, 0, stream>>>(CUR, AUX);
    k_scan2<<<1, 256, 0, stream>>>(AUX);
    k_scan3<<<256, 256, 0, stream>>>(CUR, AUX);
    k_trans<<<4096, 256, 0, stream>>>(features, FT);
    k_place<<<1024, 256, 0, stream>>>(ws + OFF_CB3, CUR, ORD);
    k_gather<<<32768, 256, 0, stream>>>(CUR, ORD, FT, G0);

    dim3 cg(256, 4);
    k_conv<<<cg, 256, 0, stream>>>(G0, WB + 0 * 110592, Bv + 0,   nullptr, GA,      G1, 0);
    k_conv<<<cg, 256, 0, stream>>>(G1, WB + 1 * 110592, Bv + 64,  nullptr, nullptr, G0, 0);
    k_conv<<<cg, 256, 0, stream>>>(G0, WB + 2 * 110592, Bv + 128, GA,      GA,      G1, 0);
    k_conv<<<cg, 256, 0, stream>>>(G1, WB + 3 * 110592, Bv + 192, nullptr, nullptr, G0, 0);
    k_conv<<<cg, 256, 0, stream>>>(G0, WB + 4 * 110592, Bv + 256, GA,      nullptr, G1, 1);

    k_pfeat<<<2048, 256, 0, stream>>>(features, ws + OFF_PB, PWB, PF);

    dim3 fg(2048, 4);
    k_final<<<fg, 256, 0, stream>>>(ws + OFF_CB3, G1, PF, ws, out);
}

// Round 8
// 537.238 us; speedup vs baseline: 22.1223x; 1.0321x over previous
//
#include <hip/hip_runtime.h>
#include <math.h>

#define NPT 65536
#define NB 4
#define R3 32768

typedef __attribute__((ext_vector_type(8))) short short8;
typedef __attribute__((ext_vector_type(16))) float f32x16;

// ws layout (float offsets)
#define OFF_WB16 0          // 276480 floats = 552960 bf16: 5 conv layers, B-frag order
#define OFF_BEFF 276480     // 5*64 conv biases (BN-folded)
#define OFF_PWB  276800     // 2048 floats = 4096 bf16: point-branch weights, B-frag order
#define OFF_PB   280896     // 64
#define OFF_WAE  280960     // 64
#define OFF_WBE  281024     // 64
#define OFF_Q0   281088     // 1 (+pad)
#define OFF_MEAN 281104     // 12
#define OFF_MAXN 281116     // 4
#define OFF_PART 281120     // 128 reduction partials (96 mean + 32 max)
#define OFF_AUX  281248     // 256 scan block sums (int)
#define OFF_CB3  281504     // 786432: 3 floats/point normalized coords
#define OFF_CUR  1067936    // 131072 int cursor
#define OFF_ORD  1199008    // 131072 floats = 262144 ushort sorted point ids
#define OFF_GA   1330080    // 8388608 fp32 residual; FT bf16 overlays pre-conv; PF bf16 overlays post-conv
#define OFF_G0   9718688    // 4194304 floats = 8388608 bf16 swizzled grid ping
#define OFF_G1   13912992   // 4194304 floats = 8388608 bf16 swizzled grid pong

__device__ __forceinline__ unsigned short f2b(float f) {
    union { float f; unsigned int u; } v; v.f = f;
    unsigned int r = v.u + 0x7fffu + ((v.u >> 16) & 1u);
    return (unsigned short)(r >> 16);
}
__device__ __forceinline__ float b2f(unsigned short u) {
    union { unsigned int u; float f; } v; v.u = ((unsigned int)u) << 16; return v.f;
}

// merged: conv-weight fold (idx < 552960) + misc param prep (idx >= 552960)
__global__ void k_setup(const float* __restrict__ vconv_w, const float* __restrict__ vconv_b,
                        const float* __restrict__ vbn_g, const float* __restrict__ vbn_b,
                        const float* __restrict__ res_w, const float* __restrict__ res_b,
                        const float* __restrict__ res_bn_g, const float* __restrict__ res_bn_b,
                        const float* __restrict__ pf_w, const float* __restrict__ pf_b,
                        const float* __restrict__ pf_bn_g, const float* __restrict__ pf_bn_b,
                        const float* __restrict__ wa, const float* __restrict__ ba,
                        const float* __restrict__ wb, const float* __restrict__ bb,
                        const float* __restrict__ wc, const float* __restrict__ bc,
                        float* __restrict__ ws) {
    int idx = blockIdx.x * 256 + threadIdx.x;
    const float invs = rsqrtf(1.00001f);
    if (idx < 552960) {
        unsigned short* wb16 = (unsigned short*)(ws + OFF_WB16);
        int j = idx & 7;
        int l = (idx >> 3) & 63;
        int nh = (idx >> 9) & 1;
        int ks = (idx >> 10) & 3;
        int rest = idx >> 12;          // layer*27 + t
        int t = rest % 27;
        int layer = rest / 27;
        int i = ks * 16 + ((l >> 5) << 3) + j;
        int o = nh * 32 + (l & 31);
        float scale, wsrc;
        if (layer == 0) {
            scale = vbn_g[o] * invs;
            wsrc = vconv_w[(o * 64 + i) * 27 + t];
        } else {
            scale = res_bn_g[(layer - 1) * 64 + o] * invs;
            wsrc = res_w[(size_t)(layer - 1) * 110592 + (o * 64 + i) * 27 + t];
        }
        wb16[idx] = f2b(wsrc * scale);
        return;
    }
    idx -= 552960;
    if (idx < 320) {
        int l = idx >> 6, o = idx & 63;
        float b_, g_, s_;
        if (l == 0) { b_ = vconv_b[o]; g_ = vbn_g[o]; s_ = vbn_b[o]; }
        else {
            b_ = res_b[(l - 1) * 64 + o];
            g_ = res_bn_g[(l - 1) * 64 + o];
            s_ = res_bn_b[(l - 1) * 64 + o];
        }
        ws[OFF_BEFF + idx] = b_ * g_ * invs + s_;
    } else if (idx < 4416) {
        int e = idx - 320;                 // 0..4095
        int j = e & 7;
        int lane = (e >> 3) & 63;
        int ks = (e >> 9) & 3;
        int half = e >> 11;
        int i = ks * 16 + ((lane >> 5) << 3) + j;
        int o = half * 32 + (lane & 31);
        ((unsigned short*)(ws + OFF_PWB))[e] = f2b(pf_w[o * 64 + i] * pf_bn_g[o] * invs);
    } else if (idx < 4480) {
        int o = idx - 4416;
        ws[OFF_PB + o] = pf_b[o] * pf_bn_g[o] * invs + pf_bn_b[o];
    } else if (idx < 4544) {
        int o = idx - 4480;
        float s = 0.f;
        for (int j = 0; j < 16; j++) s += wc[j] * wa[j * 64 + o];
        ws[OFF_WAE + o] = s;
    } else if (idx < 4608) {
        int o = idx - 4544;
        float s = 0.f;
        for (int j = 0; j < 16; j++) s += wc[16 + j] * wb[j * 64 + o];
        ws[OFF_WBE + o] = s;
    } else if (idx == 4608) {
        float s = bc[0];
        for (int j = 0; j < 16; j++) s += wc[j] * ba[j] + wc[16 + j] * bb[j];
        ws[OFF_Q0] = s;
    }
}

// stage-1 mean partials (96 blocks = 12 (b,d) x 8 chunks) + grid-stride zero of CUR
__global__ __launch_bounds__(256) void k_mean1(const float* __restrict__ coords,
                                               float* __restrict__ part,
                                               float4* __restrict__ curz) {
    for (int i = blockIdx.x * 256 + threadIdx.x; i < 32768; i += 96 * 256)
        curz[i] = make_float4(0.f, 0.f, 0.f, 0.f);
    __shared__ float sm[256];
    int bd = blockIdx.x >> 3, chunk = blockIdx.x & 7;
    int tid = threadIdx.x;
    const float* p = coords + (size_t)bd * NPT + chunk * 8192;
    float s = 0.f;
    for (int n = tid; n < 8192; n += 256) s += p[n];
    sm[tid] = s; __syncthreads();
    for (int st = 128; st > 0; st >>= 1) {
        if (tid < st) sm[tid] += sm[tid + st];
        __syncthreads();
    }
    if (tid == 0) part[blockIdx.x] = sm[0];
}

// stage-1 max-norm^2 partials (32 blocks = 4 b x 8 chunks); mean computed from partials inline.
// chunk-0 block stores mean for k_prep.
__global__ __launch_bounds__(256) void k_maxn1(const float* __restrict__ coords,
                                               float* __restrict__ part,
                                               float* __restrict__ mean) {
    __shared__ float sm[256];
    int b = blockIdx.x >> 3, chunk = blockIdx.x & 7;
    int tid = threadIdx.x;
    float m0 = 0.f, m1 = 0.f, m2 = 0.f;
    #pragma unroll
    for (int c = 0; c < 8; c++) {
        m0 += part[(b * 3 + 0) * 8 + c];
        m1 += part[(b * 3 + 1) * 8 + c];
        m2 += part[(b * 3 + 2) * 8 + c];
    }
    m0 *= (1.0f / NPT); m1 *= (1.0f / NPT); m2 *= (1.0f / NPT);
    if (chunk == 0 && tid == 0) {
        mean[b * 3] = m0; mean[b * 3 + 1] = m1; mean[b * 3 + 2] = m2;
    }
    const float* p0 = coords + (size_t)(b * 3) * NPT + chunk * 8192;
    float mx = 0.f;
    for (int n = tid; n < 8192; n += 256) {
        float dx = p0[n] - m0, dy = p0[NPT + n] - m1, dz = p0[2 * NPT + n] - m2;
        mx = fmaxf(mx, dx * dx + dy * dy + dz * dz);
    }
    sm[tid] = mx; __syncthreads();
    for (int st = 128; st > 0; st >>= 1) {
        if (tid < st) sm[tid] = fmaxf(sm[tid], sm[tid + st]);
        __syncthreads();
    }
    if (tid == 0) part[96 + blockIdx.x] = sm[0];
}

// per-point normalized coords + voxel histogram; max-norm finalized inline from partials
__global__ void k_prep(const float* __restrict__ coords, const float* __restrict__ mean,
                       const float* __restrict__ part, float* __restrict__ cb3,
                       int* __restrict__ cursor) {
    int gid = blockIdx.x * 256 + threadIdx.x;
    int b = gid >> 16, n = gid & 65535;
    float mx = 0.f;
    #pragma unroll
    for (int c = 0; c < 8; c++) mx = fmaxf(mx, part[96 + b * 8 + c]);
    float inv = 0.5f / sqrtf(mx);
    float c0 = (coords[(size_t)(b * 3) * NPT + n]     - mean[b * 3])     * inv + 0.5f;
    float c1 = (coords[(size_t)(b * 3 + 1) * NPT + n] - mean[b * 3 + 1]) * inv + 0.5f;
    float c2 = (coords[(size_t)(b * 3 + 2) * NPT + n] - mean[b * 3 + 2]) * inv + 0.5f;
    c0 = fminf(fmaxf(c0 * 32.f, 0.f), 31.f);
    c1 = fminf(fmaxf(c1 * 32.f, 0.f), 31.f);
    c2 = fminf(fmaxf(c2 * 32.f, 0.f), 31.f);
    cb3[gid * 3]     = c0;
    cb3[gid * 3 + 1] = c1;
    cb3[gid * 3 + 2] = c2;
    int vx = b * R3 + ((int)rintf(c0) * 1024 + (int)rintf(c1) * 32 + (int)rintf(c2));
    atomicAdd(&cursor[vx], 1);
}

// scan stage 1: 256 blocks x 512 bins -> local exclusive scan + block totals
__global__ void k_scan1(int* __restrict__ cur, int* __restrict__ aux) {
    __shared__ int sm[256];
    int t = threadIdx.x;
    int base = blockIdx.x * 512 + t * 2;
    int c0 = cur[base], c1 = cur[base + 1];
    int s = c0 + c1;
    sm[t] = s; __syncthreads();
    for (int off = 1; off < 256; off <<= 1) {
        int v = (t >= off) ? sm[t - off] : 0;
        __syncthreads();
        sm[t] += v;
        __syncthreads();
    }
    int ex = sm[t] - s;
    cur[base] = ex;
    cur[base + 1] = ex + c0;
    if (t == 255) aux[blockIdx.x] = sm[t];
}

// scan stage 2+3 fused: each block reduces aux[0..blk) locally, adds offset
__global__ void k_scan3(int* __restrict__ cur, const int* __restrict__ aux) {
    __shared__ int sm[256];
    int t = threadIdx.x;
    sm[t] = (t < blockIdx.x) ? aux[t] : 0;
    __syncthreads();
    for (int off = 128; off > 0; off >>= 1) {
        if (t < off) sm[t] += sm[t + off];
        __syncthreads();
    }
    int add = sm[0];
    int base = blockIdx.x * 512 + t * 2;
    cur[base] += add;
    cur[base + 1] += add;
}

// features [B][64][N] fp32 -> FT [B][N][64] bf16 (LDS transpose)
__global__ __launch_bounds__(256) void k_trans(const float* __restrict__ feats,
                                               unsigned short* __restrict__ ft) {
    __shared__ float lds[64][65];
    int b = blockIdx.x >> 10;
    int n0 = (blockIdx.x & 1023) << 6;
    int tid = threadIdx.x;
    int nl = tid & 63;
    #pragma unroll
    for (int it = 0; it < 16; it++) {
        int ch = it * 4 + (tid >> 6);
        lds[nl][ch] = feats[((size_t)(b * 64 + ch) << 16) + n0 + nl];
    }
    __syncthreads();
    int nn = tid >> 2;
    int ch0 = (tid & 3) << 4;
    size_t obase = (((size_t)(b << 16) + n0 + nn) << 6) + ch0;
    short8 v0, v1;
    #pragma unroll
    for (int j = 0; j < 8; j++) v0[j] = (short)f2b(lds[nn][ch0 + j]);
    #pragma unroll
    for (int j = 0; j < 8; j++) v1[j] = (short)f2b(lds[nn][ch0 + 8 + j]);
    *(short8*)(ft + obase) = v0;
    *(short8*)(ft + obase + 8) = v1;
}

// place point ids into voxel-sorted order
__global__ void k_place(const float* __restrict__ cb3, int* __restrict__ cursor,
                        unsigned short* __restrict__ order) {
    int gid = blockIdx.x * 256 + threadIdx.x;
    int b = gid >> 16;
    float c0 = cb3[gid * 3], c1 = cb3[gid * 3 + 1], c2 = cb3[gid * 3 + 2];
    int vx = b * R3 + ((int)rintf(c0) * 1024 + (int)rintf(c1) * 32 + (int)rintf(c2));
    int slot = atomicAdd(&cursor[vx], 1);
    order[slot] = (unsigned short)(gid & 65535);
}

// one wave per voxel, point-parallel: lane = (point-slot p, ch-group g).
__global__ __launch_bounds__(256) void k_gather(const int* __restrict__ cursor,
        const unsigned short* __restrict__ order, const unsigned short* __restrict__ ft,
        unsigned short* __restrict__ g0) {
    int tid = threadIdx.x;
    int lane = tid & 63;
    int vx = blockIdx.x * 4 + (tid >> 6);
    int e = cursor[vx];
    int s = (vx == 0) ? 0 : cursor[vx - 1];
    int cnt = e - s;
    int p = lane >> 3;      // point slot 0..7
    int g = lane & 7;       // channel group 0..7 (8 channels each)
    int bb = vx >> 15;
    float acc[8] = {0.f, 0.f, 0.f, 0.f, 0.f, 0.f, 0.f, 0.f};
    for (int base = s; base < e; base += 8) {
        int idx = base + p;
        if (idx < e) {
            int n = order[idx];
            const unsigned short* fp = ft + (((size_t)(bb << 16) + n) << 6) + (g << 3);
            short8 v = *(const short8*)fp;
            #pragma unroll
            for (int j = 0; j < 8; j++) acc[j] += b2f((unsigned short)v[j]);
        }
    }
    #pragma unroll
    for (int j = 0; j < 8; j++) {
        acc[j] += __shfl_xor(acc[j], 8, 64);
        acc[j] += __shfl_xor(acc[j], 16, 64);
        acc[j] += __shfl_xor(acc[j], 32, 64);
    }
    if (p == 0) {
        float inv = 1.0f / (float)max(cnt, 1);
        int col = vx >> 5, z = vx & 31;
        short8 o8;
        #pragma unroll
        for (int j = 0; j < 8; j++) o8[j] = (short)f2b(acc[j] * inv);
        *(short8*)(g0 + (size_t)col * 2048 + (g << 8) + z * 8) = o8;
    }
}

// MFMA implicit-GEMM 3^3 conv, 4 columns/block.
// 4 waves: (column-pair, out-ch-half). 18 staged columns (72KB LDS) via global_load_lds.
// Tap loop: 9 (dx,dy) columns outer; (dz x ks) = 12 K-steps fully unrolled for ILP.
// zmaj: write output in devox-friendly z-major layout [col][z][64ch].
__global__ __launch_bounds__(256) void k_conv(const unsigned short* __restrict__ in,
        const unsigned short* __restrict__ w, const float* __restrict__ bias,
        const float* __restrict__ idF, float* __restrict__ outF,
        unsigned short* __restrict__ out, int zmaj) {
    __shared__ unsigned short sA[18 * 2048];    // 72 KB
    int tid = threadIdx.x;
    int lane = tid & 63;
    int wid = tid >> 6;
    int cp = wid & 1;          // column pair: y0+2cp, y0+2cp+1
    int nh = wid >> 1;         // out-channel half
    int tile = blockIdx.x;     // 0..255
    int b = blockIdx.y;
    int x = tile >> 3;
    int y0 = (tile & 7) << 2;
    #pragma unroll 1
    for (int s = 0; s < 18; s++) {
        int gx = x + s / 6 - 1;
        int gy = y0 + s % 6 - 1;
        if ((unsigned)gx < 32u && (unsigned)gy < 32u) {
            const unsigned short* gsrc = in + (((size_t)b * 1024 + gx * 32 + gy) << 11)
                                            + ((size_t)tid << 3);
            __builtin_amdgcn_global_load_lds(
                (const __attribute__((address_space(1))) unsigned int*)gsrc,
                (__attribute__((address_space(3))) unsigned int*)(sA + s * 2048 + (wid << 9)),
                16, 0, 0);
        } else {
            ((float4*)(sA + s * 2048))[tid] = make_float4(0.f, 0.f, 0.f, 0.f);
        }
    }
    __syncthreads();
    f32x16 accA = {}, accB = {};
    const short8 zero8 = {0, 0, 0, 0, 0, 0, 0, 0};
    int half = lane >> 5;
    int z = lane & 31;
    #pragma unroll 1
    for (int c9 = 0; c9 < 9; c9++) {
        int dxi = c9 / 3, dyi = c9 % 3;
        int s0 = dxi * 6 + dyi + cp * 2;
        const unsigned short* acol0 = sA + s0 * 2048 + (half << 8);
        const unsigned short* wbase = w + (dxi * 9 + dyi * 3) * 4096 + nh * 512 + lane * 8;
        #pragma unroll
        for (int dzi = 0; dzi < 3; dzi++) {
            int zz = z + dzi - 1;
            bool zv = (unsigned)zz < 32u;
            int zc = zv ? zz : 0;
            const unsigned short* ac0 = acol0 + zc * 8;
            const unsigned short* wp = wbase + dzi * 4096;
            #pragma unroll
            for (int ks = 0; ks < 4; ks++) {
                short8 bf = *(const short8*)(wp + ks * 1024);
                short8 a0 = *(const short8*)(ac0 + ks * 512);
                short8 a1 = *(const short8*)(ac0 + 2048 + ks * 512);
                if (!zv) { a0 = zero8; a1 = zero8; }
                accA = __builtin_amdgcn_mfma_f32_32x32x16_bf16(a0, bf, accA, 0, 0, 0);
                accB = __builtin_amdgcn_mfma_f32_32x32x16_bf16(a1, bf, accB, 0, 0, 0);
            }
        }
    }
    int o = nh * 32 + (lane & 31);
    float bb = bias[o];
    #pragma unroll
    for (int cc = 0; cc < 2; cc++) {
        int outcol = b * 1024 + x * 32 + (y0 + cp * 2 + cc);
        size_t cbase = (size_t)outcol << 11;
        size_t obase = cbase + (size_t)((o >> 3) << 8) + (o & 7);
        const f32x16& acc = cc ? accB : accA;
        #pragma unroll
        for (int r = 0; r < 16; r++) {
            int zr = (r & 3) + ((r >> 2) << 3) + ((lane >> 5) << 2);
            size_t oe = obase + (size_t)zr * 8;
            float v = acc[r] + bb;
            if (idF) v += idF[oe];
            v = fmaxf(v, 0.f);
            if (zmaj) out[cbase + (size_t)zr * 64 + o] = f2b(v);
            else out[oe] = f2b(v);
            if (outF) outF[oe] = v;
        }
    }
}

// point-branch MLP via MFMA: pfeat[B][N][64] bf16 = relu(PW * feat + PB)
__global__ __launch_bounds__(256) void k_pfeat(const float* __restrict__ feats,
        const float* __restrict__ pb, const unsigned short* __restrict__ pwb,
        unsigned short* __restrict__ pf) {
    int tid = threadIdx.x;
    int lane = tid & 63;
    int wv = tid >> 6;
    int tile = blockIdx.x * 4 + wv;          // 0..8191
    int b = tile >> 11;
    int n0 = (tile & 2047) << 5;
    int m = lane & 31, kg = lane >> 5;
    const float* fb = feats + ((size_t)b << 22) + n0 + m;
    f32x16 acc0 = {}, acc1 = {};
    #pragma unroll
    for (int ks = 0; ks < 4; ks++) {
        short8 af;
        #pragma unroll
        for (int j = 0; j < 8; j++)
            af[j] = (short)f2b(fb[(size_t)(ks * 16 + kg * 8 + j) << 16]);
        short8 b0 = *(const short8*)(pwb + ((size_t)(ks * 64 + lane) << 3));
        short8 b1 = *(const short8*)(pwb + ((size_t)((4 + ks) * 64 + lane) << 3));
        acc0 = __builtin_amdgcn_mfma_f32_32x32x16_bf16(af, b0, acc0, 0, 0, 0);
        acc1 = __builtin_amdgcn_mfma_f32_32x32x16_bf16(af, b1, acc1, 0, 0, 0);
    }
    int och = lane & 31;
    float bias0 = pb[och], bias1 = pb[32 + och];
    #pragma unroll
    for (int r = 0; r < 16; r++) {
        int p = (r & 3) + ((r >> 2) << 3) + ((lane >> 5) << 2);
        size_t base = ((size_t)(b << 16) + n0 + p) << 6;
        pf[base + och]      = f2b(fmaxf(acc0[r] + bias0, 0.f));
        pf[base + 32 + och] = f2b(fmaxf(acc1[r] + bias1, 0.f));
    }
}

// devox gather (z-major grid) + pfeat load + collapsed attention + fuse.
// wave = 8 points x 8 channel-groups; per-corner loads coalesce to 8x128B segments.
__global__ __launch_bounds__(256) void k_final(const float* __restrict__ cb3,
        const unsigned short* __restrict__ gb, const unsigned short* __restrict__ pfeat,
        const float* __restrict__ ws, float* __restrict__ out) {
    int tid = threadIdx.x;
    int lane = tid & 63;
    int g = lane >> 3;      // channel group 0..7
    int p = lane & 7;       // point within wave
    int b = blockIdx.y;
    int n = (blockIdx.x << 5) + ((tid >> 6) << 3) + p;
    int gid = (b << 16) + n;
    float c0 = cb3[gid * 3], c1 = cb3[gid * 3 + 1], c2 = cb3[gid * 3 + 2];
    int lx = (int)floorf(c0), ly = (int)floorf(c1), lz = (int)floorf(c2);
    int hx = min(lx + 1, 31), hy = min(ly + 1, 31), hz = min(lz + 1, 31);
    float fx = c0 - (float)lx, fy = c1 - (float)ly, fz = c2 - (float)lz;
    int xs[2] = {lx, hx}; float wxx[2] = {1.f - fx, fx};
    int ys[2] = {ly, hy}; float wyy[2] = {1.f - fy, fy};
    int zs[2] = {lz, hz}; float wzz[2] = {1.f - fz, fz};
    float vf[8];
    #pragma unroll
    for (int j = 0; j < 8; j++) vf[j] = 0.f;
    #pragma unroll
    for (int ii = 0; ii < 2; ii++)
    #pragma unroll
    for (int jj = 0; jj < 2; jj++)
    #pragma unroll
    for (int kk = 0; kk < 2; kk++) {
        float wgt = wxx[ii] * wyy[jj] * wzz[kk];
        const unsigned short* gp = gb + (((size_t)b * 1024 + xs[ii] * 32 + ys[jj]) << 11)
                                      + zs[kk] * 64 + (g << 3);
        short8 v = *(const short8*)gp;
        #pragma unroll
        for (int j = 0; j < 8; j++) vf[j] += wgt * b2f((unsigned short)v[j]);
    }
    float pfv[8];
    const unsigned short* pp = pfeat + ((size_t)gid << 6) + (g << 3);
    short8 pv = *(const short8*)pp;
    #pragma unroll
    for (int j = 0; j < 8; j++) pfv[j] = b2f((unsigned short)pv[j]);
    const float* wae = ws + OFF_WAE + (g << 3);
    const float* wbe = ws + OFF_WBE + (g << 3);
    float part = 0.f;
    #pragma unroll
    for (int j = 0; j < 8; j++) part += wae[j] * vf[j] + wbe[j] * pfv[j];
    part += __shfl_xor(part, 8, 64);
    part += __shfl_xor(part, 16, 64);
    part += __shfl_xor(part, 32, 64);
    float q = part + ws[OFF_Q0];
    float attn = 1.0f + 1.0f / (1.0f + expf(-q));
    float* op = out + (((size_t)(b * 64 + (g << 3))) << 16) + n;
    #pragma unroll
    for (int j = 0; j < 8; j++) op[(size_t)j << 16] = vf[j] * attn + pfv[j];
}

extern "C" void kernel_launch(void* const* d_in, const int* in_sizes, int n_in,
                              void* d_out, int out_size, void* d_ws, size_t ws_size,
                              hipStream_t stream) {
    const float* features = (const float*)d_in[0];
    const float* coords   = (const float*)d_in[1];
    const float* vconv_w  = (const float*)d_in[2];
    const float* vconv_b  = (const float*)d_in[3];
    const float* vbn_g    = (const float*)d_in[4];
    const float* vbn_b    = (const float*)d_in[5];
    const float* res_w    = (const float*)d_in[6];
    const float* res_b    = (const float*)d_in[7];
    const float* res_bn_g = (const float*)d_in[8];
    const float* res_bn_b = (const float*)d_in[9];
    const float* pf_w     = (const float*)d_in[10];
    const float* pf_b     = (const float*)d_in[11];
    const float* pf_bn_g  = (const float*)d_in[12];
    const float* pf_bn_b  = (const float*)d_in[13];
    const float* attn_wa  = (const float*)d_in[14];
    const float* attn_ba  = (const float*)d_in[15];
    const float* attn_wb  = (const float*)d_in[16];
    const float* attn_bb  = (const float*)d_in[17];
    const float* attn_wc  = (const float*)d_in[18];
    const float* attn_bc  = (const float*)d_in[19];
    float* ws  = (float*)d_ws;
    float* out = (float*)d_out;

    unsigned short* WB  = (unsigned short*)(ws + OFF_WB16);
    unsigned short* PWB = (unsigned short*)(ws + OFF_PWB);
    int*            CUR = (int*)(ws + OFF_CUR);
    int*            AUX = (int*)(ws + OFF_AUX);
    unsigned short* ORD = (unsigned short*)(ws + OFF_ORD);
    unsigned short* FT  = (unsigned short*)(ws + OFF_GA);   // pre-conv overlay
    unsigned short* PF  = (unsigned short*)(ws + OFF_GA);   // post-conv overlay
    float* GA = ws + OFF_GA;
    unsigned short* G0 = (unsigned short*)(ws + OFF_G0);
    unsigned short* G1 = (unsigned short*)(ws + OFF_G1);
    const float* Bv = ws + OFF_BEFF;

    k_setup<<<2179, 256, 0, stream>>>(vconv_w, vconv_b, vbn_g, vbn_b, res_w, res_b,
                                      res_bn_g, res_bn_b, pf_w, pf_b, pf_bn_g, pf_bn_b,
                                      attn_wa, attn_ba, attn_wb, attn_bb, attn_wc, attn_bc, ws);
    k_mean1<<<96, 256, 0, stream>>>(coords, ws + OFF_PART, (float4*)CUR);
    k_maxn1<<<32, 256, 0, stream>>>(coords, ws + OFF_PART, ws + OFF_MEAN);
    k_prep<<<1024, 256, 0, stream>>>(coords, ws + OFF_MEAN, ws + OFF_PART,
                                     ws + OFF_CB3, CUR);
    k_scan1<<<256, 256, 0, stream>>>(CUR, AUX);
    k_scan3<<<256, 256, 0, stream>>>(CUR, AUX);
    k_trans<<<4096, 256, 0, stream>>>(features, FT);
    k_place<<<1024, 256, 0, stream>>>(ws + OFF_CB3, CUR, ORD);
    k_gather<<<32768, 256, 0, stream>>>(CUR, ORD, FT, G0);

    dim3 cg(256, 4);
    k_conv<<<cg, 256, 0, stream>>>(G0, WB + 0 * 110592, Bv + 0,   nullptr, GA,      G1, 0);
    k_conv<<<cg, 256, 0, stream>>>(G1, WB + 1 * 110592, Bv + 64,  nullptr, nullptr, G0, 0);
    k_conv<<<cg, 256, 0, stream>>>(G0, WB + 2 * 110592, Bv + 128, GA,      GA,      G1, 0);
    k_conv<<<cg, 256, 0, stream>>>(G1, WB + 3 * 110592, Bv + 192, nullptr, nullptr, G0, 0);
    k_conv<<<cg, 256, 0, stream>>>(G0, WB + 4 * 110592, Bv + 256, GA,      nullptr, G1, 1);

    k_pfeat<<<2048, 256, 0, stream>>>(features, ws + OFF_PB, PWB, PF);

    dim3 fg(2048, 4);
    k_final<<<fg, 256, 0, stream>>>(ws + OFF_CB3, G1, PF, ws, out);
}